// Round 1
// 622.256 us; speedup vs baseline: 1.0090x; 1.0090x over previous
//
#include <hip/hip_runtime.h>
#include <cmath>

// ---------------------------------------------------------------------------
// VQ-VAE forward. B=256, C=3, HW=64, D=256, K=8192, LAT=128
// R9: decoder tail goes bf16. convt_mfma stores packed bf16 (2 ch/dword, via
// weight-column permutation so lane ln15 owns channels 2*ln15, 2*ln15+1):
// halves g3/g31 write bytes AND store-instruction count. t31 reads bf16 g3;
// convt4_tanh reads bf16 g31. BN stats still fp32 (pre-rounding). Loss path
// (VQ) untouched. conv2-4, t1, t2 keep parity mfmaconv. fc/VQ/conv1 fp32.
// ---------------------------------------------------------------------------

#define EPS_BN 1e-5f
typedef unsigned short ushort;
typedef short short8 __attribute__((ext_vector_type(8)));
typedef ushort us4 __attribute__((ext_vector_type(4)));
typedef float f32x4 __attribute__((ext_vector_type(4)));

__device__ __forceinline__ float lrelu(float v) { return v >= 0.f ? v : 0.01f * v; }
__device__ __forceinline__ ushort f2bf(float f) {
  unsigned u = __float_as_uint(f);
  return (ushort)((u + 0x7FFF + ((u >> 16) & 1)) >> 16);
}
__device__ __forceinline__ float bf2f(ushort u) {
  return __uint_as_float(((unsigned)u) << 16);
}

// ======================= weight transposes (once per launch) ===============
// conv (COUT,CIN,3,3) -> bf16 [co][t*CIN+ci]
__global__ __launch_bounds__(256) void tr_convw_bf(const float* __restrict__ w,
                                                   ushort* __restrict__ wT,
                                                   int CIN, int COUT, int total) {
  int i = blockIdx.x * 256 + threadIdx.x;
  if (i >= total) return;
  int co = i / (9 * CIN);
  int r = i - co * 9 * CIN;
  int t = r / CIN, ci = r - t * CIN;
  wT[i] = f2bf(w[((size_t)co * CIN + ci) * 9 + t]);
}

// convT (CIN,COUT,3,3) -> bf16 parity-concat [p][co][k]
__global__ __launch_bounds__(256) void tr_convtw_bf(const float* __restrict__ w,
                                                    ushort* __restrict__ wT,
                                                    int CIN, int COUT, int total) {
  int i = blockIdx.x * 256 + threadIdx.x;
  if (i >= total) return;
  const int cc = CIN * COUT;
  int p, base, Kp;
  if (i < cc) { p = 0; base = 0; Kp = CIN; }
  else if (i < 3 * cc) { p = 1; base = cc; Kp = 2 * CIN; }
  else if (i < 5 * cc) { p = 2; base = 3 * cc; Kp = 2 * CIN; }
  else { p = 3; base = 5 * cc; Kp = 4 * CIN; }
  const int r = i - base;
  const int co = r / Kp;
  const int q = r - co * Kp;
  const int tix = q / CIN, ci = q - (q / CIN) * CIN;
  const int py = p >> 1, px = p & 1;
  const int nx = px ? 2 : 1;
  const int kyi = tix / nx, kxi = tix - kyi * nx;
  const int ky = py ? (kyi == 0 ? 0 : 2) : 1;
  const int kx = px ? (kxi == 0 ? 0 : 2) : 1;
  wT[i] = f2bf(w[((size_t)ci * COUT + co) * 9 + ky * 3 + kx]);
}

// convT (CIN,COUT=32,3,3) -> bf16 [t][co_slot][ci] (tap-major, columns
// PERMUTED so slot f*16+ln15 holds channel 2*ln15+f -> packed bf16 stores)
__global__ __launch_bounds__(256) void tr_convtw_tc(const float* __restrict__ w,
                                                    ushort* __restrict__ wT,
                                                    int CIN, int COUT, int total) {
  int i = blockIdx.x * 256 + threadIdx.x;
  if (i >= total) return;
  int ci = i % CIN;
  int tmp = i / CIN;
  int co = tmp % COUT;
  int t = tmp / COUT;
  const int co_slot = ((co & 1) << 4) | (co >> 1);
  wT[((size_t)t * COUT + co_slot) * CIN + ci] =
      f2bf(w[((size_t)ci * COUT + co) * 9 + t]);
}

// a4 NHWC [256,4,4,256] -> NCHW [256,256,4,4]
__global__ __launch_bounds__(256) void tr_a4(const float* __restrict__ in,
                                             float* __restrict__ out) {
  int i = blockIdx.x * 256 + threadIdx.x;
  int n = i >> 12, k = i & 4095;
  out[i] = in[(size_t)(n << 12) + ((k & 15) << 8) + (k >> 4)];
}

// wfc [4096,256] + bfc: permute ROWS from (c,y,x) to (y,x,c)
__global__ __launch_bounds__(256) void tr_fcdec(const float* __restrict__ in,
                                                const float* __restrict__ bin,
                                                float* __restrict__ out,
                                                float* __restrict__ bout) {
  int i = blockIdx.x * 256 + threadIdx.x;
  int k = i >> 8, d = i & 255;
  int kp = (k & 15) * 256 + (k >> 4);
  out[(size_t)kp * 256 + d] = in[i];
  if (d == 0) bout[kp] = bin[k];
}

// ======================= bf16 MFMA implicit-GEMM conv / convT ==============
template <int TN, int MODE, int IH, int CIN, int COUT, bool HASN>
__global__ __launch_bounds__(256) void mfmaconv(
    const float* __restrict__ X, const ushort* __restrict__ WT,
    const float* __restrict__ bias, const float* __restrict__ st, float invN,
    float* __restrict__ Y, float* __restrict__ stOut) {
  constexpr int OH = (MODE == 0) ? IH / 2 : 2 * IH;
  constexpr int NF = TN / 16;
  __shared__ short As[64][40];
  __shared__ short Bs[TN][40];
  __shared__ float nrm0[HASN ? CIN : 4], nrm1[HASN ? CIN : 4];
  __shared__ float redS[4][TN], redQ[4][TN];
  const int tid = threadIdx.x;
  const int wv = tid >> 6, lane = tid & 63;
  const int quad = lane >> 4, ln15 = tid & 15;
  if (HASN) {
    for (int c = tid; c < CIN; c += 256) {
      float m = st[c] * invN;
      float var = st[256 + c] * invN - m * m;
      float s = rsqrtf(var + EPS_BN);
      nrm0[c] = s;
      nrm1[c] = m * s;
    }
    __syncthreads();
  }
  int py = 0, px = 0, nx = 1, K = 9 * CIN;
  const ushort* W = WT;
  if (MODE == 1) {
    const int pz = blockIdx.z;
    py = pz >> 1;
    px = pz & 1;
    nx = px ? 2 : 1;
    const int ny = py ? 2 : 1;
    K = ny * nx * CIN;
    const int pre[4] = {0, 1, 3, 5};
    W = WT + (size_t)pre[pz] * CIN * COUT;
  }
  const int gyTM = blockIdx.y * 64;
  const int gxTN = blockIdx.x * TN;

  const int sm = tid & 63, skg = (tid >> 6) * 8;
  int baseNB, baseIY, baseIX;
  {
    const int gm = gyTM + sm;
    if (MODE == 0) {
      const int ni = gm / (OH * OH), r = gm % (OH * OH);
      baseNB = ni * IH * IH;
      baseIY = 2 * (r / OH) - 1;
      baseIX = 2 * (r % OH) - 1;
    } else {
      const int ni = gm / (IH * IH), r = gm % (IH * IH);
      baseNB = ni * IH * IH;
      baseIY = r / IH;
      baseIX = r % IH;
    }
  }
  f32x4 acc[NF];
#pragma unroll
  for (int f = 0; f < NF; ++f) acc[f] = (f32x4){0.f, 0.f, 0.f, 0.f};

  for (int k0 = 0; k0 < K; k0 += 32) {
    const int t = k0 / CIN;
    const int ci0 = k0 - t * CIN;
    int iy, ix;
    if (MODE == 0) {
      iy = baseIY + t / 3;
      ix = baseIX + (t - (t / 3) * 3);
    } else {
      const int kyi = t / nx, kxi = t - (t / nx) * nx;
      iy = baseIY + ((py && kyi == 0) ? 1 : 0);
      ix = baseIX + ((px && kxi == 0) ? 1 : 0);
    }
    {
      const bool ok =
          ((unsigned)iy < (unsigned)IH) && ((unsigned)ix < (unsigned)IH);
      float4 va = make_float4(0.f, 0.f, 0.f, 0.f), vb = va;
      if (ok) {
        const float* xp = &X[((size_t)baseNB + iy * IH + ix) * CIN + ci0 + skg];
        va = *(const float4*)xp;
        vb = *(const float4*)(xp + 4);
        if (HASN) {
          const int c = ci0 + skg;
          va.x = fmaf(va.x, nrm0[c + 0], -nrm1[c + 0]);
          va.y = fmaf(va.y, nrm0[c + 1], -nrm1[c + 1]);
          va.z = fmaf(va.z, nrm0[c + 2], -nrm1[c + 2]);
          va.w = fmaf(va.w, nrm0[c + 3], -nrm1[c + 3]);
          vb.x = fmaf(vb.x, nrm0[c + 4], -nrm1[c + 4]);
          vb.y = fmaf(vb.y, nrm0[c + 5], -nrm1[c + 5]);
          vb.z = fmaf(vb.z, nrm0[c + 6], -nrm1[c + 6]);
          vb.w = fmaf(vb.w, nrm0[c + 7], -nrm1[c + 7]);
        }
      }
      short8 o;
      o[0] = (short)f2bf(va.x); o[1] = (short)f2bf(va.y);
      o[2] = (short)f2bf(va.z); o[3] = (short)f2bf(va.w);
      o[4] = (short)f2bf(vb.x); o[5] = (short)f2bf(vb.y);
      o[6] = (short)f2bf(vb.z); o[7] = (short)f2bf(vb.w);
      *(short8*)&As[sm][skg] = o;
    }
    if (tid < TN * 4) {
      const int bn = tid >> 2, bkg = (tid & 3) * 8;
      *(short8*)&Bs[bn][bkg] =
          *(const short8*)&W[(size_t)(gxTN + bn) * K + k0 + bkg];
    }
    __syncthreads();
    const short8 a = *(const short8*)&As[wv * 16 + ln15][quad * 8];
#pragma unroll
    for (int f = 0; f < NF; ++f) {
      const short8 b = *(const short8*)&Bs[f * 16 + ln15][quad * 8];
      acc[f] = __builtin_amdgcn_mfma_f32_16x16x32_bf16(a, b, acc[f], 0, 0, 0);
    }
    __syncthreads();
  }

  size_t maddr[4];
#pragma unroll
  for (int r = 0; r < 4; ++r) {
    const int m = gyTM + wv * 16 + quad * 4 + r;
    if (MODE == 0) {
      const int ni = m / (OH * OH), rr = m % (OH * OH);
      maddr[r] = (((size_t)ni * OH + rr / OH) * OH + rr % OH) * COUT;
    } else {
      const int ni = m / (IH * IH), rr = m % (IH * IH);
      const int oy = 2 * (rr / IH) + py, ox = 2 * (rr % IH) + px;
      maddr[r] = (((size_t)ni * OH + oy) * OH + ox) * COUT;
    }
  }
#pragma unroll
  for (int f = 0; f < NF; ++f) {
    const int col = gxTN + f * 16 + ln15;
    const float bv = bias[col];
    float cS = 0.f, cQ = 0.f;
#pragma unroll
    for (int r = 0; r < 4; ++r) {
      const float o = lrelu(acc[f][r] + bv);
      cS += o;
      cQ += o * o;
      Y[maddr[r] + col] = o;
    }
    cS += __shfl_down(cS, 32); cS += __shfl_down(cS, 16);
    cQ += __shfl_down(cQ, 32); cQ += __shfl_down(cQ, 16);
    if (lane < 16) { redS[wv][f * 16 + ln15] = cS; redQ[wv][f * 16 + ln15] = cQ; }
  }
  __syncthreads();
  if (tid < TN) {
    float S = redS[0][tid] + redS[1][tid] + redS[2][tid] + redS[3][tid];
    float Q = redQ[0][tid] + redQ[1][tid] + redQ[2][tid] + redQ[3][tid];
    atomicAdd(&stOut[gxTN + tid], S);
    atomicAdd(&stOut[256 + gxTN + tid], Q);
  }
}

// ======================= halo-tile merged convT (COUT=32, CIN<=64) =========
// block = 64-px raster strip. Zero-padded halo tile staged once; all 9 taps'
// weights in LDS; no barriers inside the MFMA loop. Output stored as PACKED
// bf16 (weight columns permuted: slot f*16+ln15 = channel 2*ln15+f, so each
// lane packs its two channels into one dword). INBF: input is bf16 NHWC.
template <int IH, int CIN, bool HASN, bool INBF>
__global__ __launch_bounds__(256) void convt_mfma(
    const float* __restrict__ X, const ushort* __restrict__ WT,
    const float* __restrict__ bias, const float* __restrict__ st, float invN,
    float* __restrict__ Y, float* __restrict__ stOut) {
  constexpr int OH = 2 * IH;
  constexpr int L = (IH == 32) ? 5 : 4;
  constexpr int RSPAN = 64 / IH;
  constexpr int NP = (RSPAN + 1) * (IH + 1);
  constexpr int LK = CIN + 8;
  __shared__ short As[NP][LK];
  __shared__ short Ws[9 * 32][LK];
  __shared__ float nrm0[HASN ? CIN : 4], nrm1[HASN ? CIN : 4];
  __shared__ float redS[4][32], redQ[4][32];
  const int tid = threadIdx.x;
  const int wv = tid >> 6, lane = tid & 63;
  const int quad = lane >> 4, ln15 = lane & 15;
  if (HASN) {
    for (int c = tid; c < CIN; c += 256) {
      float m = st[c] * invN;
      float var = st[256 + c] * invN - m * m;
      float s = rsqrtf(var + EPS_BN);
      nrm0[c] = s;
      nrm1[c] = m * s;
    }
  }
  // weights -> LDS ([t*32+co_slot][ci])
  for (int i = tid; i < 9 * 32 * (CIN / 8); i += 256) {
    const int row = i / (CIN / 8), kg = (i % (CIN / 8)) * 8;
    *(short8*)&Ws[row][kg] = *(const short8*)&WT[(size_t)row * CIN + kg];
  }
  __syncthreads();  // nrm + Ws visible
  const int gy = blockIdx.x * 64;
  const int n = gy / (IH * IH);
  const int r0 = gy - n * (IH * IH);
  const int iy0 = r0 >> L;
  // halo tile -> LDS (normalized bf16, zero-padded)
  for (int i = tid; i < NP * (CIN / 8); i += 256) {
    const int slot = i / (CIN / 8), kg = (i % (CIN / 8)) * 8;
    const int ty = slot / (IH + 1), tx = slot - ty * (IH + 1);
    const int iy = iy0 + ty;
    short8 o = {0, 0, 0, 0, 0, 0, 0, 0};
    if (iy < IH && tx < IH) {
      float v[8];
      if constexpr (INBF) {
        const ushort* xp =
            (const ushort*)X + (((size_t)n * IH + iy) * IH + tx) * CIN + kg;
        const short8 raw = *(const short8*)xp;
#pragma unroll
        for (int u = 0; u < 8; ++u) v[u] = bf2f((ushort)raw[u]);
      } else {
        const float* xp = &X[(((size_t)n * IH + iy) * IH + tx) * CIN + kg];
        const float4 va = *(const float4*)xp, vb = *(const float4*)(xp + 4);
        v[0] = va.x; v[1] = va.y; v[2] = va.z; v[3] = va.w;
        v[4] = vb.x; v[5] = vb.y; v[6] = vb.z; v[7] = vb.w;
      }
      if (HASN) {
#pragma unroll
        for (int u = 0; u < 8; ++u) v[u] = fmaf(v[u], nrm0[kg + u], -nrm1[kg + u]);
      }
#pragma unroll
      for (int u = 0; u < 8; ++u) o[u] = (short)f2bf(v[u]);
    }
    *(short8*)&As[slot][kg] = o;
  }
  __syncthreads();

  const int rA = wv * 16 + ln15;
  const int baseIdx = (rA >> L) * (IH + 1) + (rA & (IH - 1));
  f32x4 acc[4][2];
#pragma unroll
  for (int p = 0; p < 4; ++p)
#pragma unroll
    for (int f = 0; f < 2; ++f) acc[p][f] = (f32x4){0.f, 0.f, 0.f, 0.f};

  constexpr int NT[4] = {4, 2, 2, 1};
  constexpr int TT[4][4] = {{4, 5, 7, 8}, {3, 6, 0, 0}, {1, 2, 0, 0}, {0, 0, 0, 0}};
#pragma unroll
  for (int s = 0; s < 4; ++s) {
    const int off = (s >> 1) * (IH + 1) + (s & 1);
#pragma unroll
    for (int j = 0; j < NT[s]; ++j) {
      const int t = TT[s][j];
      const int ky = t / 3, kx = t - ky * 3;
      const int par = ((ky == 1) ? 0 : 2) + ((kx == 1) ? 0 : 1);
#pragma unroll
      for (int ks = 0; ks < CIN / 32; ++ks) {
        const short8 a =
            *(const short8*)&As[baseIdx + off][ks * 32 + quad * 8];
#pragma unroll
        for (int f = 0; f < 2; ++f) {
          const short8 b =
              *(const short8*)&Ws[t * 32 + f * 16 + ln15][ks * 32 + quad * 8];
          acc[par][f] =
              __builtin_amdgcn_mfma_f32_16x16x32_bf16(a, b, acc[par][f], 0, 0, 0);
        }
      }
    }
  }

  // epilogue: lane owns channels 2*ln15 (f=0) and 2*ln15+1 (f=1) -> one
  // packed-bf16 dword store per output pixel per lane.
  const float bv0 = bias[2 * ln15], bv1 = bias[2 * ln15 + 1];
  unsigned* Yp = (unsigned*)Y;
  float cS[2] = {0.f, 0.f}, cQ[2] = {0.f, 0.f};
#pragma unroll
  for (int i = 0; i < 4; ++i) {
    const int rD = wv * 16 + quad * 4 + i;
    const int ry = rD >> L, rx = rD & (IH - 1);
    const int iy = iy0 + ry;
#pragma unroll
    for (int p = 0; p < 4; ++p) {
      const int a = p >> 1, b = p & 1;
      const size_t base = (((size_t)n * OH + 2 * iy + a) * OH + 2 * rx + b) * 32;
      const float o0 = lrelu(acc[p][0][i] + bv0);
      const float o1 = lrelu(acc[p][1][i] + bv1);
      cS[0] += o0; cQ[0] += o0 * o0;
      cS[1] += o1; cQ[1] += o1 * o1;
      Yp[(base >> 1) + ln15] = (unsigned)f2bf(o0) | ((unsigned)f2bf(o1) << 16);
    }
  }
#pragma unroll
  for (int f = 0; f < 2; ++f) {
    float s_ = cS[f], q_ = cQ[f];
    s_ += __shfl_down(s_, 32); s_ += __shfl_down(s_, 16);
    q_ += __shfl_down(q_, 32); q_ += __shfl_down(q_, 16);
    if (lane < 16) { redS[wv][f * 16 + ln15] = s_; redQ[wv][f * 16 + ln15] = q_; }
  }
  __syncthreads();
  if (tid < 32) {
    float S = redS[0][tid] + redS[1][tid] + redS[2][tid] + redS[3][tid];
    float Q = redQ[0][tid] + redQ[1][tid] + redQ[2][tid] + redQ[3][tid];
    const int ch = ((tid & 15) << 1) | (tid >> 4);  // slot -> actual channel
    atomicAdd(&stOut[ch], S);
    atomicAdd(&stOut[256 + ch], Q);
  }
}

// ======================= conv1 (CIN=3), NCHW in -> NHWC out ================
__global__ __launch_bounds__(256) void conv1(
    const float* __restrict__ x, const float* __restrict__ w,
    const float* __restrict__ bias, float* __restrict__ y,
    float* __restrict__ st) {
  __shared__ float lw[4 * 3 * 12];
  __shared__ float red[2][4][4];
  const int tid = threadIdx.x;
  const int cog = blockIdx.y * 4;
  for (int i = tid; i < 4 * 27; i += 256) {
    int cor = i / 27, rem = i % 27;
    lw[(cor * 3 + rem / 9) * 12 + rem % 9] = w[cog * 27 + i];
  }
  __syncthreads();
  const int idx = blockIdx.x * 256 + tid;
  const int q = idx & 255;
  const int n = idx >> 8;
  const int qy = q >> 4, qx = q & 15;
  const int iy0 = 4 * qy - 1, ix0 = 4 * qx - 1;
  const float* xn = x + (size_t)n * 3 * 4096;
  bool okr[5], okc[5];
#pragma unroll
  for (int r = 0; r < 5; ++r) okr[r] = (unsigned)(iy0 + r) < 64u;
#pragma unroll
  for (int c = 0; c < 5; ++c) okc[c] = (unsigned)(ix0 + c) < 64u;

  float acc[4][4];
#pragma unroll
  for (int j = 0; j < 4; ++j) {
    const float b = bias[cog + j];
#pragma unroll
    for (int p = 0; p < 4; ++p) acc[j][p] = b;
  }
#pragma unroll
  for (int ci = 0; ci < 3; ++ci) {
    const float* xp = xn + ci * 4096;
    float v[5][5];
#pragma unroll
    for (int r = 0; r < 5; ++r)
#pragma unroll
      for (int c = 0; c < 5; ++c)
        v[r][c] = (okr[r] && okc[c]) ? xp[(iy0 + r) * 64 + ix0 + c] : 0.f;
#pragma unroll
    for (int j = 0; j < 4; ++j) {
      const float* wj = &lw[(j * 3 + ci) * 12];
#pragma unroll
      for (int dy = 0; dy < 2; ++dy)
#pragma unroll
        for (int dx = 0; dx < 2; ++dx)
#pragma unroll
          for (int ky = 0; ky < 3; ++ky)
#pragma unroll
            for (int kx = 0; kx < 3; ++kx)
              acc[j][dy * 2 + dx] = fmaf(v[2 * dy + ky][2 * dx + kx],
                                         wj[ky * 3 + kx], acc[j][dy * 2 + dx]);
    }
  }
  const int wv = tid >> 6, ln = tid & 63;
  float sS[4], sQ[4];
#pragma unroll
  for (int j = 0; j < 4; ++j) { sS[j] = 0.f; sQ[j] = 0.f; }
#pragma unroll
  for (int dy = 0; dy < 2; ++dy)
#pragma unroll
    for (int dx = 0; dx < 2; ++dx) {
      float4 o;
      o.x = lrelu(acc[0][dy * 2 + dx]);
      o.y = lrelu(acc[1][dy * 2 + dx]);
      o.z = lrelu(acc[2][dy * 2 + dx]);
      o.w = lrelu(acc[3][dy * 2 + dx]);
      *(float4*)&y[(((size_t)n * 32 + 2 * qy + dy) * 32 + 2 * qx + dx) * 32 +
                   cog] = o;
      sS[0] += o.x; sS[1] += o.y; sS[2] += o.z; sS[3] += o.w;
      sQ[0] += o.x * o.x; sQ[1] += o.y * o.y;
      sQ[2] += o.z * o.z; sQ[3] += o.w * o.w;
    }
#pragma unroll
  for (int j = 0; j < 4; ++j) {
    float s_ = sS[j], q_ = sQ[j];
#pragma unroll
    for (int off = 32; off > 0; off >>= 1) {
      s_ += __shfl_down(s_, off);
      q_ += __shfl_down(q_, off);
    }
    if (ln == 0) { red[0][wv][j] = s_; red[1][wv][j] = q_; }
  }
  __syncthreads();
  if (tid < 4) {
    const int j = tid;
    float S = red[0][0][j] + red[0][1][j] + red[0][2][j] + red[0][3][j];
    float Q = red[1][0][j] + red[1][1][j] + red[1][2][j] + red[1][3][j];
    atomicAdd(&st[cog + j], S);
    atomicAdd(&st[256 + cog + j], Q);
  }
}

// ======================= final convT 3x3 s1 p1 + tanh, LDS-tiled ===========
// input x is bf16 NHWC [256,64,64,32]
__global__ __launch_bounds__(256) void convt4_tanh(
    const float* __restrict__ x, const float* __restrict__ w,
    const float* __restrict__ bias, const float* __restrict__ st, float invN,
    float* __restrict__ out) {
  __shared__ float tile[324 * 36];
  __shared__ float s0[32], s1[32];
  const int tid = threadIdx.x;
  for (int c = tid; c < 32; c += 256) {
    float m = st[c] * invN;
    float var = st[256 + c] * invN - m * m;
    float s = rsqrtf(var + EPS_BN);
    s0[c] = s;
    s1[c] = m * s;
  }
  __syncthreads();
  const int n = blockIdx.x >> 4;
  const int t16 = blockIdx.x & 15;
  const int oy0 = (t16 >> 2) * 16, ox0 = (t16 & 3) * 16;
  const ushort* xn = (const ushort*)x + (size_t)n * 131072;
  for (int j = tid; j < 2592; j += 256) {
    const int px = j >> 3, cq = (j & 7) * 4;
    const int r = px / 18, c = px - r * 18;
    const int gy = oy0 - 1 + r, gx = ox0 - 1 + c;
    float4 v = make_float4(0.f, 0.f, 0.f, 0.f);
    if ((unsigned)gy < 64u && (unsigned)gx < 64u) {
      const us4 rv = *(const us4*)&xn[(((size_t)gy << 6) + gx) * 32 + cq];
      v.x = fmaf(bf2f(rv[0]), s0[cq + 0], -s1[cq + 0]);
      v.y = fmaf(bf2f(rv[1]), s0[cq + 1], -s1[cq + 1]);
      v.z = fmaf(bf2f(rv[2]), s0[cq + 2], -s1[cq + 2]);
      v.w = fmaf(bf2f(rv[3]), s0[cq + 3], -s1[cq + 3]);
    }
    *(float4*)&tile[px * 36 + cq] = v;
  }
  __syncthreads();
  const int py = tid >> 4, pxx = tid & 15;
  float acc0 = bias[0], acc1 = bias[1], acc2 = bias[2];
  for (int cb4 = 0; cb4 < 8; ++cb4) {
    float4 wv[27];
    const float4* wp = (const float4*)(w + cb4 * 108);
#pragma unroll
    for (int q = 0; q < 27; ++q) wv[q] = wp[q];
    const float* wr = (const float*)wv;
#pragma unroll
    for (int ky = 0; ky < 3; ++ky)
#pragma unroll
      for (int kx = 0; kx < 3; ++kx) {
        const float4 v = *(const float4*)
            &tile[((py + 2 - ky) * 18 + (pxx + 2 - kx)) * 36 + cb4 * 4];
        const int tt = ky * 3 + kx;
#pragma unroll
        for (int u = 0; u < 4; ++u) {
          const float vi = (&v.x)[u];
          acc0 = fmaf(vi, wr[u * 27 + tt], acc0);
          acc1 = fmaf(vi, wr[u * 27 + 9 + tt], acc1);
          acc2 = fmaf(vi, wr[u * 27 + 18 + tt], acc2);
        }
      }
  }
  const int oy = oy0 + py, ox = ox0 + pxx;
  float* op = out + (size_t)n * 3 * 4096 + oy * 64 + ox;
  op[0] = 1.f / (1.f + __expf(-2.f * acc0));
  op[4096] = 1.f / (1.f + __expf(-2.f * acc1));
  op[8192] = 1.f / (1.f + __expf(-2.f * acc2));
}

// ======================= dense GEMM (fc / VQ distance), fp32 ===============
__global__ __launch_bounds__(256) void gemm_abt(
    const float* __restrict__ A, const float* __restrict__ B,
    const float* __restrict__ bias, const float* __restrict__ stA, float invN,
    float* __restrict__ C, float* __restrict__ P, int K, int ldc, int col0,
    float alpha, int act) {
  __shared__ float As[16][68];
  __shared__ float Bsh[16][68];
  __shared__ float nrm[2][256];
  const int tid = threadIdx.x;
  if (stA) {
    const int c = tid;
    float m = stA[c] * invN;
    float var = stA[256 + c] * invN - m * m;
    float s = rsqrtf(var + EPS_BN);
    nrm[0][c] = s;
    nrm[1][c] = m * s;
    __syncthreads();
  }
  const int lm = tid >> 2, lk = (tid & 3) << 2;
  const int KS = gridDim.z;
  const int kChunk = K / KS;
  const int kStart = blockIdx.z * kChunk;
  const float* Arow = A + (size_t)(blockIdx.y * 64 + lm) * K + lk;
  const float* Brow = B + (size_t)(blockIdx.x * 64 + lm) * K + lk;
  float acc[4][4] = {};
  const int m0 = (tid >> 4) << 2, n0 = (tid & 15) << 2;

  for (int k0 = kStart; k0 < kStart + kChunk; k0 += 16) {
    float4 av = *(const float4*)(Arow + k0);
    float4 bv = *(const float4*)(Brow + k0);
    if (stA) {
      const int ch = (k0 + lk) >> 4;
      const float s = nrm[0][ch], ms = nrm[1][ch];
      av.x = fmaf(av.x, s, -ms);
      av.y = fmaf(av.y, s, -ms);
      av.z = fmaf(av.z, s, -ms);
      av.w = fmaf(av.w, s, -ms);
    }
    As[lk + 0][lm] = av.x; As[lk + 1][lm] = av.y;
    As[lk + 2][lm] = av.z; As[lk + 3][lm] = av.w;
    Bsh[lk + 0][lm] = bv.x; Bsh[lk + 1][lm] = bv.y;
    Bsh[lk + 2][lm] = bv.z; Bsh[lk + 3][lm] = bv.w;
    __syncthreads();
#pragma unroll
    for (int kk = 0; kk < 16; ++kk) {
      const float4 a = *(const float4*)&As[kk][m0];
      const float4 b = *(const float4*)&Bsh[kk][n0];
      acc[0][0] = fmaf(a.x, b.x, acc[0][0]); acc[0][1] = fmaf(a.x, b.y, acc[0][1]);
      acc[0][2] = fmaf(a.x, b.z, acc[0][2]); acc[0][3] = fmaf(a.x, b.w, acc[0][3]);
      acc[1][0] = fmaf(a.y, b.x, acc[1][0]); acc[1][1] = fmaf(a.y, b.y, acc[1][1]);
      acc[1][2] = fmaf(a.y, b.z, acc[1][2]); acc[1][3] = fmaf(a.y, b.w, acc[1][3]);
      acc[2][0] = fmaf(a.z, b.x, acc[2][0]); acc[2][1] = fmaf(a.z, b.y, acc[2][1]);
      acc[2][2] = fmaf(a.z, b.z, acc[2][2]); acc[2][3] = fmaf(a.z, b.w, acc[2][3]);
      acc[3][0] = fmaf(a.w, b.x, acc[3][0]); acc[3][1] = fmaf(a.w, b.y, acc[3][1]);
      acc[3][2] = fmaf(a.w, b.z, acc[3][2]); acc[3][3] = fmaf(a.w, b.w, acc[3][3]);
    }
    __syncthreads();
  }

  const int gm = blockIdx.y * 64 + m0;
  const int gn = blockIdx.x * 64 + n0;
  if (KS == 1) {
#pragma unroll
    for (int i = 0; i < 4; ++i) {
      float4 o;
      o.x = alpha * acc[i][0] + bias[gn + 0];
      o.y = alpha * acc[i][1] + bias[gn + 1];
      o.z = alpha * acc[i][2] + bias[gn + 2];
      o.w = alpha * acc[i][3] + bias[gn + 3];
      if (act == 1) {
        o.x = fmaxf(o.x, 0.f); o.y = fmaxf(o.y, 0.f);
        o.z = fmaxf(o.z, 0.f); o.w = fmaxf(o.w, 0.f);
      }
      *(float4*)&C[(size_t)(gm + i) * ldc + col0 + gn] = o;
    }
  } else {
    const int M = gridDim.y * 64, N = gridDim.x * 64;
#pragma unroll
    for (int i = 0; i < 4; ++i)
      *(float4*)&P[((size_t)blockIdx.z * M + gm + i) * N + gn] =
          make_float4(acc[i][0], acc[i][1], acc[i][2], acc[i][3]);
  }
}

__global__ __launch_bounds__(256) void gemm_reduce(
    const float* __restrict__ P, float* __restrict__ C,
    const float* __restrict__ bias, int M, int N, int ldc, int col0,
    float alpha, int act, int KS) {
  const int idx = blockIdx.x * 256 + threadIdx.x;
  if (idx >= M * N) return;
  const int m = idx / N, n = idx % N;
  float s = 0.f;
  for (int z = 0; z < KS; ++z) s += P[((size_t)z * M + m) * N + n];
  float v = alpha * s + bias[n];
  if (act == 1) v = fmaxf(v, 0.f);
  C[(size_t)m * ldc + col0 + n] = v;
}

// ======================= VQ =================================================
__global__ __launch_bounds__(256) void rowsq(const float* __restrict__ cb,
                                             float* __restrict__ csq) {
  const int row = blockIdx.x * 4 + (threadIdx.x >> 6);
  const int ln = threadIdx.x & 63;
  const float4 v = ((const float4*)(cb + (size_t)row * 256))[ln];
  float s = v.x * v.x + v.y * v.y + v.z * v.z + v.w * v.w;
#pragma unroll
  for (int off = 32; off > 0; off >>= 1) s += __shfl_down(s, off);
  if (ln == 0) csq[row] = s;
}

__global__ __launch_bounds__(256) void argmin_d2(const float* __restrict__ d2,
                                                 int* __restrict__ idx) {
  const int b = blockIdx.x, t = threadIdx.x;
  const float* row = d2 + (size_t)b * 8192;
  float best = 3.4e38f;
  int bi = 0x7fffffff;
  for (int k = t; k < 8192; k += 256) {
    const float v = row[k];
    if (v < best) { best = v; bi = k; }
  }
  __shared__ float bval[256];
  __shared__ int bidx[256];
  bval[t] = best;
  bidx[t] = bi;
  __syncthreads();
  for (int s = 128; s > 0; s >>= 1) {
    if (t < s) {
      const float ov = bval[t + s];
      const int oi = bidx[t + s];
      if (ov < bval[t] || (ov == bval[t] && oi < bidx[t])) {
        bval[t] = ov;
        bidx[t] = oi;
      }
    }
    __syncthreads();
  }
  if (t == 0) idx[b] = bidx[0];
}

__global__ __launch_bounds__(256) void vq_gather_loss(
    const float* __restrict__ ze, const float* __restrict__ cb,
    const int* __restrict__ idx, float* __restrict__ zq,
    float* __restrict__ lossacc) {
  const int b = blockIdx.x, d = threadIdx.x;
  const int i = b * 256 + d;
  const float q = cb[(size_t)idx[b] * 256 + d];
  zq[i] = q;
  const float df = ze[i] - q;
  float v = df * df;
  __shared__ float sh[256];
  sh[d] = v;
  __syncthreads();
  for (int s = 128; s > 0; s >>= 1) {
    if (d < s) sh[d] += sh[d + s];
    __syncthreads();
  }
  if (d == 0) atomicAdd(lossacc, sh[0]);
}

__global__ void write_loss(const float* __restrict__ lossacc,
                           float* __restrict__ out) {
  out[0] = 2.f * lossacc[0];
}

// ---------------------------------------------------------------------------
extern "C" void kernel_launch(void* const* d_in, const int* in_sizes, int n_in,
                              void* d_out, int out_size, void* d_ws,
                              size_t ws_size, hipStream_t stream) {
  const float* x = (const float*)d_in[0];
  const float* ew1 = (const float*)d_in[1];
  const float* eb1 = (const float*)d_in[2];
  const float* ew2 = (const float*)d_in[3];
  const float* eb2 = (const float*)d_in[4];
  const float* ew3 = (const float*)d_in[5];
  const float* eb3 = (const float*)d_in[6];
  const float* ew4 = (const float*)d_in[7];
  const float* eb4 = (const float*)d_in[8];
  const float* wmu = (const float*)d_in[9];
  const float* bmu = (const float*)d_in[10];
  const float* wcov = (const float*)d_in[11];
  const float* bcov = (const float*)d_in[12];
  const float* cb = (const float*)d_in[13];
  const float* wfc = (const float*)d_in[14];
  const float* bfc = (const float*)d_in[15];
  const float* wt1 = (const float*)d_in[16];
  const float* bt1 = (const float*)d_in[17];
  const float* wt2 = (const float*)d_in[18];
  const float* bt2 = (const float*)d_in[19];
  const float* wt3 = (const float*)d_in[20];
  const float* bt3 = (const float*)d_in[21];
  const float* wt31 = (const float*)d_in[22];
  const float* bt31 = (const float*)d_in[23];
  const float* wt4 = (const float*)d_in[24];
  const float* bt4 = (const float*)d_in[25];

  float* ws = (float*)d_ws;
  float* a1 = ws;               // NHWC [256,32,32,32]  (reused as g3, bf16)
  float* a2 = a1 + 8388608;     // NHWC [256,16,16,64]  (reused as g2)
  float* a3 = a2 + 4194304;     // NHWC [256,8,8,128]   (reused as g1)
  float* a4 = a3 + 2097152;     // NHWC [256,4,4,256]   (reused as g0)
  float* g31 = a4 + 1048576;    // NHWC [256,64,64,32] bf16 (region 33554432 f)
  float* d2 = g31;              // [256,8192]
  float* P = g31 + 2097152;     // 262144
  float* csq = g31 + 2359296;   // 8192
  float* a4n = g31 + 2367488;   // NCHW a4 copy
  float* wfcT = g31 + 3416064;  // 1048576
  float* bfcT = g31 + 4464640;  // 4096
  ushort* wTc2 = (ushort*)(g31 + 4468736);  // 18432 bf16
  ushort* wTc3 = (ushort*)(g31 + 4487168);  // 73728 bf16
  ushort* wTc4 = (ushort*)(g31 + 4560896);  // 294912 bf16
  float* ze = g31 + 33554432;   // [256,256]
  float* zq = ze + 65536;
  float* stats = zq + 65536;    // 8 layers x 512
  float* lossacc = stats + 4096;
  int* idx = (int*)(lossacc + 4);
  ushort* wTt1 = (ushort*)(lossacc + 4 + 256);  // 294912 bf16 (parity)
  ushort* wTt2 = wTt1 + 294912;                 // 73728 bf16 (parity)
  ushort* wTt3 = wTt2 + 73728;                  // 18432 bf16 (tap-major,perm)
  ushort* wTt31 = wTt3 + 18432;                 // 9216 bf16 (tap-major,perm)
  float* g3 = a1;   // bf16 content
  float* g2 = a2;
  float* g1 = a3;
  float* g0 = a4;

  float* st0 = stats + 0 * 512;
  float* st1 = stats + 1 * 512;
  float* st2 = stats + 2 * 512;
  float* st3 = stats + 3 * 512;
  float* st4 = stats + 4 * 512;
  float* st5 = stats + 5 * 512;
  float* st6 = stats + 6 * 512;
  float* st7 = stats + 7 * 512;

  hipMemsetAsync(stats, 0, (4096 + 8) * sizeof(float), stream);

  // ---- weight transposes (bf16) ----
  tr_convw_bf<<<72, 256, 0, stream>>>(ew2, wTc2, 32, 64, 18432);
  tr_convw_bf<<<288, 256, 0, stream>>>(ew3, wTc3, 64, 128, 73728);
  tr_convw_bf<<<1152, 256, 0, stream>>>(ew4, wTc4, 128, 256, 294912);
  tr_convtw_bf<<<1152, 256, 0, stream>>>(wt1, wTt1, 256, 128, 294912);
  tr_convtw_bf<<<288, 256, 0, stream>>>(wt2, wTt2, 128, 64, 73728);
  tr_convtw_tc<<<72, 256, 0, stream>>>(wt3, wTt3, 64, 32, 18432);
  tr_convtw_tc<<<36, 256, 0, stream>>>(wt31, wTt31, 32, 32, 9216);
  tr_fcdec<<<4096, 256, 0, stream>>>(wfc, bfc, wfcT, bfcT);
  rowsq<<<2048, 256, 0, stream>>>(cb, csq);

  // ---- encoder ----
  conv1<<<dim3(256, 8), 256, 0, stream>>>(x, ew1, eb1, a1, st0);
  mfmaconv<64, 0, 32, 32, 64, true><<<dim3(1, 1024), 256, 0, stream>>>(
      a1, wTc2, eb2, st0, 1.f / (256.f * 1024.f), a2, st1);
  mfmaconv<64, 0, 16, 64, 128, true><<<dim3(2, 256), 256, 0, stream>>>(
      a2, wTc3, eb3, st1, 1.f / (256.f * 256.f), a3, st2);
  mfmaconv<64, 0, 8, 128, 256, true><<<dim3(4, 64), 256, 0, stream>>>(
      a3, wTc4, eb4, st2, 1.f / (256.f * 64.f), a4, st3);
  tr_a4<<<4096, 256, 0, stream>>>(a4, a4n);

  // ---- encoder FC (fp32) ----
  gemm_abt<<<dim3(2, 4, 8), 256, 0, stream>>>(a4n, wmu, nullptr, st3,
                                              1.f / 4096.f, nullptr, P, 4096,
                                              0, 0, 1.f, 0);
  gemm_reduce<<<128, 256, 0, stream>>>(P, ze, bmu, 256, 128, 256, 0, 1.f, 0, 8);
  gemm_abt<<<dim3(2, 4, 8), 256, 0, stream>>>(a4n, wcov, nullptr, st3,
                                              1.f / 4096.f, nullptr, P, 4096,
                                              0, 0, 1.f, 0);
  gemm_reduce<<<128, 256, 0, stream>>>(P, ze, bcov, 256, 128, 256, 128, 1.f, 1, 8);

  // ---- VQ (fp32) ----
  gemm_abt<<<dim3(128, 4, 1), 256, 0, stream>>>(ze, cb, csq, nullptr, 0.f, d2,
                                                nullptr, 256, 8192, 0, -2.f, 0);
  argmin_d2<<<256, 256, 0, stream>>>(d2, idx);
  vq_gather_loss<<<256, 256, 0, stream>>>(ze, cb, idx, zq, lossacc);

  // ---- decoder FC (fp32) ----
  gemm_abt<<<dim3(64, 4, 1), 256, 0, stream>>>(zq, wfcT, bfcT, nullptr, 0.f,
                                               g0, nullptr, 256, 4096, 0, 1.f, 0);

  // ---- decoder ----
  mfmaconv<64, 1, 4, 256, 128, false><<<dim3(2, 64, 4), 256, 0, stream>>>(
      g0, wTt1, bt1, nullptr, 0.f, g1, st4);
  mfmaconv<64, 1, 8, 128, 64, true><<<dim3(1, 256, 4), 256, 0, stream>>>(
      g1, wTt2, bt2, st4, 1.f / (256.f * 64.f), g2, st5);
  convt_mfma<16, 64, true, false><<<1024, 256, 0, stream>>>(
      g2, wTt3, bt3, st5, 1.f / (256.f * 256.f), g3, st6);
  convt_mfma<32, 32, true, true><<<4096, 256, 0, stream>>>(
      g3, wTt31, bt31, st6, 1.f / (256.f * 1024.f), g31, st7);

  convt4_tanh<<<4096, 256, 0, stream>>>(g31, wt4, bt4, st7,
                                        1.f / (256.f * 4096.f), (float*)d_out);
  write_loss<<<1, 1, 0, stream>>>(lossacc, (float*)d_out + 3145728);
}

// Round 2
// 591.622 us; speedup vs baseline: 1.0613x; 1.0518x over previous
//
#include <hip/hip_runtime.h>
#include <cmath>

// ---------------------------------------------------------------------------
// VQ-VAE forward. B=256, C=3, HW=64, D=256, K=8192, LAT=128
// R10: convt_mfma becomes a multi-strip software pipeline. Each block owns
// NSTRIP consecutive 64-px strips of one image: weights staged ONCE, halo
// tiles double-buffered in LDS, strip s+1's global loads issued before the
// MFMAs of strip s (async-STAGE split), LDS-write after. t31: NSTRIP=4 ->
// 1024 blocks, 40KB LDS, whole grid co-resident (4 blk/CU). t3: NSTRIP=2 ->
// 512 blocks (2 blk/CU). Stats accumulate in regs across strips (atomics /N).
// Decoder tail stays packed bf16 (R9). conv2-4,t1,t2 parity mfmaconv.
// ---------------------------------------------------------------------------

#define EPS_BN 1e-5f
typedef unsigned short ushort;
typedef short short8 __attribute__((ext_vector_type(8)));
typedef ushort us4 __attribute__((ext_vector_type(4)));
typedef float f32x4 __attribute__((ext_vector_type(4)));

__device__ __forceinline__ float lrelu(float v) { return v >= 0.f ? v : 0.01f * v; }
__device__ __forceinline__ ushort f2bf(float f) {
  unsigned u = __float_as_uint(f);
  return (ushort)((u + 0x7FFF + ((u >> 16) & 1)) >> 16);
}
__device__ __forceinline__ float bf2f(ushort u) {
  return __uint_as_float(((unsigned)u) << 16);
}

// ======================= weight transposes (once per launch) ===============
// conv (COUT,CIN,3,3) -> bf16 [co][t*CIN+ci]
__global__ __launch_bounds__(256) void tr_convw_bf(const float* __restrict__ w,
                                                   ushort* __restrict__ wT,
                                                   int CIN, int COUT, int total) {
  int i = blockIdx.x * 256 + threadIdx.x;
  if (i >= total) return;
  int co = i / (9 * CIN);
  int r = i - co * 9 * CIN;
  int t = r / CIN, ci = r - t * CIN;
  wT[i] = f2bf(w[((size_t)co * CIN + ci) * 9 + t]);
}

// convT (CIN,COUT,3,3) -> bf16 parity-concat [p][co][k]
__global__ __launch_bounds__(256) void tr_convtw_bf(const float* __restrict__ w,
                                                    ushort* __restrict__ wT,
                                                    int CIN, int COUT, int total) {
  int i = blockIdx.x * 256 + threadIdx.x;
  if (i >= total) return;
  const int cc = CIN * COUT;
  int p, base, Kp;
  if (i < cc) { p = 0; base = 0; Kp = CIN; }
  else if (i < 3 * cc) { p = 1; base = cc; Kp = 2 * CIN; }
  else if (i < 5 * cc) { p = 2; base = 3 * cc; Kp = 2 * CIN; }
  else { p = 3; base = 5 * cc; Kp = 4 * CIN; }
  const int r = i - base;
  const int co = r / Kp;
  const int q = r - co * Kp;
  const int tix = q / CIN, ci = q - (q / CIN) * CIN;
  const int py = p >> 1, px = p & 1;
  const int nx = px ? 2 : 1;
  const int kyi = tix / nx, kxi = tix - kyi * nx;
  const int ky = py ? (kyi == 0 ? 0 : 2) : 1;
  const int kx = px ? (kxi == 0 ? 0 : 2) : 1;
  wT[i] = f2bf(w[((size_t)ci * COUT + co) * 9 + ky * 3 + kx]);
}

// convT (CIN,COUT=32,3,3) -> bf16 [t][co_slot][ci] (tap-major, columns
// PERMUTED so slot f*16+ln15 holds channel 2*ln15+f -> packed bf16 stores)
__global__ __launch_bounds__(256) void tr_convtw_tc(const float* __restrict__ w,
                                                    ushort* __restrict__ wT,
                                                    int CIN, int COUT, int total) {
  int i = blockIdx.x * 256 + threadIdx.x;
  if (i >= total) return;
  int ci = i % CIN;
  int tmp = i / CIN;
  int co = tmp % COUT;
  int t = tmp / COUT;
  const int co_slot = ((co & 1) << 4) | (co >> 1);
  wT[((size_t)t * COUT + co_slot) * CIN + ci] =
      f2bf(w[((size_t)ci * COUT + co) * 9 + t]);
}

// a4 NHWC [256,4,4,256] -> NCHW [256,256,4,4]
__global__ __launch_bounds__(256) void tr_a4(const float* __restrict__ in,
                                             float* __restrict__ out) {
  int i = blockIdx.x * 256 + threadIdx.x;
  int n = i >> 12, k = i & 4095;
  out[i] = in[(size_t)(n << 12) + ((k & 15) << 8) + (k >> 4)];
}

// wfc [4096,256] + bfc: permute ROWS from (c,y,x) to (y,x,c)
__global__ __launch_bounds__(256) void tr_fcdec(const float* __restrict__ in,
                                                const float* __restrict__ bin,
                                                float* __restrict__ out,
                                                float* __restrict__ bout) {
  int i = blockIdx.x * 256 + threadIdx.x;
  int k = i >> 8, d = i & 255;
  int kp = (k & 15) * 256 + (k >> 4);
  out[(size_t)kp * 256 + d] = in[i];
  if (d == 0) bout[kp] = bin[k];
}

// ======================= bf16 MFMA implicit-GEMM conv / convT ==============
template <int TN, int MODE, int IH, int CIN, int COUT, bool HASN>
__global__ __launch_bounds__(256) void mfmaconv(
    const float* __restrict__ X, const ushort* __restrict__ WT,
    const float* __restrict__ bias, const float* __restrict__ st, float invN,
    float* __restrict__ Y, float* __restrict__ stOut) {
  constexpr int OH = (MODE == 0) ? IH / 2 : 2 * IH;
  constexpr int NF = TN / 16;
  __shared__ short As[64][40];
  __shared__ short Bs[TN][40];
  __shared__ float nrm0[HASN ? CIN : 4], nrm1[HASN ? CIN : 4];
  __shared__ float redS[4][TN], redQ[4][TN];
  const int tid = threadIdx.x;
  const int wv = tid >> 6, lane = tid & 63;
  const int quad = lane >> 4, ln15 = tid & 15;
  if (HASN) {
    for (int c = tid; c < CIN; c += 256) {
      float m = st[c] * invN;
      float var = st[256 + c] * invN - m * m;
      float s = rsqrtf(var + EPS_BN);
      nrm0[c] = s;
      nrm1[c] = m * s;
    }
    __syncthreads();
  }
  int py = 0, px = 0, nx = 1, K = 9 * CIN;
  const ushort* W = WT;
  if (MODE == 1) {
    const int pz = blockIdx.z;
    py = pz >> 1;
    px = pz & 1;
    nx = px ? 2 : 1;
    const int ny = py ? 2 : 1;
    K = ny * nx * CIN;
    const int pre[4] = {0, 1, 3, 5};
    W = WT + (size_t)pre[pz] * CIN * COUT;
  }
  const int gyTM = blockIdx.y * 64;
  const int gxTN = blockIdx.x * TN;

  const int sm = tid & 63, skg = (tid >> 6) * 8;
  int baseNB, baseIY, baseIX;
  {
    const int gm = gyTM + sm;
    if (MODE == 0) {
      const int ni = gm / (OH * OH), r = gm % (OH * OH);
      baseNB = ni * IH * IH;
      baseIY = 2 * (r / OH) - 1;
      baseIX = 2 * (r % OH) - 1;
    } else {
      const int ni = gm / (IH * IH), r = gm % (IH * IH);
      baseNB = ni * IH * IH;
      baseIY = r / IH;
      baseIX = r % IH;
    }
  }
  f32x4 acc[NF];
#pragma unroll
  for (int f = 0; f < NF; ++f) acc[f] = (f32x4){0.f, 0.f, 0.f, 0.f};

  for (int k0 = 0; k0 < K; k0 += 32) {
    const int t = k0 / CIN;
    const int ci0 = k0 - t * CIN;
    int iy, ix;
    if (MODE == 0) {
      iy = baseIY + t / 3;
      ix = baseIX + (t - (t / 3) * 3);
    } else {
      const int kyi = t / nx, kxi = t - (t / nx) * nx;
      iy = baseIY + ((py && kyi == 0) ? 1 : 0);
      ix = baseIX + ((px && kxi == 0) ? 1 : 0);
    }
    {
      const bool ok =
          ((unsigned)iy < (unsigned)IH) && ((unsigned)ix < (unsigned)IH);
      float4 va = make_float4(0.f, 0.f, 0.f, 0.f), vb = va;
      if (ok) {
        const float* xp = &X[((size_t)baseNB + iy * IH + ix) * CIN + ci0 + skg];
        va = *(const float4*)xp;
        vb = *(const float4*)(xp + 4);
        if (HASN) {
          const int c = ci0 + skg;
          va.x = fmaf(va.x, nrm0[c + 0], -nrm1[c + 0]);
          va.y = fmaf(va.y, nrm0[c + 1], -nrm1[c + 1]);
          va.z = fmaf(va.z, nrm0[c + 2], -nrm1[c + 2]);
          va.w = fmaf(va.w, nrm0[c + 3], -nrm1[c + 3]);
          vb.x = fmaf(vb.x, nrm0[c + 4], -nrm1[c + 4]);
          vb.y = fmaf(vb.y, nrm0[c + 5], -nrm1[c + 5]);
          vb.z = fmaf(vb.z, nrm0[c + 6], -nrm1[c + 6]);
          vb.w = fmaf(vb.w, nrm0[c + 7], -nrm1[c + 7]);
        }
      }
      short8 o;
      o[0] = (short)f2bf(va.x); o[1] = (short)f2bf(va.y);
      o[2] = (short)f2bf(va.z); o[3] = (short)f2bf(va.w);
      o[4] = (short)f2bf(vb.x); o[5] = (short)f2bf(vb.y);
      o[6] = (short)f2bf(vb.z); o[7] = (short)f2bf(vb.w);
      *(short8*)&As[sm][skg] = o;
    }
    if (tid < TN * 4) {
      const int bn = tid >> 2, bkg = (tid & 3) * 8;
      *(short8*)&Bs[bn][bkg] =
          *(const short8*)&W[(size_t)(gxTN + bn) * K + k0 + bkg];
    }
    __syncthreads();
    const short8 a = *(const short8*)&As[wv * 16 + ln15][quad * 8];
#pragma unroll
    for (int f = 0; f < NF; ++f) {
      const short8 b = *(const short8*)&Bs[f * 16 + ln15][quad * 8];
      acc[f] = __builtin_amdgcn_mfma_f32_16x16x32_bf16(a, b, acc[f], 0, 0, 0);
    }
    __syncthreads();
  }

  size_t maddr[4];
#pragma unroll
  for (int r = 0; r < 4; ++r) {
    const int m = gyTM + wv * 16 + quad * 4 + r;
    if (MODE == 0) {
      const int ni = m / (OH * OH), rr = m % (OH * OH);
      maddr[r] = (((size_t)ni * OH + rr / OH) * OH + rr % OH) * COUT;
    } else {
      const int ni = m / (IH * IH), rr = m % (IH * IH);
      const int oy = 2 * (rr / IH) + py, ox = 2 * (rr % IH) + px;
      maddr[r] = (((size_t)ni * OH + oy) * OH + ox) * COUT;
    }
  }
#pragma unroll
  for (int f = 0; f < NF; ++f) {
    const int col = gxTN + f * 16 + ln15;
    const float bv = bias[col];
    float cS = 0.f, cQ = 0.f;
#pragma unroll
    for (int r = 0; r < 4; ++r) {
      const float o = lrelu(acc[f][r] + bv);
      cS += o;
      cQ += o * o;
      Y[maddr[r] + col] = o;
    }
    cS += __shfl_down(cS, 32); cS += __shfl_down(cS, 16);
    cQ += __shfl_down(cQ, 32); cQ += __shfl_down(cQ, 16);
    if (lane < 16) { redS[wv][f * 16 + ln15] = cS; redQ[wv][f * 16 + ln15] = cQ; }
  }
  __syncthreads();
  if (tid < TN) {
    float S = redS[0][tid] + redS[1][tid] + redS[2][tid] + redS[3][tid];
    float Q = redQ[0][tid] + redQ[1][tid] + redQ[2][tid] + redQ[3][tid];
    atomicAdd(&stOut[gxTN + tid], S);
    atomicAdd(&stOut[256 + gxTN + tid], Q);
  }
}

// ======================= halo-tile merged convT (COUT=32, CIN<=64) =========
// Multi-strip software pipeline: each block owns NSTRIP consecutive 64-px
// strips (same image). Weights+nrm staged once; halo tiles double-buffered;
// strip s+1's global loads issued BEFORE strip s's MFMAs, LDS-write after
// (async-STAGE split). One barrier per strip. Output = packed bf16 (weight
// columns permuted: slot f*16+ln15 = channel 2*ln15+f). INBF: bf16 input.
template <int IH, int CIN, bool HASN, bool INBF, int NSTRIP>
__global__ __launch_bounds__(256) void convt_mfma(
    const float* __restrict__ X, const ushort* __restrict__ WT,
    const float* __restrict__ bias, const float* __restrict__ st, float invN,
    float* __restrict__ Y, float* __restrict__ stOut) {
  constexpr int OH = 2 * IH;
  constexpr int L = (IH == 32) ? 5 : 4;
  constexpr int RSPAN = 64 / IH;
  constexpr int NP = (RSPAN + 1) * (IH + 1);
  constexpr int LK = CIN + 8;
  constexpr int TI = NP * (CIN / 8);
  constexpr int ITER = (TI + 255) / 256;
  __shared__ short As[2][NP][LK];
  __shared__ short Ws[9 * 32][LK];
  __shared__ float nrm0[HASN ? CIN : 4], nrm1[HASN ? CIN : 4];
  __shared__ float redS[4][32], redQ[4][32];
  const int tid = threadIdx.x;
  const int wv = tid >> 6, lane = tid & 63;
  const int quad = lane >> 4, ln15 = lane & 15;
  if (HASN) {
    for (int c = tid; c < CIN; c += 256) {
      float m = st[c] * invN;
      float var = st[256 + c] * invN - m * m;
      float s = rsqrtf(var + EPS_BN);
      nrm0[c] = s;
      nrm1[c] = m * s;
    }
  }
  // weights -> LDS ([t*32+co_slot][ci]) -- ONCE per block
  for (int i = tid; i < 9 * 32 * (CIN / 8); i += 256) {
    const int row = i / (CIN / 8), kg = (i % (CIN / 8)) * 8;
    *(short8*)&Ws[row][kg] = *(const short8*)&WT[(size_t)row * CIN + kg];
  }
  __syncthreads();  // nrm + Ws visible

  const int strip0 = blockIdx.x * NSTRIP;
  const int n = (strip0 * 64) / (IH * IH);
  const int iy0base = (strip0 * 64 - n * (IH * IH)) >> L;

  // ---- stage strip 0 into buf 0 ----
#pragma unroll
  for (int it = 0; it < ITER; ++it) {
    const int i = tid + it * 256;
    if (i < TI) {
      const int slot = i / (CIN / 8), kg = (i % (CIN / 8)) * 8;
      const int ty = slot / (IH + 1), tx = slot - ty * (IH + 1);
      const int iy = iy0base + ty;
      short8 o = {0, 0, 0, 0, 0, 0, 0, 0};
      if (iy < IH && tx < IH) {
        float v[8];
        if constexpr (INBF) {
          const ushort* xp =
              (const ushort*)X + (((size_t)n * IH + iy) * IH + tx) * CIN + kg;
          const short8 raw = *(const short8*)xp;
#pragma unroll
          for (int u = 0; u < 8; ++u) v[u] = bf2f((ushort)raw[u]);
        } else {
          const float* xp = &X[(((size_t)n * IH + iy) * IH + tx) * CIN + kg];
          const float4 va = *(const float4*)xp, vb = *(const float4*)(xp + 4);
          v[0] = va.x; v[1] = va.y; v[2] = va.z; v[3] = va.w;
          v[4] = vb.x; v[5] = vb.y; v[6] = vb.z; v[7] = vb.w;
        }
        if (HASN) {
#pragma unroll
          for (int u = 0; u < 8; ++u)
            v[u] = fmaf(v[u], nrm0[kg + u], -nrm1[kg + u]);
        }
#pragma unroll
        for (int u = 0; u < 8; ++u) o[u] = (short)f2bf(v[u]);
      }
      *(short8*)&As[0][slot][kg] = o;
    }
  }
  __syncthreads();

  const int rA = wv * 16 + ln15;
  const int baseIdx = (rA >> L) * (IH + 1) + (rA & (IH - 1));
  constexpr int NT[4] = {4, 2, 2, 1};
  constexpr int TT[4][4] = {{4, 5, 7, 8}, {3, 6, 0, 0}, {1, 2, 0, 0}, {0, 0, 0, 0}};
  const float bv0 = bias[2 * ln15], bv1 = bias[2 * ln15 + 1];
  unsigned* Yp = (unsigned*)Y;
  float cS[2] = {0.f, 0.f}, cQ[2] = {0.f, 0.f};

#pragma unroll
  for (int s = 0; s < NSTRIP; ++s) {
    const int cur = s & 1, nxt = cur ^ 1;
    const int iy0 = iy0base + s * RSPAN;

    // ---- issue next strip's global loads (results land later) ----
    short8 rbf[ITER];
    float4 rva[ITER], rvb[ITER];
    bool vld[ITER];
    if (s + 1 < NSTRIP) {
      const int iyN0 = iy0 + RSPAN;
#pragma unroll
      for (int it = 0; it < ITER; ++it) {
        vld[it] = false;
        const int i = tid + it * 256;
        if (i < TI) {
          const int slot = i / (CIN / 8), kg = (i % (CIN / 8)) * 8;
          const int ty = slot / (IH + 1), tx = slot - ty * (IH + 1);
          const int iy = iyN0 + ty;
          if (iy < IH && tx < IH) {
            vld[it] = true;
            if constexpr (INBF) {
              const ushort* xp = (const ushort*)X +
                                 (((size_t)n * IH + iy) * IH + tx) * CIN + kg;
              rbf[it] = *(const short8*)xp;
            } else {
              const float* xp =
                  &X[(((size_t)n * IH + iy) * IH + tx) * CIN + kg];
              rva[it] = *(const float4*)xp;
              rvb[it] = *(const float4*)(xp + 4);
            }
          }
        }
      }
    }

    // ---- MFMAs on As[cur] ----
    f32x4 acc[4][2];
#pragma unroll
    for (int p = 0; p < 4; ++p)
#pragma unroll
      for (int f = 0; f < 2; ++f) acc[p][f] = (f32x4){0.f, 0.f, 0.f, 0.f};
#pragma unroll
    for (int sh = 0; sh < 4; ++sh) {
      const int off = (sh >> 1) * (IH + 1) + (sh & 1);
#pragma unroll
      for (int j = 0; j < NT[sh]; ++j) {
        const int t = TT[sh][j];
        const int ky = t / 3, kx = t - ky * 3;
        const int par = ((ky == 1) ? 0 : 2) + ((kx == 1) ? 0 : 1);
#pragma unroll
        for (int ks = 0; ks < CIN / 32; ++ks) {
          const short8 a =
              *(const short8*)&As[cur][baseIdx + off][ks * 32 + quad * 8];
#pragma unroll
          for (int f = 0; f < 2; ++f) {
            const short8 b =
                *(const short8*)&Ws[t * 32 + f * 16 + ln15][ks * 32 + quad * 8];
            acc[par][f] = __builtin_amdgcn_mfma_f32_16x16x32_bf16(
                a, b, acc[par][f], 0, 0, 0);
          }
        }
      }
    }

    // ---- epilogue: packed bf16 stores; accumulate stats in regs ----
#pragma unroll
    for (int i = 0; i < 4; ++i) {
      const int rD = wv * 16 + quad * 4 + i;
      const int ry = rD >> L, rx = rD & (IH - 1);
      const int iy = iy0 + ry;
#pragma unroll
      for (int p = 0; p < 4; ++p) {
        const int a = p >> 1, b = p & 1;
        const size_t base =
            (((size_t)n * OH + 2 * iy + a) * OH + 2 * rx + b) * 32;
        const float o0 = lrelu(acc[p][0][i] + bv0);
        const float o1 = lrelu(acc[p][1][i] + bv1);
        cS[0] += o0; cQ[0] += o0 * o0;
        cS[1] += o1; cQ[1] += o1 * o1;
        Yp[(base >> 1) + ln15] = (unsigned)f2bf(o0) | ((unsigned)f2bf(o1) << 16);
      }
    }

    // ---- convert + LDS-write next strip into As[nxt] ----
    if (s + 1 < NSTRIP) {
#pragma unroll
      for (int it = 0; it < ITER; ++it) {
        const int i = tid + it * 256;
        if (i < TI) {
          const int slot = i / (CIN / 8), kg = (i % (CIN / 8)) * 8;
          short8 o = {0, 0, 0, 0, 0, 0, 0, 0};
          if (vld[it]) {
            float v[8];
            if constexpr (INBF) {
#pragma unroll
              for (int u = 0; u < 8; ++u) v[u] = bf2f((ushort)rbf[it][u]);
            } else {
              v[0] = rva[it].x; v[1] = rva[it].y;
              v[2] = rva[it].z; v[3] = rva[it].w;
              v[4] = rvb[it].x; v[5] = rvb[it].y;
              v[6] = rvb[it].z; v[7] = rvb[it].w;
            }
            if (HASN) {
#pragma unroll
              for (int u = 0; u < 8; ++u)
                v[u] = fmaf(v[u], nrm0[kg + u], -nrm1[kg + u]);
            }
#pragma unroll
            for (int u = 0; u < 8; ++u) o[u] = (short)f2bf(v[u]);
          }
          *(short8*)&As[nxt][slot][kg] = o;
        }
      }
    }
    __syncthreads();
  }

  // ---- block-level stats reduction + atomics (once per block) ----
#pragma unroll
  for (int f = 0; f < 2; ++f) {
    float s_ = cS[f], q_ = cQ[f];
    s_ += __shfl_down(s_, 32); s_ += __shfl_down(s_, 16);
    q_ += __shfl_down(q_, 32); q_ += __shfl_down(q_, 16);
    if (lane < 16) { redS[wv][f * 16 + ln15] = s_; redQ[wv][f * 16 + ln15] = q_; }
  }
  __syncthreads();
  if (tid < 32) {
    float S = redS[0][tid] + redS[1][tid] + redS[2][tid] + redS[3][tid];
    float Q = redQ[0][tid] + redQ[1][tid] + redQ[2][tid] + redQ[3][tid];
    const int ch = ((tid & 15) << 1) | (tid >> 4);  // slot -> actual channel
    atomicAdd(&stOut[ch], S);
    atomicAdd(&stOut[256 + ch], Q);
  }
}

// ======================= conv1 (CIN=3), NCHW in -> NHWC out ================
__global__ __launch_bounds__(256) void conv1(
    const float* __restrict__ x, const float* __restrict__ w,
    const float* __restrict__ bias, float* __restrict__ y,
    float* __restrict__ st) {
  __shared__ float lw[4 * 3 * 12];
  __shared__ float red[2][4][4];
  const int tid = threadIdx.x;
  const int cog = blockIdx.y * 4;
  for (int i = tid; i < 4 * 27; i += 256) {
    int cor = i / 27, rem = i % 27;
    lw[(cor * 3 + rem / 9) * 12 + rem % 9] = w[cog * 27 + i];
  }
  __syncthreads();
  const int idx = blockIdx.x * 256 + tid;
  const int q = idx & 255;
  const int n = idx >> 8;
  const int qy = q >> 4, qx = q & 15;
  const int iy0 = 4 * qy - 1, ix0 = 4 * qx - 1;
  const float* xn = x + (size_t)n * 3 * 4096;
  bool okr[5], okc[5];
#pragma unroll
  for (int r = 0; r < 5; ++r) okr[r] = (unsigned)(iy0 + r) < 64u;
#pragma unroll
  for (int c = 0; c < 5; ++c) okc[c] = (unsigned)(ix0 + c) < 64u;

  float acc[4][4];
#pragma unroll
  for (int j = 0; j < 4; ++j) {
    const float b = bias[cog + j];
#pragma unroll
    for (int p = 0; p < 4; ++p) acc[j][p] = b;
  }
#pragma unroll
  for (int ci = 0; ci < 3; ++ci) {
    const float* xp = xn + ci * 4096;
    float v[5][5];
#pragma unroll
    for (int r = 0; r < 5; ++r)
#pragma unroll
      for (int c = 0; c < 5; ++c)
        v[r][c] = (okr[r] && okc[c]) ? xp[(iy0 + r) * 64 + ix0 + c] : 0.f;
#pragma unroll
    for (int j = 0; j < 4; ++j) {
      const float* wj = &lw[(j * 3 + ci) * 12];
#pragma unroll
      for (int dy = 0; dy < 2; ++dy)
#pragma unroll
        for (int dx = 0; dx < 2; ++dx)
#pragma unroll
          for (int ky = 0; ky < 3; ++ky)
#pragma unroll
            for (int kx = 0; kx < 3; ++kx)
              acc[j][dy * 2 + dx] = fmaf(v[2 * dy + ky][2 * dx + kx],
                                         wj[ky * 3 + kx], acc[j][dy * 2 + dx]);
    }
  }
  const int wv = tid >> 6, ln = tid & 63;
  float sS[4], sQ[4];
#pragma unroll
  for (int j = 0; j < 4; ++j) { sS[j] = 0.f; sQ[j] = 0.f; }
#pragma unroll
  for (int dy = 0; dy < 2; ++dy)
#pragma unroll
    for (int dx = 0; dx < 2; ++dx) {
      float4 o;
      o.x = lrelu(acc[0][dy * 2 + dx]);
      o.y = lrelu(acc[1][dy * 2 + dx]);
      o.z = lrelu(acc[2][dy * 2 + dx]);
      o.w = lrelu(acc[3][dy * 2 + dx]);
      *(float4*)&y[(((size_t)n * 32 + 2 * qy + dy) * 32 + 2 * qx + dx) * 32 +
                   cog] = o;
      sS[0] += o.x; sS[1] += o.y; sS[2] += o.z; sS[3] += o.w;
      sQ[0] += o.x * o.x; sQ[1] += o.y * o.y;
      sQ[2] += o.z * o.z; sQ[3] += o.w * o.w;
    }
#pragma unroll
  for (int j = 0; j < 4; ++j) {
    float s_ = sS[j], q_ = sQ[j];
#pragma unroll
    for (int off = 32; off > 0; off >>= 1) {
      s_ += __shfl_down(s_, off);
      q_ += __shfl_down(q_, off);
    }
    if (ln == 0) { red[0][wv][j] = s_; red[1][wv][j] = q_; }
  }
  __syncthreads();
  if (tid < 4) {
    const int j = tid;
    float S = red[0][0][j] + red[0][1][j] + red[0][2][j] + red[0][3][j];
    float Q = red[1][0][j] + red[1][1][j] + red[1][2][j] + red[1][3][j];
    atomicAdd(&st[cog + j], S);
    atomicAdd(&st[256 + cog + j], Q);
  }
}

// ======================= final convT 3x3 s1 p1 + tanh, LDS-tiled ===========
// input x is bf16 NHWC [256,64,64,32]
__global__ __launch_bounds__(256) void convt4_tanh(
    const float* __restrict__ x, const float* __restrict__ w,
    const float* __restrict__ bias, const float* __restrict__ st, float invN,
    float* __restrict__ out) {
  __shared__ float tile[324 * 36];
  __shared__ float s0[32], s1[32];
  const int tid = threadIdx.x;
  for (int c = tid; c < 32; c += 256) {
    float m = st[c] * invN;
    float var = st[256 + c] * invN - m * m;
    float s = rsqrtf(var + EPS_BN);
    s0[c] = s;
    s1[c] = m * s;
  }
  __syncthreads();
  const int n = blockIdx.x >> 4;
  const int t16 = blockIdx.x & 15;
  const int oy0 = (t16 >> 2) * 16, ox0 = (t16 & 3) * 16;
  const ushort* xn = (const ushort*)x + (size_t)n * 131072;
  for (int j = tid; j < 2592; j += 256) {
    const int px = j >> 3, cq = (j & 7) * 4;
    const int r = px / 18, c = px - r * 18;
    const int gy = oy0 - 1 + r, gx = ox0 - 1 + c;
    float4 v = make_float4(0.f, 0.f, 0.f, 0.f);
    if ((unsigned)gy < 64u && (unsigned)gx < 64u) {
      const us4 rv = *(const us4*)&xn[(((size_t)gy << 6) + gx) * 32 + cq];
      v.x = fmaf(bf2f(rv[0]), s0[cq + 0], -s1[cq + 0]);
      v.y = fmaf(bf2f(rv[1]), s0[cq + 1], -s1[cq + 1]);
      v.z = fmaf(bf2f(rv[2]), s0[cq + 2], -s1[cq + 2]);
      v.w = fmaf(bf2f(rv[3]), s0[cq + 3], -s1[cq + 3]);
    }
    *(float4*)&tile[px * 36 + cq] = v;
  }
  __syncthreads();
  const int py = tid >> 4, pxx = tid & 15;
  float acc0 = bias[0], acc1 = bias[1], acc2 = bias[2];
  for (int cb4 = 0; cb4 < 8; ++cb4) {
    float4 wv[27];
    const float4* wp = (const float4*)(w + cb4 * 108);
#pragma unroll
    for (int q = 0; q < 27; ++q) wv[q] = wp[q];
    const float* wr = (const float*)wv;
#pragma unroll
    for (int ky = 0; ky < 3; ++ky)
#pragma unroll
      for (int kx = 0; kx < 3; ++kx) {
        const float4 v = *(const float4*)
            &tile[((py + 2 - ky) * 18 + (pxx + 2 - kx)) * 36 + cb4 * 4];
        const int tt = ky * 3 + kx;
#pragma unroll
        for (int u = 0; u < 4; ++u) {
          const float vi = (&v.x)[u];
          acc0 = fmaf(vi, wr[u * 27 + tt], acc0);
          acc1 = fmaf(vi, wr[u * 27 + 9 + tt], acc1);
          acc2 = fmaf(vi, wr[u * 27 + 18 + tt], acc2);
        }
      }
  }
  const int oy = oy0 + py, ox = ox0 + pxx;
  float* op = out + (size_t)n * 3 * 4096 + oy * 64 + ox;
  op[0] = 1.f / (1.f + __expf(-2.f * acc0));
  op[4096] = 1.f / (1.f + __expf(-2.f * acc1));
  op[8192] = 1.f / (1.f + __expf(-2.f * acc2));
}

// ======================= dense GEMM (fc / VQ distance), fp32 ===============
__global__ __launch_bounds__(256) void gemm_abt(
    const float* __restrict__ A, const float* __restrict__ B,
    const float* __restrict__ bias, const float* __restrict__ stA, float invN,
    float* __restrict__ C, float* __restrict__ P, int K, int ldc, int col0,
    float alpha, int act) {
  __shared__ float As[16][68];
  __shared__ float Bsh[16][68];
  __shared__ float nrm[2][256];
  const int tid = threadIdx.x;
  if (stA) {
    const int c = tid;
    float m = stA[c] * invN;
    float var = stA[256 + c] * invN - m * m;
    float s = rsqrtf(var + EPS_BN);
    nrm[0][c] = s;
    nrm[1][c] = m * s;
    __syncthreads();
  }
  const int lm = tid >> 2, lk = (tid & 3) << 2;
  const int KS = gridDim.z;
  const int kChunk = K / KS;
  const int kStart = blockIdx.z * kChunk;
  const float* Arow = A + (size_t)(blockIdx.y * 64 + lm) * K + lk;
  const float* Brow = B + (size_t)(blockIdx.x * 64 + lm) * K + lk;
  float acc[4][4] = {};
  const int m0 = (tid >> 4) << 2, n0 = (tid & 15) << 2;

  for (int k0 = kStart; k0 < kStart + kChunk; k0 += 16) {
    float4 av = *(const float4*)(Arow + k0);
    float4 bv = *(const float4*)(Brow + k0);
    if (stA) {
      const int ch = (k0 + lk) >> 4;
      const float s = nrm[0][ch], ms = nrm[1][ch];
      av.x = fmaf(av.x, s, -ms);
      av.y = fmaf(av.y, s, -ms);
      av.z = fmaf(av.z, s, -ms);
      av.w = fmaf(av.w, s, -ms);
    }
    As[lk + 0][lm] = av.x; As[lk + 1][lm] = av.y;
    As[lk + 2][lm] = av.z; As[lk + 3][lm] = av.w;
    Bsh[lk + 0][lm] = bv.x; Bsh[lk + 1][lm] = bv.y;
    Bsh[lk + 2][lm] = bv.z; Bsh[lk + 3][lm] = bv.w;
    __syncthreads();
#pragma unroll
    for (int kk = 0; kk < 16; ++kk) {
      const float4 a = *(const float4*)&As[kk][m0];
      const float4 b = *(const float4*)&Bsh[kk][n0];
      acc[0][0] = fmaf(a.x, b.x, acc[0][0]); acc[0][1] = fmaf(a.x, b.y, acc[0][1]);
      acc[0][2] = fmaf(a.x, b.z, acc[0][2]); acc[0][3] = fmaf(a.x, b.w, acc[0][3]);
      acc[1][0] = fmaf(a.y, b.x, acc[1][0]); acc[1][1] = fmaf(a.y, b.y, acc[1][1]);
      acc[1][2] = fmaf(a.y, b.z, acc[1][2]); acc[1][3] = fmaf(a.y, b.w, acc[1][3]);
      acc[2][0] = fmaf(a.z, b.x, acc[2][0]); acc[2][1] = fmaf(a.z, b.y, acc[2][1]);
      acc[2][2] = fmaf(a.z, b.z, acc[2][2]); acc[2][3] = fmaf(a.z, b.w, acc[2][3]);
      acc[3][0] = fmaf(a.w, b.x, acc[3][0]); acc[3][1] = fmaf(a.w, b.y, acc[3][1]);
      acc[3][2] = fmaf(a.w, b.z, acc[3][2]); acc[3][3] = fmaf(a.w, b.w, acc[3][3]);
    }
    __syncthreads();
  }

  const int gm = blockIdx.y * 64 + m0;
  const int gn = blockIdx.x * 64 + n0;
  if (KS == 1) {
#pragma unroll
    for (int i = 0; i < 4; ++i) {
      float4 o;
      o.x = alpha * acc[i][0] + bias[gn + 0];
      o.y = alpha * acc[i][1] + bias[gn + 1];
      o.z = alpha * acc[i][2] + bias[gn + 2];
      o.w = alpha * acc[i][3] + bias[gn + 3];
      if (act == 1) {
        o.x = fmaxf(o.x, 0.f); o.y = fmaxf(o.y, 0.f);
        o.z = fmaxf(o.z, 0.f); o.w = fmaxf(o.w, 0.f);
      }
      *(float4*)&C[(size_t)(gm + i) * ldc + col0 + gn] = o;
    }
  } else {
    const int M = gridDim.y * 64, N = gridDim.x * 64;
#pragma unroll
    for (int i = 0; i < 4; ++i)
      *(float4*)&P[((size_t)blockIdx.z * M + gm + i) * N + gn] =
          make_float4(acc[i][0], acc[i][1], acc[i][2], acc[i][3]);
  }
}

__global__ __launch_bounds__(256) void gemm_reduce(
    const float* __restrict__ P, float* __restrict__ C,
    const float* __restrict__ bias, int M, int N, int ldc, int col0,
    float alpha, int act, int KS) {
  const int idx = blockIdx.x * 256 + threadIdx.x;
  if (idx >= M * N) return;
  const int m = idx / N, n = idx % N;
  float s = 0.f;
  for (int z = 0; z < KS; ++z) s += P[((size_t)z * M + m) * N + n];
  float v = alpha * s + bias[n];
  if (act == 1) v = fmaxf(v, 0.f);
  C[(size_t)m * ldc + col0 + n] = v;
}

// ======================= VQ =================================================
__global__ __launch_bounds__(256) void rowsq(const float* __restrict__ cb,
                                             float* __restrict__ csq) {
  const int row = blockIdx.x * 4 + (threadIdx.x >> 6);
  const int ln = threadIdx.x & 63;
  const float4 v = ((const float4*)(cb + (size_t)row * 256))[ln];
  float s = v.x * v.x + v.y * v.y + v.z * v.z + v.w * v.w;
#pragma unroll
  for (int off = 32; off > 0; off >>= 1) s += __shfl_down(s, off);
  if (ln == 0) csq[row] = s;
}

__global__ __launch_bounds__(256) void argmin_d2(const float* __restrict__ d2,
                                                 int* __restrict__ idx) {
  const int b = blockIdx.x, t = threadIdx.x;
  const float* row = d2 + (size_t)b * 8192;
  float best = 3.4e38f;
  int bi = 0x7fffffff;
  for (int k = t; k < 8192; k += 256) {
    const float v = row[k];
    if (v < best) { best = v; bi = k; }
  }
  __shared__ float bval[256];
  __shared__ int bidx[256];
  bval[t] = best;
  bidx[t] = bi;
  __syncthreads();
  for (int s = 128; s > 0; s >>= 1) {
    if (t < s) {
      const float ov = bval[t + s];
      const int oi = bidx[t + s];
      if (ov < bval[t] || (ov == bval[t] && oi < bidx[t])) {
        bval[t] = ov;
        bidx[t] = oi;
      }
    }
    __syncthreads();
  }
  if (t == 0) idx[b] = bidx[0];
}

__global__ __launch_bounds__(256) void vq_gather_loss(
    const float* __restrict__ ze, const float* __restrict__ cb,
    const int* __restrict__ idx, float* __restrict__ zq,
    float* __restrict__ lossacc) {
  const int b = blockIdx.x, d = threadIdx.x;
  const int i = b * 256 + d;
  const float q = cb[(size_t)idx[b] * 256 + d];
  zq[i] = q;
  const float df = ze[i] - q;
  float v = df * df;
  __shared__ float sh[256];
  sh[d] = v;
  __syncthreads();
  for (int s = 128; s > 0; s >>= 1) {
    if (d < s) sh[d] += sh[d + s];
    __syncthreads();
  }
  if (d == 0) atomicAdd(lossacc, sh[0]);
}

__global__ void write_loss(const float* __restrict__ lossacc,
                           float* __restrict__ out) {
  out[0] = 2.f * lossacc[0];
}

// ---------------------------------------------------------------------------
extern "C" void kernel_launch(void* const* d_in, const int* in_sizes, int n_in,
                              void* d_out, int out_size, void* d_ws,
                              size_t ws_size, hipStream_t stream) {
  const float* x = (const float*)d_in[0];
  const float* ew1 = (const float*)d_in[1];
  const float* eb1 = (const float*)d_in[2];
  const float* ew2 = (const float*)d_in[3];
  const float* eb2 = (const float*)d_in[4];
  const float* ew3 = (const float*)d_in[5];
  const float* eb3 = (const float*)d_in[6];
  const float* ew4 = (const float*)d_in[7];
  const float* eb4 = (const float*)d_in[8];
  const float* wmu = (const float*)d_in[9];
  const float* bmu = (const float*)d_in[10];
  const float* wcov = (const float*)d_in[11];
  const float* bcov = (const float*)d_in[12];
  const float* cb = (const float*)d_in[13];
  const float* wfc = (const float*)d_in[14];
  const float* bfc = (const float*)d_in[15];
  const float* wt1 = (const float*)d_in[16];
  const float* bt1 = (const float*)d_in[17];
  const float* wt2 = (const float*)d_in[18];
  const float* bt2 = (const float*)d_in[19];
  const float* wt3 = (const float*)d_in[20];
  const float* bt3 = (const float*)d_in[21];
  const float* wt31 = (const float*)d_in[22];
  const float* bt31 = (const float*)d_in[23];
  const float* wt4 = (const float*)d_in[24];
  const float* bt4 = (const float*)d_in[25];

  float* ws = (float*)d_ws;
  float* a1 = ws;               // NHWC [256,32,32,32]  (reused as g3, bf16)
  float* a2 = a1 + 8388608;     // NHWC [256,16,16,64]  (reused as g2)
  float* a3 = a2 + 4194304;     // NHWC [256,8,8,128]   (reused as g1)
  float* a4 = a3 + 2097152;     // NHWC [256,4,4,256]   (reused as g0)
  float* g31 = a4 + 1048576;    // NHWC [256,64,64,32] bf16 (region 33554432 f)
  float* d2 = g31;              // [256,8192]
  float* P = g31 + 2097152;     // 262144
  float* csq = g31 + 2359296;   // 8192
  float* a4n = g31 + 2367488;   // NCHW a4 copy
  float* wfcT = g31 + 3416064;  // 1048576
  float* bfcT = g31 + 4464640;  // 4096
  ushort* wTc2 = (ushort*)(g31 + 4468736);  // 18432 bf16
  ushort* wTc3 = (ushort*)(g31 + 4487168);  // 73728 bf16
  ushort* wTc4 = (ushort*)(g31 + 4560896);  // 294912 bf16
  float* ze = g31 + 33554432;   // [256,256]
  float* zq = ze + 65536;
  float* stats = zq + 65536;    // 8 layers x 512
  float* lossacc = stats + 4096;
  int* idx = (int*)(lossacc + 4);
  ushort* wTt1 = (ushort*)(lossacc + 4 + 256);  // 294912 bf16 (parity)
  ushort* wTt2 = wTt1 + 294912;                 // 73728 bf16 (parity)
  ushort* wTt3 = wTt2 + 73728;                  // 18432 bf16 (tap-major,perm)
  ushort* wTt31 = wTt3 + 18432;                 // 9216 bf16 (tap-major,perm)
  float* g3 = a1;   // bf16 content
  float* g2 = a2;
  float* g1 = a3;
  float* g0 = a4;

  float* st0 = stats + 0 * 512;
  float* st1 = stats + 1 * 512;
  float* st2 = stats + 2 * 512;
  float* st3 = stats + 3 * 512;
  float* st4 = stats + 4 * 512;
  float* st5 = stats + 5 * 512;
  float* st6 = stats + 6 * 512;
  float* st7 = stats + 7 * 512;

  hipMemsetAsync(stats, 0, (4096 + 8) * sizeof(float), stream);

  // ---- weight transposes (bf16) ----
  tr_convw_bf<<<72, 256, 0, stream>>>(ew2, wTc2, 32, 64, 18432);
  tr_convw_bf<<<288, 256, 0, stream>>>(ew3, wTc3, 64, 128, 73728);
  tr_convw_bf<<<1152, 256, 0, stream>>>(ew4, wTc4, 128, 256, 294912);
  tr_convtw_bf<<<1152, 256, 0, stream>>>(wt1, wTt1, 256, 128, 294912);
  tr_convtw_bf<<<288, 256, 0, stream>>>(wt2, wTt2, 128, 64, 73728);
  tr_convtw_tc<<<72, 256, 0, stream>>>(wt3, wTt3, 64, 32, 18432);
  tr_convtw_tc<<<36, 256, 0, stream>>>(wt31, wTt31, 32, 32, 9216);
  tr_fcdec<<<4096, 256, 0, stream>>>(wfc, bfc, wfcT, bfcT);
  rowsq<<<2048, 256, 0, stream>>>(cb, csq);

  // ---- encoder ----
  conv1<<<dim3(256, 8), 256, 0, stream>>>(x, ew1, eb1, a1, st0);
  mfmaconv<64, 0, 32, 32, 64, true><<<dim3(1, 1024), 256, 0, stream>>>(
      a1, wTc2, eb2, st0, 1.f / (256.f * 1024.f), a2, st1);
  mfmaconv<64, 0, 16, 64, 128, true><<<dim3(2, 256), 256, 0, stream>>>(
      a2, wTc3, eb3, st1, 1.f / (256.f * 256.f), a3, st2);
  mfmaconv<64, 0, 8, 128, 256, true><<<dim3(4, 64), 256, 0, stream>>>(
      a3, wTc4, eb4, st2, 1.f / (256.f * 64.f), a4, st3);
  tr_a4<<<4096, 256, 0, stream>>>(a4, a4n);

  // ---- encoder FC (fp32) ----
  gemm_abt<<<dim3(2, 4, 8), 256, 0, stream>>>(a4n, wmu, nullptr, st3,
                                              1.f / 4096.f, nullptr, P, 4096,
                                              0, 0, 1.f, 0);
  gemm_reduce<<<128, 256, 0, stream>>>(P, ze, bmu, 256, 128, 256, 0, 1.f, 0, 8);
  gemm_abt<<<dim3(2, 4, 8), 256, 0, stream>>>(a4n, wcov, nullptr, st3,
                                              1.f / 4096.f, nullptr, P, 4096,
                                              0, 0, 1.f, 0);
  gemm_reduce<<<128, 256, 0, stream>>>(P, ze, bcov, 256, 128, 256, 128, 1.f, 1, 8);

  // ---- VQ (fp32) ----
  gemm_abt<<<dim3(128, 4, 1), 256, 0, stream>>>(ze, cb, csq, nullptr, 0.f, d2,
                                                nullptr, 256, 8192, 0, -2.f, 0);
  argmin_d2<<<256, 256, 0, stream>>>(d2, idx);
  vq_gather_loss<<<256, 256, 0, stream>>>(ze, cb, idx, zq, lossacc);

  // ---- decoder FC (fp32) ----
  gemm_abt<<<dim3(64, 4, 1), 256, 0, stream>>>(zq, wfcT, bfcT, nullptr, 0.f,
                                               g0, nullptr, 256, 4096, 0, 1.f, 0);

  // ---- decoder ----
  mfmaconv<64, 1, 4, 256, 128, false><<<dim3(2, 64, 4), 256, 0, stream>>>(
      g0, wTt1, bt1, nullptr, 0.f, g1, st4);
  mfmaconv<64, 1, 8, 128, 64, true><<<dim3(1, 256, 4), 256, 0, stream>>>(
      g1, wTt2, bt2, st4, 1.f / (256.f * 64.f), g2, st5);
  convt_mfma<16, 64, true, false, 2><<<512, 256, 0, stream>>>(
      g2, wTt3, bt3, st5, 1.f / (256.f * 256.f), g3, st6);
  convt_mfma<32, 32, true, true, 4><<<1024, 256, 0, stream>>>(
      g3, wTt31, bt31, st6, 1.f / (256.f * 1024.f), g31, st7);

  convt4_tanh<<<4096, 256, 0, stream>>>(g31, wt4, bt4, st7,
                                        1.f / (256.f * 4096.f), (float*)d_out);
  write_loss<<<1, 1, 0, stream>>>(lossacc, (float*)d_out + 3145728);
}

// Round 3
// 570.455 us; speedup vs baseline: 1.1007x; 1.0371x over previous
//
#include <hip/hip_runtime.h>
#include <cmath>

// ---------------------------------------------------------------------------
// VQ-VAE forward. B=256, C=3, HW=64, D=256, K=8192, LAT=128
// R11: convt4 rewritten as bf16 MFMA implicit GEMM with a 4-row LDS ring.
// M=pixels, K=288 (9 taps x 32ch, 9 MFMA k-steps), N=16 (3 ch used; matrix
// pipe was idle anyway). Block = image x 16 rows; per row: stage ONE new
// 64px x 32ch bf16 row (1 short8/thread, async-split), 9 ds_read_b128 +
// 9 MFMA per wave, logistic epilogue, float4 stores. Weights pre-transposed
// into per-lane B-fragments (tr_w4), held in 36 VGPRs. LDS 47->17KB.
// R10 multi-strip convt_mfma, R9 packed-bf16 tail, parity mfmaconv retained.
// ---------------------------------------------------------------------------

#define EPS_BN 1e-5f
typedef unsigned short ushort;
typedef short short8 __attribute__((ext_vector_type(8)));
typedef ushort us4 __attribute__((ext_vector_type(4)));
typedef float f32x4 __attribute__((ext_vector_type(4)));

__device__ __forceinline__ float lrelu(float v) { return v >= 0.f ? v : 0.01f * v; }
__device__ __forceinline__ ushort f2bf(float f) {
  unsigned u = __float_as_uint(f);
  return (ushort)((u + 0x7FFF + ((u >> 16) & 1)) >> 16);
}
__device__ __forceinline__ float bf2f(ushort u) {
  return __uint_as_float(((unsigned)u) << 16);
}

// ======================= weight transposes (once per launch) ===============
// conv (COUT,CIN,3,3) -> bf16 [co][t*CIN+ci]
__global__ __launch_bounds__(256) void tr_convw_bf(const float* __restrict__ w,
                                                   ushort* __restrict__ wT,
                                                   int CIN, int COUT, int total) {
  int i = blockIdx.x * 256 + threadIdx.x;
  if (i >= total) return;
  int co = i / (9 * CIN);
  int r = i - co * 9 * CIN;
  int t = r / CIN, ci = r - t * CIN;
  wT[i] = f2bf(w[((size_t)co * CIN + ci) * 9 + t]);
}

// convT (CIN,COUT,3,3) -> bf16 parity-concat [p][co][k]
__global__ __launch_bounds__(256) void tr_convtw_bf(const float* __restrict__ w,
                                                    ushort* __restrict__ wT,
                                                    int CIN, int COUT, int total) {
  int i = blockIdx.x * 256 + threadIdx.x;
  if (i >= total) return;
  const int cc = CIN * COUT;
  int p, base, Kp;
  if (i < cc) { p = 0; base = 0; Kp = CIN; }
  else if (i < 3 * cc) { p = 1; base = cc; Kp = 2 * CIN; }
  else if (i < 5 * cc) { p = 2; base = 3 * cc; Kp = 2 * CIN; }
  else { p = 3; base = 5 * cc; Kp = 4 * CIN; }
  const int r = i - base;
  const int co = r / Kp;
  const int q = r - co * Kp;
  const int tix = q / CIN, ci = q - (q / CIN) * CIN;
  const int py = p >> 1, px = p & 1;
  const int nx = px ? 2 : 1;
  const int kyi = tix / nx, kxi = tix - kyi * nx;
  const int ky = py ? (kyi == 0 ? 0 : 2) : 1;
  const int kx = px ? (kxi == 0 ? 0 : 2) : 1;
  wT[i] = f2bf(w[((size_t)ci * COUT + co) * 9 + ky * 3 + kx]);
}

// convT (CIN,COUT=32,3,3) -> bf16 [t][co_slot][ci] (tap-major, columns
// PERMUTED so slot f*16+ln15 holds channel 2*ln15+f -> packed bf16 stores)
__global__ __launch_bounds__(256) void tr_convtw_tc(const float* __restrict__ w,
                                                    ushort* __restrict__ wT,
                                                    int CIN, int COUT, int total) {
  int i = blockIdx.x * 256 + threadIdx.x;
  if (i >= total) return;
  int ci = i % CIN;
  int tmp = i / CIN;
  int co = tmp % COUT;
  int t = tmp / COUT;
  const int co_slot = ((co & 1) << 4) | (co >> 1);
  wT[((size_t)t * COUT + co_slot) * CIN + ci] =
      f2bf(w[((size_t)ci * COUT + co) * 9 + t]);
}

// convt4 weights (CIN=32, COUT=3, 3,3) -> per-lane B fragments
// wT[(s*64 + lane)*8 + j] = W[n=lane&15][ci=(lane>>4)*8+j] for tap s=ty*3+tx,
// using flipped tap (2-ty,2-tx); zero for n>=3.
__global__ __launch_bounds__(256) void tr_w4(const float* __restrict__ w,
                                             ushort* __restrict__ wT) {
  int i = blockIdx.x * 256 + threadIdx.x;
  if (i >= 4608) return;
  const int s = i >> 9;
  const int l = (i >> 3) & 63;
  const int j = i & 7;
  const int nn = l & 15;
  const int ci = ((l >> 4) << 3) + j;
  const int ty = s / 3, tx = s - ty * 3;
  ushort v = 0;
  if (nn < 3)
    v = f2bf(w[((size_t)ci * 3 + nn) * 9 + (2 - ty) * 3 + (2 - tx)]);
  wT[i] = v;
}

// a4 NHWC [256,4,4,256] -> NCHW [256,256,4,4]
__global__ __launch_bounds__(256) void tr_a4(const float* __restrict__ in,
                                             float* __restrict__ out) {
  int i = blockIdx.x * 256 + threadIdx.x;
  int n = i >> 12, k = i & 4095;
  out[i] = in[(size_t)(n << 12) + ((k & 15) << 8) + (k >> 4)];
}

// wfc [4096,256] + bfc: permute ROWS from (c,y,x) to (y,x,c)
__global__ __launch_bounds__(256) void tr_fcdec(const float* __restrict__ in,
                                                const float* __restrict__ bin,
                                                float* __restrict__ out,
                                                float* __restrict__ bout) {
  int i = blockIdx.x * 256 + threadIdx.x;
  int k = i >> 8, d = i & 255;
  int kp = (k & 15) * 256 + (k >> 4);
  out[(size_t)kp * 256 + d] = in[i];
  if (d == 0) bout[kp] = bin[k];
}

// ======================= bf16 MFMA implicit-GEMM conv / convT ==============
template <int TN, int MODE, int IH, int CIN, int COUT, bool HASN>
__global__ __launch_bounds__(256) void mfmaconv(
    const float* __restrict__ X, const ushort* __restrict__ WT,
    const float* __restrict__ bias, const float* __restrict__ st, float invN,
    float* __restrict__ Y, float* __restrict__ stOut) {
  constexpr int OH = (MODE == 0) ? IH / 2 : 2 * IH;
  constexpr int NF = TN / 16;
  __shared__ short As[64][40];
  __shared__ short Bs[TN][40];
  __shared__ float nrm0[HASN ? CIN : 4], nrm1[HASN ? CIN : 4];
  __shared__ float redS[4][TN], redQ[4][TN];
  const int tid = threadIdx.x;
  const int wv = tid >> 6, lane = tid & 63;
  const int quad = lane >> 4, ln15 = tid & 15;
  if (HASN) {
    for (int c = tid; c < CIN; c += 256) {
      float m = st[c] * invN;
      float var = st[256 + c] * invN - m * m;
      float s = rsqrtf(var + EPS_BN);
      nrm0[c] = s;
      nrm1[c] = m * s;
    }
    __syncthreads();
  }
  int py = 0, px = 0, nx = 1, K = 9 * CIN;
  const ushort* W = WT;
  if (MODE == 1) {
    const int pz = blockIdx.z;
    py = pz >> 1;
    px = pz & 1;
    nx = px ? 2 : 1;
    const int ny = py ? 2 : 1;
    K = ny * nx * CIN;
    const int pre[4] = {0, 1, 3, 5};
    W = WT + (size_t)pre[pz] * CIN * COUT;
  }
  const int gyTM = blockIdx.y * 64;
  const int gxTN = blockIdx.x * TN;

  const int sm = tid & 63, skg = (tid >> 6) * 8;
  int baseNB, baseIY, baseIX;
  {
    const int gm = gyTM + sm;
    if (MODE == 0) {
      const int ni = gm / (OH * OH), r = gm % (OH * OH);
      baseNB = ni * IH * IH;
      baseIY = 2 * (r / OH) - 1;
      baseIX = 2 * (r % OH) - 1;
    } else {
      const int ni = gm / (IH * IH), r = gm % (IH * IH);
      baseNB = ni * IH * IH;
      baseIY = r / IH;
      baseIX = r % IH;
    }
  }
  f32x4 acc[NF];
#pragma unroll
  for (int f = 0; f < NF; ++f) acc[f] = (f32x4){0.f, 0.f, 0.f, 0.f};

  for (int k0 = 0; k0 < K; k0 += 32) {
    const int t = k0 / CIN;
    const int ci0 = k0 - t * CIN;
    int iy, ix;
    if (MODE == 0) {
      iy = baseIY + t / 3;
      ix = baseIX + (t - (t / 3) * 3);
    } else {
      const int kyi = t / nx, kxi = t - (t / nx) * nx;
      iy = baseIY + ((py && kyi == 0) ? 1 : 0);
      ix = baseIX + ((px && kxi == 0) ? 1 : 0);
    }
    {
      const bool ok =
          ((unsigned)iy < (unsigned)IH) && ((unsigned)ix < (unsigned)IH);
      float4 va = make_float4(0.f, 0.f, 0.f, 0.f), vb = va;
      if (ok) {
        const float* xp = &X[((size_t)baseNB + iy * IH + ix) * CIN + ci0 + skg];
        va = *(const float4*)xp;
        vb = *(const float4*)(xp + 4);
        if (HASN) {
          const int c = ci0 + skg;
          va.x = fmaf(va.x, nrm0[c + 0], -nrm1[c + 0]);
          va.y = fmaf(va.y, nrm0[c + 1], -nrm1[c + 1]);
          va.z = fmaf(va.z, nrm0[c + 2], -nrm1[c + 2]);
          va.w = fmaf(va.w, nrm0[c + 3], -nrm1[c + 3]);
          vb.x = fmaf(vb.x, nrm0[c + 4], -nrm1[c + 4]);
          vb.y = fmaf(vb.y, nrm0[c + 5], -nrm1[c + 5]);
          vb.z = fmaf(vb.z, nrm0[c + 6], -nrm1[c + 6]);
          vb.w = fmaf(vb.w, nrm0[c + 7], -nrm1[c + 7]);
        }
      }
      short8 o;
      o[0] = (short)f2bf(va.x); o[1] = (short)f2bf(va.y);
      o[2] = (short)f2bf(va.z); o[3] = (short)f2bf(va.w);
      o[4] = (short)f2bf(vb.x); o[5] = (short)f2bf(vb.y);
      o[6] = (short)f2bf(vb.z); o[7] = (short)f2bf(vb.w);
      *(short8*)&As[sm][skg] = o;
    }
    if (tid < TN * 4) {
      const int bn = tid >> 2, bkg = (tid & 3) * 8;
      *(short8*)&Bs[bn][bkg] =
          *(const short8*)&W[(size_t)(gxTN + bn) * K + k0 + bkg];
    }
    __syncthreads();
    const short8 a = *(const short8*)&As[wv * 16 + ln15][quad * 8];
#pragma unroll
    for (int f = 0; f < NF; ++f) {
      const short8 b = *(const short8*)&Bs[f * 16 + ln15][quad * 8];
      acc[f] = __builtin_amdgcn_mfma_f32_16x16x32_bf16(a, b, acc[f], 0, 0, 0);
    }
    __syncthreads();
  }

  size_t maddr[4];
#pragma unroll
  for (int r = 0; r < 4; ++r) {
    const int m = gyTM + wv * 16 + quad * 4 + r;
    if (MODE == 0) {
      const int ni = m / (OH * OH), rr = m % (OH * OH);
      maddr[r] = (((size_t)ni * OH + rr / OH) * OH + rr % OH) * COUT;
    } else {
      const int ni = m / (IH * IH), rr = m % (IH * IH);
      const int oy = 2 * (rr / IH) + py, ox = 2 * (rr % IH) + px;
      maddr[r] = (((size_t)ni * OH + oy) * OH + ox) * COUT;
    }
  }
#pragma unroll
  for (int f = 0; f < NF; ++f) {
    const int col = gxTN + f * 16 + ln15;
    const float bv = bias[col];
    float cS = 0.f, cQ = 0.f;
#pragma unroll
    for (int r = 0; r < 4; ++r) {
      const float o = lrelu(acc[f][r] + bv);
      cS += o;
      cQ += o * o;
      Y[maddr[r] + col] = o;
    }
    cS += __shfl_down(cS, 32); cS += __shfl_down(cS, 16);
    cQ += __shfl_down(cQ, 32); cQ += __shfl_down(cQ, 16);
    if (lane < 16) { redS[wv][f * 16 + ln15] = cS; redQ[wv][f * 16 + ln15] = cQ; }
  }
  __syncthreads();
  if (tid < TN) {
    float S = redS[0][tid] + redS[1][tid] + redS[2][tid] + redS[3][tid];
    float Q = redQ[0][tid] + redQ[1][tid] + redQ[2][tid] + redQ[3][tid];
    atomicAdd(&stOut[gxTN + tid], S);
    atomicAdd(&stOut[256 + gxTN + tid], Q);
  }
}

// ======================= halo-tile merged convT (COUT=32, CIN<=64) =========
// Multi-strip software pipeline (R10). Output = packed bf16.
template <int IH, int CIN, bool HASN, bool INBF, int NSTRIP>
__global__ __launch_bounds__(256) void convt_mfma(
    const float* __restrict__ X, const ushort* __restrict__ WT,
    const float* __restrict__ bias, const float* __restrict__ st, float invN,
    float* __restrict__ Y, float* __restrict__ stOut) {
  constexpr int OH = 2 * IH;
  constexpr int L = (IH == 32) ? 5 : 4;
  constexpr int RSPAN = 64 / IH;
  constexpr int NP = (RSPAN + 1) * (IH + 1);
  constexpr int LK = CIN + 8;
  constexpr int TI = NP * (CIN / 8);
  constexpr int ITER = (TI + 255) / 256;
  __shared__ short As[2][NP][LK];
  __shared__ short Ws[9 * 32][LK];
  __shared__ float nrm0[HASN ? CIN : 4], nrm1[HASN ? CIN : 4];
  __shared__ float redS[4][32], redQ[4][32];
  const int tid = threadIdx.x;
  const int wv = tid >> 6, lane = tid & 63;
  const int quad = lane >> 4, ln15 = lane & 15;
  if (HASN) {
    for (int c = tid; c < CIN; c += 256) {
      float m = st[c] * invN;
      float var = st[256 + c] * invN - m * m;
      float s = rsqrtf(var + EPS_BN);
      nrm0[c] = s;
      nrm1[c] = m * s;
    }
  }
  for (int i = tid; i < 9 * 32 * (CIN / 8); i += 256) {
    const int row = i / (CIN / 8), kg = (i % (CIN / 8)) * 8;
    *(short8*)&Ws[row][kg] = *(const short8*)&WT[(size_t)row * CIN + kg];
  }
  __syncthreads();

  const int strip0 = blockIdx.x * NSTRIP;
  const int n = (strip0 * 64) / (IH * IH);
  const int iy0base = (strip0 * 64 - n * (IH * IH)) >> L;

#pragma unroll
  for (int it = 0; it < ITER; ++it) {
    const int i = tid + it * 256;
    if (i < TI) {
      const int slot = i / (CIN / 8), kg = (i % (CIN / 8)) * 8;
      const int ty = slot / (IH + 1), tx = slot - ty * (IH + 1);
      const int iy = iy0base + ty;
      short8 o = {0, 0, 0, 0, 0, 0, 0, 0};
      if (iy < IH && tx < IH) {
        float v[8];
        if constexpr (INBF) {
          const ushort* xp =
              (const ushort*)X + (((size_t)n * IH + iy) * IH + tx) * CIN + kg;
          const short8 raw = *(const short8*)xp;
#pragma unroll
          for (int u = 0; u < 8; ++u) v[u] = bf2f((ushort)raw[u]);
        } else {
          const float* xp = &X[(((size_t)n * IH + iy) * IH + tx) * CIN + kg];
          const float4 va = *(const float4*)xp, vb = *(const float4*)(xp + 4);
          v[0] = va.x; v[1] = va.y; v[2] = va.z; v[3] = va.w;
          v[4] = vb.x; v[5] = vb.y; v[6] = vb.z; v[7] = vb.w;
        }
        if (HASN) {
#pragma unroll
          for (int u = 0; u < 8; ++u)
            v[u] = fmaf(v[u], nrm0[kg + u], -nrm1[kg + u]);
        }
#pragma unroll
        for (int u = 0; u < 8; ++u) o[u] = (short)f2bf(v[u]);
      }
      *(short8*)&As[0][slot][kg] = o;
    }
  }
  __syncthreads();

  const int rA = wv * 16 + ln15;
  const int baseIdx = (rA >> L) * (IH + 1) + (rA & (IH - 1));
  constexpr int NT[4] = {4, 2, 2, 1};
  constexpr int TT[4][4] = {{4, 5, 7, 8}, {3, 6, 0, 0}, {1, 2, 0, 0}, {0, 0, 0, 0}};
  const float bv0 = bias[2 * ln15], bv1 = bias[2 * ln15 + 1];
  unsigned* Yp = (unsigned*)Y;
  float cS[2] = {0.f, 0.f}, cQ[2] = {0.f, 0.f};

#pragma unroll
  for (int s = 0; s < NSTRIP; ++s) {
    const int cur = s & 1, nxt = cur ^ 1;
    const int iy0 = iy0base + s * RSPAN;

    short8 rbf[ITER];
    float4 rva[ITER], rvb[ITER];
    bool vld[ITER];
    if (s + 1 < NSTRIP) {
      const int iyN0 = iy0 + RSPAN;
#pragma unroll
      for (int it = 0; it < ITER; ++it) {
        vld[it] = false;
        const int i = tid + it * 256;
        if (i < TI) {
          const int slot = i / (CIN / 8), kg = (i % (CIN / 8)) * 8;
          const int ty = slot / (IH + 1), tx = slot - ty * (IH + 1);
          const int iy = iyN0 + ty;
          if (iy < IH && tx < IH) {
            vld[it] = true;
            if constexpr (INBF) {
              const ushort* xp = (const ushort*)X +
                                 (((size_t)n * IH + iy) * IH + tx) * CIN + kg;
              rbf[it] = *(const short8*)xp;
            } else {
              const float* xp =
                  &X[(((size_t)n * IH + iy) * IH + tx) * CIN + kg];
              rva[it] = *(const float4*)xp;
              rvb[it] = *(const float4*)(xp + 4);
            }
          }
        }
      }
    }

    f32x4 acc[4][2];
#pragma unroll
    for (int p = 0; p < 4; ++p)
#pragma unroll
      for (int f = 0; f < 2; ++f) acc[p][f] = (f32x4){0.f, 0.f, 0.f, 0.f};
#pragma unroll
    for (int sh = 0; sh < 4; ++sh) {
      const int off = (sh >> 1) * (IH + 1) + (sh & 1);
#pragma unroll
      for (int j = 0; j < NT[sh]; ++j) {
        const int t = TT[sh][j];
        const int ky = t / 3, kx = t - ky * 3;
        const int par = ((ky == 1) ? 0 : 2) + ((kx == 1) ? 0 : 1);
#pragma unroll
        for (int ks = 0; ks < CIN / 32; ++ks) {
          const short8 a =
              *(const short8*)&As[cur][baseIdx + off][ks * 32 + quad * 8];
#pragma unroll
          for (int f = 0; f < 2; ++f) {
            const short8 b =
                *(const short8*)&Ws[t * 32 + f * 16 + ln15][ks * 32 + quad * 8];
            acc[par][f] = __builtin_amdgcn_mfma_f32_16x16x32_bf16(
                a, b, acc[par][f], 0, 0, 0);
          }
        }
      }
    }

#pragma unroll
    for (int i = 0; i < 4; ++i) {
      const int rD = wv * 16 + quad * 4 + i;
      const int ry = rD >> L, rx = rD & (IH - 1);
      const int iy = iy0 + ry;
#pragma unroll
      for (int p = 0; p < 4; ++p) {
        const int a = p >> 1, b = p & 1;
        const size_t base =
            (((size_t)n * OH + 2 * iy + a) * OH + 2 * rx + b) * 32;
        const float o0 = lrelu(acc[p][0][i] + bv0);
        const float o1 = lrelu(acc[p][1][i] + bv1);
        cS[0] += o0; cQ[0] += o0 * o0;
        cS[1] += o1; cQ[1] += o1 * o1;
        Yp[(base >> 1) + ln15] = (unsigned)f2bf(o0) | ((unsigned)f2bf(o1) << 16);
      }
    }

    if (s + 1 < NSTRIP) {
#pragma unroll
      for (int it = 0; it < ITER; ++it) {
        const int i = tid + it * 256;
        if (i < TI) {
          const int slot = i / (CIN / 8), kg = (i % (CIN / 8)) * 8;
          short8 o = {0, 0, 0, 0, 0, 0, 0, 0};
          if (vld[it]) {
            float v[8];
            if constexpr (INBF) {
#pragma unroll
              for (int u = 0; u < 8; ++u) v[u] = bf2f((ushort)rbf[it][u]);
            } else {
              v[0] = rva[it].x; v[1] = rva[it].y;
              v[2] = rva[it].z; v[3] = rva[it].w;
              v[4] = rvb[it].x; v[5] = rvb[it].y;
              v[6] = rvb[it].z; v[7] = rvb[it].w;
            }
            if (HASN) {
#pragma unroll
              for (int u = 0; u < 8; ++u)
                v[u] = fmaf(v[u], nrm0[kg + u], -nrm1[kg + u]);
            }
#pragma unroll
            for (int u = 0; u < 8; ++u) o[u] = (short)f2bf(v[u]);
          }
          *(short8*)&As[nxt][slot][kg] = o;
        }
      }
    }
    __syncthreads();
  }

#pragma unroll
  for (int f = 0; f < 2; ++f) {
    float s_ = cS[f], q_ = cQ[f];
    s_ += __shfl_down(s_, 32); s_ += __shfl_down(s_, 16);
    q_ += __shfl_down(q_, 32); q_ += __shfl_down(q_, 16);
    if (lane < 16) { redS[wv][f * 16 + ln15] = s_; redQ[wv][f * 16 + ln15] = q_; }
  }
  __syncthreads();
  if (tid < 32) {
    float S = redS[0][tid] + redS[1][tid] + redS[2][tid] + redS[3][tid];
    float Q = redQ[0][tid] + redQ[1][tid] + redQ[2][tid] + redQ[3][tid];
    const int ch = ((tid & 15) << 1) | (tid >> 4);
    atomicAdd(&stOut[ch], S);
    atomicAdd(&stOut[256 + ch], Q);
  }
}

// ======================= conv1 (CIN=3), NCHW in -> NHWC out ================
__global__ __launch_bounds__(256) void conv1(
    const float* __restrict__ x, const float* __restrict__ w,
    const float* __restrict__ bias, float* __restrict__ y,
    float* __restrict__ st) {
  __shared__ float lw[4 * 3 * 12];
  __shared__ float red[2][4][4];
  const int tid = threadIdx.x;
  const int cog = blockIdx.y * 4;
  for (int i = tid; i < 4 * 27; i += 256) {
    int cor = i / 27, rem = i % 27;
    lw[(cor * 3 + rem / 9) * 12 + rem % 9] = w[cog * 27 + i];
  }
  __syncthreads();
  const int idx = blockIdx.x * 256 + tid;
  const int q = idx & 255;
  const int n = idx >> 8;
  const int qy = q >> 4, qx = q & 15;
  const int iy0 = 4 * qy - 1, ix0 = 4 * qx - 1;
  const float* xn = x + (size_t)n * 3 * 4096;
  bool okr[5], okc[5];
#pragma unroll
  for (int r = 0; r < 5; ++r) okr[r] = (unsigned)(iy0 + r) < 64u;
#pragma unroll
  for (int c = 0; c < 5; ++c) okc[c] = (unsigned)(ix0 + c) < 64u;

  float acc[4][4];
#pragma unroll
  for (int j = 0; j < 4; ++j) {
    const float b = bias[cog + j];
#pragma unroll
    for (int p = 0; p < 4; ++p) acc[j][p] = b;
  }
#pragma unroll
  for (int ci = 0; ci < 3; ++ci) {
    const float* xp = xn + ci * 4096;
    float v[5][5];
#pragma unroll
    for (int r = 0; r < 5; ++r)
#pragma unroll
      for (int c = 0; c < 5; ++c)
        v[r][c] = (okr[r] && okc[c]) ? xp[(iy0 + r) * 64 + ix0 + c] : 0.f;
#pragma unroll
    for (int j = 0; j < 4; ++j) {
      const float* wj = &lw[(j * 3 + ci) * 12];
#pragma unroll
      for (int dy = 0; dy < 2; ++dy)
#pragma unroll
        for (int dx = 0; dx < 2; ++dx)
#pragma unroll
          for (int ky = 0; ky < 3; ++ky)
#pragma unroll
            for (int kx = 0; kx < 3; ++kx)
              acc[j][dy * 2 + dx] = fmaf(v[2 * dy + ky][2 * dx + kx],
                                         wj[ky * 3 + kx], acc[j][dy * 2 + dx]);
    }
  }
  const int wv = tid >> 6, ln = tid & 63;
  float sS[4], sQ[4];
#pragma unroll
  for (int j = 0; j < 4; ++j) { sS[j] = 0.f; sQ[j] = 0.f; }
#pragma unroll
  for (int dy = 0; dy < 2; ++dy)
#pragma unroll
    for (int dx = 0; dx < 2; ++dx) {
      float4 o;
      o.x = lrelu(acc[0][dy * 2 + dx]);
      o.y = lrelu(acc[1][dy * 2 + dx]);
      o.z = lrelu(acc[2][dy * 2 + dx]);
      o.w = lrelu(acc[3][dy * 2 + dx]);
      *(float4*)&y[(((size_t)n * 32 + 2 * qy + dy) * 32 + 2 * qx + dx) * 32 +
                   cog] = o;
      sS[0] += o.x; sS[1] += o.y; sS[2] += o.z; sS[3] += o.w;
      sQ[0] += o.x * o.x; sQ[1] += o.y * o.y;
      sQ[2] += o.z * o.z; sQ[3] += o.w * o.w;
    }
#pragma unroll
  for (int j = 0; j < 4; ++j) {
    float s_ = sS[j], q_ = sQ[j];
#pragma unroll
    for (int off = 32; off > 0; off >>= 1) {
      s_ += __shfl_down(s_, off);
      q_ += __shfl_down(q_, off);
    }
    if (ln == 0) { red[0][wv][j] = s_; red[1][wv][j] = q_; }
  }
  __syncthreads();
  if (tid < 4) {
    const int j = tid;
    float S = red[0][0][j] + red[0][1][j] + red[0][2][j] + red[0][3][j];
    float Q = red[1][0][j] + red[1][1][j] + red[1][2][j] + red[1][3][j];
    atomicAdd(&st[cog + j], S);
    atomicAdd(&st[256 + cog + j], Q);
  }
}

// ======================= final convT via MFMA + 4-row LDS ring =============
// Input g31 bf16 NHWC [256,64,64,32]. Block = image x 16 rows, 4 waves.
// Wave w: output pixels x0=16w..x0+15 of row y, channels n=0..2 (N=16 tile).
// K = 288 -> 9 MFMA steps (tap-major); B fragments preloaded to 36 VGPRs.
// Ring: 4 rows x 66 px x 32 ch bf16 (halo cols 0,65 zeroed once).
__global__ __launch_bounds__(256) void convt4_mfma(
    const float* __restrict__ X, const ushort* __restrict__ WT,
    const float* __restrict__ bias, const float* __restrict__ st, float invN,
    float* __restrict__ out) {
  __shared__ short ring[4][66][32];
  __shared__ float s0[32], s1[32];
  const int tid = threadIdx.x;
  const int wv = tid >> 6, lane = tid & 63;
  const int quad = lane >> 4, ln15 = lane & 15;
  if (tid < 32) {
    float m = st[tid] * invN;
    float var = st[256 + tid] * invN - m * m;
    float s = rsqrtf(var + EPS_BN);
    s0[tid] = s;
    s1[tid] = m * s;
  }
  if (tid >= 32 && tid < 64) {
    const int t = tid - 32;
    const int slot = t >> 3, h = (t >> 2) & 1, kg = (t & 3) * 8;
    short8 z = {0, 0, 0, 0, 0, 0, 0, 0};
    *(short8*)&ring[slot][h ? 65 : 0][kg] = z;
  }
  short8 bfrag[9];
#pragma unroll
  for (int s = 0; s < 9; ++s)
    bfrag[s] = *(const short8*)&WT[((size_t)s * 64 + lane) * 8];
  __syncthreads();  // s0/s1 + halo zeros visible

  const int n = blockIdx.x >> 2;
  const int y0 = (blockIdx.x & 3) * 16;
  const ushort* xn = (const ushort*)X + (size_t)n * 131072;
  const int spx = tid >> 2, skg = (tid & 3) * 8;

  // prologue: stage rows y0-1, y0, y0+1
#pragma unroll
  for (int pr = 0; pr < 3; ++pr) {
    const int Y = y0 - 1 + pr;
    short8 o = {0, 0, 0, 0, 0, 0, 0, 0};
    if ((unsigned)Y < 64u) {
      const short8 raw = *(const short8*)&xn[((size_t)Y * 64 + spx) * 32 + skg];
#pragma unroll
      for (int u = 0; u < 8; ++u)
        o[u] = (short)f2bf(fmaf(bf2f((ushort)raw[u]), s0[skg + u], -s1[skg + u]));
    }
    *(short8*)&ring[Y & 3][spx + 1][skg] = o;
  }
  __syncthreads();

  const int x0 = wv * 16;
  const float bv = (ln15 < 3) ? bias[ln15] : 0.f;
  float* op = out + (size_t)n * 3 * 4096;

  for (int y = y0; y < y0 + 16; ++y) {
    // issue prefetch for row y+2 (needed up to y0+16)
    const int Ypf = y + 2;
    const bool pre = (Ypf <= y0 + 16);
    short8 raw;
    bool vld = false;
    if (pre && (unsigned)Ypf < 64u) {
      raw = *(const short8*)&xn[((size_t)Ypf * 64 + spx) * 32 + skg];
      vld = true;
    }

    // 9 MFMAs (2 accumulator chains)
    f32x4 acc0 = (f32x4){0.f, 0.f, 0.f, 0.f};
    f32x4 acc1 = (f32x4){0.f, 0.f, 0.f, 0.f};
#pragma unroll
    for (int ty = 0; ty < 3; ++ty) {
      const short* rp = &ring[(y - 1 + ty) & 3][0][0];
#pragma unroll
      for (int tx = 0; tx < 3; ++tx) {
        const short8 a = *(const short8*)&rp[(x0 + ln15 + tx) * 32 + quad * 8];
        const int s = ty * 3 + tx;
        if (s & 1)
          acc1 = __builtin_amdgcn_mfma_f32_16x16x32_bf16(a, bfrag[s], acc1, 0, 0, 0);
        else
          acc0 = __builtin_amdgcn_mfma_f32_16x16x32_bf16(a, bfrag[s], acc0, 0, 0, 0);
      }
    }

    // epilogue: logistic + float4 store (lanes n<3)
    if (ln15 < 3) {
      float4 o;
      float v;
      v = acc0[0] + acc1[0] + bv; o.x = 1.f / (1.f + __expf(-2.f * v));
      v = acc0[1] + acc1[1] + bv; o.y = 1.f / (1.f + __expf(-2.f * v));
      v = acc0[2] + acc1[2] + bv; o.z = 1.f / (1.f + __expf(-2.f * v));
      v = acc0[3] + acc1[3] + bv; o.w = 1.f / (1.f + __expf(-2.f * v));
      *(float4*)&op[(size_t)ln15 * 4096 + y * 64 + x0 + quad * 4] = o;
    }

    // write prefetched row into free ring slot
    if (pre) {
      short8 o = {0, 0, 0, 0, 0, 0, 0, 0};
      if (vld) {
#pragma unroll
        for (int u = 0; u < 8; ++u)
          o[u] = (short)f2bf(
              fmaf(bf2f((ushort)raw[u]), s0[skg + u], -s1[skg + u]));
      }
      *(short8*)&ring[Ypf & 3][spx + 1][skg] = o;
    }
    __syncthreads();
  }
}

// ======================= dense GEMM (fc / VQ distance), fp32 ===============
__global__ __launch_bounds__(256) void gemm_abt(
    const float* __restrict__ A, const float* __restrict__ B,
    const float* __restrict__ bias, const float* __restrict__ stA, float invN,
    float* __restrict__ C, float* __restrict__ P, int K, int ldc, int col0,
    float alpha, int act) {
  __shared__ float As[16][68];
  __shared__ float Bsh[16][68];
  __shared__ float nrm[2][256];
  const int tid = threadIdx.x;
  if (stA) {
    const int c = tid;
    float m = stA[c] * invN;
    float var = stA[256 + c] * invN - m * m;
    float s = rsqrtf(var + EPS_BN);
    nrm[0][c] = s;
    nrm[1][c] = m * s;
    __syncthreads();
  }
  const int lm = tid >> 2, lk = (tid & 3) << 2;
  const int KS = gridDim.z;
  const int kChunk = K / KS;
  const int kStart = blockIdx.z * kChunk;
  const float* Arow = A + (size_t)(blockIdx.y * 64 + lm) * K + lk;
  const float* Brow = B + (size_t)(blockIdx.x * 64 + lm) * K + lk;
  float acc[4][4] = {};
  const int m0 = (tid >> 4) << 2, n0 = (tid & 15) << 2;

  for (int k0 = kStart; k0 < kStart + kChunk; k0 += 16) {
    float4 av = *(const float4*)(Arow + k0);
    float4 bv = *(const float4*)(Brow + k0);
    if (stA) {
      const int ch = (k0 + lk) >> 4;
      const float s = nrm[0][ch], ms = nrm[1][ch];
      av.x = fmaf(av.x, s, -ms);
      av.y = fmaf(av.y, s, -ms);
      av.z = fmaf(av.z, s, -ms);
      av.w = fmaf(av.w, s, -ms);
    }
    As[lk + 0][lm] = av.x; As[lk + 1][lm] = av.y;
    As[lk + 2][lm] = av.z; As[lk + 3][lm] = av.w;
    Bsh[lk + 0][lm] = bv.x; Bsh[lk + 1][lm] = bv.y;
    Bsh[lk + 2][lm] = bv.z; Bsh[lk + 3][lm] = bv.w;
    __syncthreads();
#pragma unroll
    for (int kk = 0; kk < 16; ++kk) {
      const float4 a = *(const float4*)&As[kk][m0];
      const float4 b = *(const float4*)&Bsh[kk][n0];
      acc[0][0] = fmaf(a.x, b.x, acc[0][0]); acc[0][1] = fmaf(a.x, b.y, acc[0][1]);
      acc[0][2] = fmaf(a.x, b.z, acc[0][2]); acc[0][3] = fmaf(a.x, b.w, acc[0][3]);
      acc[1][0] = fmaf(a.y, b.x, acc[1][0]); acc[1][1] = fmaf(a.y, b.y, acc[1][1]);
      acc[1][2] = fmaf(a.y, b.z, acc[1][2]); acc[1][3] = fmaf(a.y, b.w, acc[1][3]);
      acc[2][0] = fmaf(a.z, b.x, acc[2][0]); acc[2][1] = fmaf(a.z, b.y, acc[2][1]);
      acc[2][2] = fmaf(a.z, b.z, acc[2][2]); acc[2][3] = fmaf(a.z, b.w, acc[2][3]);
      acc[3][0] = fmaf(a.w, b.x, acc[3][0]); acc[3][1] = fmaf(a.w, b.y, acc[3][1]);
      acc[3][2] = fmaf(a.w, b.z, acc[3][2]); acc[3][3] = fmaf(a.w, b.w, acc[3][3]);
    }
    __syncthreads();
  }

  const int gm = blockIdx.y * 64 + m0;
  const int gn = blockIdx.x * 64 + n0;
  if (KS == 1) {
#pragma unroll
    for (int i = 0; i < 4; ++i) {
      float4 o;
      o.x = alpha * acc[i][0] + bias[gn + 0];
      o.y = alpha * acc[i][1] + bias[gn + 1];
      o.z = alpha * acc[i][2] + bias[gn + 2];
      o.w = alpha * acc[i][3] + bias[gn + 3];
      if (act == 1) {
        o.x = fmaxf(o.x, 0.f); o.y = fmaxf(o.y, 0.f);
        o.z = fmaxf(o.z, 0.f); o.w = fmaxf(o.w, 0.f);
      }
      *(float4*)&C[(size_t)(gm + i) * ldc + col0 + gn] = o;
    }
  } else {
    const int M = gridDim.y * 64, N = gridDim.x * 64;
#pragma unroll
    for (int i = 0; i < 4; ++i)
      *(float4*)&P[((size_t)blockIdx.z * M + gm + i) * N + gn] =
          make_float4(acc[i][0], acc[i][1], acc[i][2], acc[i][3]);
  }
}

__global__ __launch_bounds__(256) void gemm_reduce(
    const float* __restrict__ P, float* __restrict__ C,
    const float* __restrict__ bias, int M, int N, int ldc, int col0,
    float alpha, int act, int KS) {
  const int idx = blockIdx.x * 256 + threadIdx.x;
  if (idx >= M * N) return;
  const int m = idx / N, n = idx % N;
  float s = 0.f;
  for (int z = 0; z < KS; ++z) s += P[((size_t)z * M + m) * N + n];
  float v = alpha * s + bias[n];
  if (act == 1) v = fmaxf(v, 0.f);
  C[(size_t)m * ldc + col0 + n] = v;
}

// ======================= VQ =================================================
__global__ __launch_bounds__(256) void rowsq(const float* __restrict__ cb,
                                             float* __restrict__ csq) {
  const int row = blockIdx.x * 4 + (threadIdx.x >> 6);
  const int ln = threadIdx.x & 63;
  const float4 v = ((const float4*)(cb + (size_t)row * 256))[ln];
  float s = v.x * v.x + v.y * v.y + v.z * v.z + v.w * v.w;
#pragma unroll
  for (int off = 32; off > 0; off >>= 1) s += __shfl_down(s, off);
  if (ln == 0) csq[row] = s;
}

__global__ __launch_bounds__(256) void argmin_d2(const float* __restrict__ d2,
                                                 int* __restrict__ idx) {
  const int b = blockIdx.x, t = threadIdx.x;
  const float* row = d2 + (size_t)b * 8192;
  float best = 3.4e38f;
  int bi = 0x7fffffff;
  for (int k = t; k < 8192; k += 256) {
    const float v = row[k];
    if (v < best) { best = v; bi = k; }
  }
  __shared__ float bval[256];
  __shared__ int bidx[256];
  bval[t] = best;
  bidx[t] = bi;
  __syncthreads();
  for (int s = 128; s > 0; s >>= 1) {
    if (t < s) {
      const float ov = bval[t + s];
      const int oi = bidx[t + s];
      if (ov < bval[t] || (ov == bval[t] && oi < bidx[t])) {
        bval[t] = ov;
        bidx[t] = oi;
      }
    }
    __syncthreads();
  }
  if (t == 0) idx[b] = bidx[0];
}

__global__ __launch_bounds__(256) void vq_gather_loss(
    const float* __restrict__ ze, const float* __restrict__ cb,
    const int* __restrict__ idx, float* __restrict__ zq,
    float* __restrict__ lossacc) {
  const int b = blockIdx.x, d = threadIdx.x;
  const int i = b * 256 + d;
  const float q = cb[(size_t)idx[b] * 256 + d];
  zq[i] = q;
  const float df = ze[i] - q;
  float v = df * df;
  __shared__ float sh[256];
  sh[d] = v;
  __syncthreads();
  for (int s = 128; s > 0; s >>= 1) {
    if (d < s) sh[d] += sh[d + s];
    __syncthreads();
  }
  if (d == 0) atomicAdd(lossacc, sh[0]);
}

__global__ void write_loss(const float* __restrict__ lossacc,
                           float* __restrict__ out) {
  out[0] = 2.f * lossacc[0];
}

// ---------------------------------------------------------------------------
extern "C" void kernel_launch(void* const* d_in, const int* in_sizes, int n_in,
                              void* d_out, int out_size, void* d_ws,
                              size_t ws_size, hipStream_t stream) {
  const float* x = (const float*)d_in[0];
  const float* ew1 = (const float*)d_in[1];
  const float* eb1 = (const float*)d_in[2];
  const float* ew2 = (const float*)d_in[3];
  const float* eb2 = (const float*)d_in[4];
  const float* ew3 = (const float*)d_in[5];
  const float* eb3 = (const float*)d_in[6];
  const float* ew4 = (const float*)d_in[7];
  const float* eb4 = (const float*)d_in[8];
  const float* wmu = (const float*)d_in[9];
  const float* bmu = (const float*)d_in[10];
  const float* wcov = (const float*)d_in[11];
  const float* bcov = (const float*)d_in[12];
  const float* cb = (const float*)d_in[13];
  const float* wfc = (const float*)d_in[14];
  const float* bfc = (const float*)d_in[15];
  const float* wt1 = (const float*)d_in[16];
  const float* bt1 = (const float*)d_in[17];
  const float* wt2 = (const float*)d_in[18];
  const float* bt2 = (const float*)d_in[19];
  const float* wt3 = (const float*)d_in[20];
  const float* bt3 = (const float*)d_in[21];
  const float* wt31 = (const float*)d_in[22];
  const float* bt31 = (const float*)d_in[23];
  const float* wt4 = (const float*)d_in[24];
  const float* bt4 = (const float*)d_in[25];

  float* ws = (float*)d_ws;
  float* a1 = ws;               // NHWC [256,32,32,32]  (reused as g3, bf16)
  float* a2 = a1 + 8388608;     // NHWC [256,16,16,64]  (reused as g2)
  float* a3 = a2 + 4194304;     // NHWC [256,8,8,128]   (reused as g1)
  float* a4 = a3 + 2097152;     // NHWC [256,4,4,256]   (reused as g0)
  float* g31 = a4 + 1048576;    // NHWC [256,64,64,32] bf16 (region 33554432 f)
  float* d2 = g31;              // [256,8192]
  float* P = g31 + 2097152;     // 262144
  float* csq = g31 + 2359296;   // 8192
  float* a4n = g31 + 2367488;   // NCHW a4 copy
  float* wfcT = g31 + 3416064;  // 1048576
  float* bfcT = g31 + 4464640;  // 4096
  ushort* wTc2 = (ushort*)(g31 + 4468736);  // 18432 bf16
  ushort* wTc3 = (ushort*)(g31 + 4487168);  // 73728 bf16
  ushort* wTc4 = (ushort*)(g31 + 4560896);  // 294912 bf16
  float* ze = g31 + 33554432;   // [256,256]
  float* zq = ze + 65536;
  float* stats = zq + 65536;    // 8 layers x 512
  float* lossacc = stats + 4096;
  int* idx = (int*)(lossacc + 4);
  ushort* wTt1 = (ushort*)(lossacc + 4 + 256);  // 294912 bf16 (parity)
  ushort* wTt2 = wTt1 + 294912;                 // 73728 bf16 (parity)
  ushort* wTt3 = wTt2 + 73728;                  // 18432 bf16 (tap-major,perm)
  ushort* wTt31 = wTt3 + 18432;                 // 9216 bf16 (tap-major,perm)
  ushort* wT4 = wTt31 + 9216;                   // 4608 bf16 (convt4 B frags)
  float* g3 = a1;   // bf16 content
  float* g2 = a2;
  float* g1 = a3;
  float* g0 = a4;

  float* st0 = stats + 0 * 512;
  float* st1 = stats + 1 * 512;
  float* st2 = stats + 2 * 512;
  float* st3 = stats + 3 * 512;
  float* st4 = stats + 4 * 512;
  float* st5 = stats + 5 * 512;
  float* st6 = stats + 6 * 512;
  float* st7 = stats + 7 * 512;

  hipMemsetAsync(stats, 0, (4096 + 8) * sizeof(float), stream);

  // ---- weight transposes (bf16) ----
  tr_convw_bf<<<72, 256, 0, stream>>>(ew2, wTc2, 32, 64, 18432);
  tr_convw_bf<<<288, 256, 0, stream>>>(ew3, wTc3, 64, 128, 73728);
  tr_convw_bf<<<1152, 256, 0, stream>>>(ew4, wTc4, 128, 256, 294912);
  tr_convtw_bf<<<1152, 256, 0, stream>>>(wt1, wTt1, 256, 128, 294912);
  tr_convtw_bf<<<288, 256, 0, stream>>>(wt2, wTt2, 128, 64, 73728);
  tr_convtw_tc<<<72, 256, 0, stream>>>(wt3, wTt3, 64, 32, 18432);
  tr_convtw_tc<<<36, 256, 0, stream>>>(wt31, wTt31, 32, 32, 9216);
  tr_w4<<<18, 256, 0, stream>>>(wt4, wT4);
  tr_fcdec<<<4096, 256, 0, stream>>>(wfc, bfc, wfcT, bfcT);
  rowsq<<<2048, 256, 0, stream>>>(cb, csq);

  // ---- encoder ----
  conv1<<<dim3(256, 8), 256, 0, stream>>>(x, ew1, eb1, a1, st0);
  mfmaconv<64, 0, 32, 32, 64, true><<<dim3(1, 1024), 256, 0, stream>>>(
      a1, wTc2, eb2, st0, 1.f / (256.f * 1024.f), a2, st1);
  mfmaconv<64, 0, 16, 64, 128, true><<<dim3(2, 256), 256, 0, stream>>>(
      a2, wTc3, eb3, st1, 1.f / (256.f * 256.f), a3, st2);
  mfmaconv<64, 0, 8, 128, 256, true><<<dim3(4, 64), 256, 0, stream>>>(
      a3, wTc4, eb4, st2, 1.f / (256.f * 64.f), a4, st3);
  tr_a4<<<4096, 256, 0, stream>>>(a4, a4n);

  // ---- encoder FC (fp32) ----
  gemm_abt<<<dim3(2, 4, 8), 256, 0, stream>>>(a4n, wmu, nullptr, st3,
                                              1.f / 4096.f, nullptr, P, 4096,
                                              0, 0, 1.f, 0);
  gemm_reduce<<<128, 256, 0, stream>>>(P, ze, bmu, 256, 128, 256, 0, 1.f, 0, 8);
  gemm_abt<<<dim3(2, 4, 8), 256, 0, stream>>>(a4n, wcov, nullptr, st3,
                                              1.f / 4096.f, nullptr, P, 4096,
                                              0, 0, 1.f, 0);
  gemm_reduce<<<128, 256, 0, stream>>>(P, ze, bcov, 256, 128, 256, 128, 1.f, 1, 8);

  // ---- VQ (fp32) ----
  gemm_abt<<<dim3(128, 4, 1), 256, 0, stream>>>(ze, cb, csq, nullptr, 0.f, d2,
                                                nullptr, 256, 8192, 0, -2.f, 0);
  argmin_d2<<<256, 256, 0, stream>>>(d2, idx);
  vq_gather_loss<<<256, 256, 0, stream>>>(ze, cb, idx, zq, lossacc);

  // ---- decoder FC (fp32) ----
  gemm_abt<<<dim3(64, 4, 1), 256, 0, stream>>>(zq, wfcT, bfcT, nullptr, 0.f,
                                               g0, nullptr, 256, 4096, 0, 1.f, 0);

  // ---- decoder ----
  mfmaconv<64, 1, 4, 256, 128, false><<<dim3(2, 64, 4), 256, 0, stream>>>(
      g0, wTt1, bt1, nullptr, 0.f, g1, st4);
  mfmaconv<64, 1, 8, 128, 64, true><<<dim3(1, 256, 4), 256, 0, stream>>>(
      g1, wTt2, bt2, st4, 1.f / (256.f * 64.f), g2, st5);
  convt_mfma<16, 64, true, false, 2><<<512, 256, 0, stream>>>(
      g2, wTt3, bt3, st5, 1.f / (256.f * 256.f), g3, st6);
  convt_mfma<32, 32, true, true, 4><<<1024, 256, 0, stream>>>(
      g3, wTt31, bt31, st6, 1.f / (256.f * 1024.f), g31, st7);

  convt4_mfma<<<1024, 256, 0, stream>>>(g31, wT4, bt4, st7,
                                        1.f / (256.f * 4096.f), (float*)d_out);
  write_loss<<<1, 1, 0, stream>>>(lossacc, (float*)d_out + 3145728);
}

// Round 4
// 557.395 us; speedup vs baseline: 1.1264x; 1.0234x over previous
//
#include <hip/hip_runtime.h>
#include <cmath>

// ---------------------------------------------------------------------------
// VQ-VAE forward. B=256, C=3, HW=64, D=256, K=8192, LAT=128
// R12: conv1 rewritten (conv1_bf): block = image x 8 output rows, all 32
// channels; input tile 3x17x67 fp32 staged coalesced into LDS once (odd
// stride -> conflict-free); weights [27][32] via uniform scalar loads; one
// thread = 1 px x 32 acc; output PACKED bf16 NHWC (full-line coalesced
// stores -> kills the 2x write RMW amplification of the old 8-block channel
// split). mfmaconv gains INBF for conv2. R11 convt4 MFMA ring, R10
// multi-strip convt_mfma, R9 packed-bf16 tail retained.
// ---------------------------------------------------------------------------

#define EPS_BN 1e-5f
typedef unsigned short ushort;
typedef short short8 __attribute__((ext_vector_type(8)));
typedef ushort us4 __attribute__((ext_vector_type(4)));
typedef float f32x4 __attribute__((ext_vector_type(4)));

__device__ __forceinline__ float lrelu(float v) { return v >= 0.f ? v : 0.01f * v; }
__device__ __forceinline__ ushort f2bf(float f) {
  unsigned u = __float_as_uint(f);
  return (ushort)((u + 0x7FFF + ((u >> 16) & 1)) >> 16);
}
__device__ __forceinline__ float bf2f(ushort u) {
  return __uint_as_float(((unsigned)u) << 16);
}

// ======================= weight transposes (once per launch) ===============
// conv (COUT,CIN,3,3) -> bf16 [co][t*CIN+ci]
__global__ __launch_bounds__(256) void tr_convw_bf(const float* __restrict__ w,
                                                   ushort* __restrict__ wT,
                                                   int CIN, int COUT, int total) {
  int i = blockIdx.x * 256 + threadIdx.x;
  if (i >= total) return;
  int co = i / (9 * CIN);
  int r = i - co * 9 * CIN;
  int t = r / CIN, ci = r - t * CIN;
  wT[i] = f2bf(w[((size_t)co * CIN + ci) * 9 + t]);
}

// convT (CIN,COUT,3,3) -> bf16 parity-concat [p][co][k]
__global__ __launch_bounds__(256) void tr_convtw_bf(const float* __restrict__ w,
                                                    ushort* __restrict__ wT,
                                                    int CIN, int COUT, int total) {
  int i = blockIdx.x * 256 + threadIdx.x;
  if (i >= total) return;
  const int cc = CIN * COUT;
  int p, base, Kp;
  if (i < cc) { p = 0; base = 0; Kp = CIN; }
  else if (i < 3 * cc) { p = 1; base = cc; Kp = 2 * CIN; }
  else if (i < 5 * cc) { p = 2; base = 3 * cc; Kp = 2 * CIN; }
  else { p = 3; base = 5 * cc; Kp = 4 * CIN; }
  const int r = i - base;
  const int co = r / Kp;
  const int q = r - co * Kp;
  const int tix = q / CIN, ci = q - (q / CIN) * CIN;
  const int py = p >> 1, px = p & 1;
  const int nx = px ? 2 : 1;
  const int kyi = tix / nx, kxi = tix - kyi * nx;
  const int ky = py ? (kyi == 0 ? 0 : 2) : 1;
  const int kx = px ? (kxi == 0 ? 0 : 2) : 1;
  wT[i] = f2bf(w[((size_t)ci * COUT + co) * 9 + ky * 3 + kx]);
}

// convT (CIN,COUT=32,3,3) -> bf16 [t][co_slot][ci] (tap-major, columns
// PERMUTED so slot f*16+ln15 holds channel 2*ln15+f -> packed bf16 stores)
__global__ __launch_bounds__(256) void tr_convtw_tc(const float* __restrict__ w,
                                                    ushort* __restrict__ wT,
                                                    int CIN, int COUT, int total) {
  int i = blockIdx.x * 256 + threadIdx.x;
  if (i >= total) return;
  int ci = i % CIN;
  int tmp = i / CIN;
  int co = tmp % COUT;
  int t = tmp / COUT;
  const int co_slot = ((co & 1) << 4) | (co >> 1);
  wT[((size_t)t * COUT + co_slot) * CIN + ci] =
      f2bf(w[((size_t)ci * COUT + co) * 9 + t]);
}

// convt4 weights (CIN=32, COUT=3, 3,3) -> per-lane B fragments
__global__ __launch_bounds__(256) void tr_w4(const float* __restrict__ w,
                                             ushort* __restrict__ wT) {
  int i = blockIdx.x * 256 + threadIdx.x;
  if (i >= 4608) return;
  const int s = i >> 9;
  const int l = (i >> 3) & 63;
  const int j = i & 7;
  const int nn = l & 15;
  const int ci = ((l >> 4) << 3) + j;
  const int ty = s / 3, tx = s - ty * 3;
  ushort v = 0;
  if (nn < 3)
    v = f2bf(w[((size_t)ci * 3 + nn) * 9 + (2 - ty) * 3 + (2 - tx)]);
  wT[i] = v;
}

// conv1 weights (32,3,3,3) -> fp32 [t=(ci*3+ky)*3+kx][co]
__global__ __launch_bounds__(256) void tr_w1(const float* __restrict__ w,
                                             float* __restrict__ wc) {
  int i = blockIdx.x * 256 + threadIdx.x;
  if (i >= 864) return;
  const int co = i & 31, t = i >> 5;
  const int ci = t / 9, r = t - ci * 9;
  wc[i] = w[((size_t)co * 3 + ci) * 9 + r];
}

// a4 NHWC [256,4,4,256] -> NCHW [256,256,4,4]
__global__ __launch_bounds__(256) void tr_a4(const float* __restrict__ in,
                                             float* __restrict__ out) {
  int i = blockIdx.x * 256 + threadIdx.x;
  int n = i >> 12, k = i & 4095;
  out[i] = in[(size_t)(n << 12) + ((k & 15) << 8) + (k >> 4)];
}

// wfc [4096,256] + bfc: permute ROWS from (c,y,x) to (y,x,c)
__global__ __launch_bounds__(256) void tr_fcdec(const float* __restrict__ in,
                                                const float* __restrict__ bin,
                                                float* __restrict__ out,
                                                float* __restrict__ bout) {
  int i = blockIdx.x * 256 + threadIdx.x;
  int k = i >> 8, d = i & 255;
  int kp = (k & 15) * 256 + (k >> 4);
  out[(size_t)kp * 256 + d] = in[i];
  if (d == 0) bout[kp] = bin[k];
}

// ======================= bf16 MFMA implicit-GEMM conv / convT ==============
template <int TN, int MODE, int IH, int CIN, int COUT, bool HASN, bool INBF>
__global__ __launch_bounds__(256) void mfmaconv(
    const float* __restrict__ X, const ushort* __restrict__ WT,
    const float* __restrict__ bias, const float* __restrict__ st, float invN,
    float* __restrict__ Y, float* __restrict__ stOut) {
  constexpr int OH = (MODE == 0) ? IH / 2 : 2 * IH;
  constexpr int NF = TN / 16;
  __shared__ short As[64][40];
  __shared__ short Bs[TN][40];
  __shared__ float nrm0[HASN ? CIN : 4], nrm1[HASN ? CIN : 4];
  __shared__ float redS[4][TN], redQ[4][TN];
  const int tid = threadIdx.x;
  const int wv = tid >> 6, lane = tid & 63;
  const int quad = lane >> 4, ln15 = tid & 15;
  if (HASN) {
    for (int c = tid; c < CIN; c += 256) {
      float m = st[c] * invN;
      float var = st[256 + c] * invN - m * m;
      float s = rsqrtf(var + EPS_BN);
      nrm0[c] = s;
      nrm1[c] = m * s;
    }
    __syncthreads();
  }
  int py = 0, px = 0, nx = 1, K = 9 * CIN;
  const ushort* W = WT;
  if (MODE == 1) {
    const int pz = blockIdx.z;
    py = pz >> 1;
    px = pz & 1;
    nx = px ? 2 : 1;
    const int ny = py ? 2 : 1;
    K = ny * nx * CIN;
    const int pre[4] = {0, 1, 3, 5};
    W = WT + (size_t)pre[pz] * CIN * COUT;
  }
  const int gyTM = blockIdx.y * 64;
  const int gxTN = blockIdx.x * TN;

  const int sm = tid & 63, skg = (tid >> 6) * 8;
  int baseNB, baseIY, baseIX;
  {
    const int gm = gyTM + sm;
    if (MODE == 0) {
      const int ni = gm / (OH * OH), r = gm % (OH * OH);
      baseNB = ni * IH * IH;
      baseIY = 2 * (r / OH) - 1;
      baseIX = 2 * (r % OH) - 1;
    } else {
      const int ni = gm / (IH * IH), r = gm % (IH * IH);
      baseNB = ni * IH * IH;
      baseIY = r / IH;
      baseIX = r % IH;
    }
  }
  f32x4 acc[NF];
#pragma unroll
  for (int f = 0; f < NF; ++f) acc[f] = (f32x4){0.f, 0.f, 0.f, 0.f};

  for (int k0 = 0; k0 < K; k0 += 32) {
    const int t = k0 / CIN;
    const int ci0 = k0 - t * CIN;
    int iy, ix;
    if (MODE == 0) {
      iy = baseIY + t / 3;
      ix = baseIX + (t - (t / 3) * 3);
    } else {
      const int kyi = t / nx, kxi = t - (t / nx) * nx;
      iy = baseIY + ((py && kyi == 0) ? 1 : 0);
      ix = baseIX + ((px && kxi == 0) ? 1 : 0);
    }
    {
      const bool ok =
          ((unsigned)iy < (unsigned)IH) && ((unsigned)ix < (unsigned)IH);
      float v[8] = {0.f, 0.f, 0.f, 0.f, 0.f, 0.f, 0.f, 0.f};
      if (ok) {
        if constexpr (INBF) {
          const ushort* xp = (const ushort*)X +
                             ((size_t)baseNB + iy * IH + ix) * CIN + ci0 + skg;
          const short8 raw = *(const short8*)xp;
#pragma unroll
          for (int u = 0; u < 8; ++u) v[u] = bf2f((ushort)raw[u]);
        } else {
          const float* xp =
              &X[((size_t)baseNB + iy * IH + ix) * CIN + ci0 + skg];
          const float4 va = *(const float4*)xp, vb = *(const float4*)(xp + 4);
          v[0] = va.x; v[1] = va.y; v[2] = va.z; v[3] = va.w;
          v[4] = vb.x; v[5] = vb.y; v[6] = vb.z; v[7] = vb.w;
        }
        if (HASN) {
          const int c = ci0 + skg;
#pragma unroll
          for (int u = 0; u < 8; ++u)
            v[u] = fmaf(v[u], nrm0[c + u], -nrm1[c + u]);
        }
      }
      short8 o;
#pragma unroll
      for (int u = 0; u < 8; ++u) o[u] = (short)f2bf(v[u]);
      *(short8*)&As[sm][skg] = o;
    }
    if (tid < TN * 4) {
      const int bn = tid >> 2, bkg = (tid & 3) * 8;
      *(short8*)&Bs[bn][bkg] =
          *(const short8*)&W[(size_t)(gxTN + bn) * K + k0 + bkg];
    }
    __syncthreads();
    const short8 a = *(const short8*)&As[wv * 16 + ln15][quad * 8];
#pragma unroll
    for (int f = 0; f < NF; ++f) {
      const short8 b = *(const short8*)&Bs[f * 16 + ln15][quad * 8];
      acc[f] = __builtin_amdgcn_mfma_f32_16x16x32_bf16(a, b, acc[f], 0, 0, 0);
    }
    __syncthreads();
  }

  size_t maddr[4];
#pragma unroll
  for (int r = 0; r < 4; ++r) {
    const int m = gyTM + wv * 16 + quad * 4 + r;
    if (MODE == 0) {
      const int ni = m / (OH * OH), rr = m % (OH * OH);
      maddr[r] = (((size_t)ni * OH + rr / OH) * OH + rr % OH) * COUT;
    } else {
      const int ni = m / (IH * IH), rr = m % (IH * IH);
      const int oy = 2 * (rr / IH) + py, ox = 2 * (rr % IH) + px;
      maddr[r] = (((size_t)ni * OH + oy) * OH + ox) * COUT;
    }
  }
#pragma unroll
  for (int f = 0; f < NF; ++f) {
    const int col = gxTN + f * 16 + ln15;
    const float bv = bias[col];
    float cS = 0.f, cQ = 0.f;
#pragma unroll
    for (int r = 0; r < 4; ++r) {
      const float o = lrelu(acc[f][r] + bv);
      cS += o;
      cQ += o * o;
      Y[maddr[r] + col] = o;
    }
    cS += __shfl_down(cS, 32); cS += __shfl_down(cS, 16);
    cQ += __shfl_down(cQ, 32); cQ += __shfl_down(cQ, 16);
    if (lane < 16) { redS[wv][f * 16 + ln15] = cS; redQ[wv][f * 16 + ln15] = cQ; }
  }
  __syncthreads();
  if (tid < TN) {
    float S = redS[0][tid] + redS[1][tid] + redS[2][tid] + redS[3][tid];
    float Q = redQ[0][tid] + redQ[1][tid] + redQ[2][tid] + redQ[3][tid];
    atomicAdd(&stOut[gxTN + tid], S);
    atomicAdd(&stOut[256 + gxTN + tid], Q);
  }
}

// ======================= halo-tile merged convT (COUT=32, CIN<=64) =========
// Multi-strip software pipeline (R10). Output = packed bf16.
template <int IH, int CIN, bool HASN, bool INBF, int NSTRIP>
__global__ __launch_bounds__(256) void convt_mfma(
    const float* __restrict__ X, const ushort* __restrict__ WT,
    const float* __restrict__ bias, const float* __restrict__ st, float invN,
    float* __restrict__ Y, float* __restrict__ stOut) {
  constexpr int OH = 2 * IH;
  constexpr int L = (IH == 32) ? 5 : 4;
  constexpr int RSPAN = 64 / IH;
  constexpr int NP = (RSPAN + 1) * (IH + 1);
  constexpr int LK = CIN + 8;
  constexpr int TI = NP * (CIN / 8);
  constexpr int ITER = (TI + 255) / 256;
  __shared__ short As[2][NP][LK];
  __shared__ short Ws[9 * 32][LK];
  __shared__ float nrm0[HASN ? CIN : 4], nrm1[HASN ? CIN : 4];
  __shared__ float redS[4][32], redQ[4][32];
  const int tid = threadIdx.x;
  const int wv = tid >> 6, lane = tid & 63;
  const int quad = lane >> 4, ln15 = lane & 15;
  if (HASN) {
    for (int c = tid; c < CIN; c += 256) {
      float m = st[c] * invN;
      float var = st[256 + c] * invN - m * m;
      float s = rsqrtf(var + EPS_BN);
      nrm0[c] = s;
      nrm1[c] = m * s;
    }
  }
  for (int i = tid; i < 9 * 32 * (CIN / 8); i += 256) {
    const int row = i / (CIN / 8), kg = (i % (CIN / 8)) * 8;
    *(short8*)&Ws[row][kg] = *(const short8*)&WT[(size_t)row * CIN + kg];
  }
  __syncthreads();

  const int strip0 = blockIdx.x * NSTRIP;
  const int n = (strip0 * 64) / (IH * IH);
  const int iy0base = (strip0 * 64 - n * (IH * IH)) >> L;

#pragma unroll
  for (int it = 0; it < ITER; ++it) {
    const int i = tid + it * 256;
    if (i < TI) {
      const int slot = i / (CIN / 8), kg = (i % (CIN / 8)) * 8;
      const int ty = slot / (IH + 1), tx = slot - ty * (IH + 1);
      const int iy = iy0base + ty;
      short8 o = {0, 0, 0, 0, 0, 0, 0, 0};
      if (iy < IH && tx < IH) {
        float v[8];
        if constexpr (INBF) {
          const ushort* xp =
              (const ushort*)X + (((size_t)n * IH + iy) * IH + tx) * CIN + kg;
          const short8 raw = *(const short8*)xp;
#pragma unroll
          for (int u = 0; u < 8; ++u) v[u] = bf2f((ushort)raw[u]);
        } else {
          const float* xp = &X[(((size_t)n * IH + iy) * IH + tx) * CIN + kg];
          const float4 va = *(const float4*)xp, vb = *(const float4*)(xp + 4);
          v[0] = va.x; v[1] = va.y; v[2] = va.z; v[3] = va.w;
          v[4] = vb.x; v[5] = vb.y; v[6] = vb.z; v[7] = vb.w;
        }
        if (HASN) {
#pragma unroll
          for (int u = 0; u < 8; ++u)
            v[u] = fmaf(v[u], nrm0[kg + u], -nrm1[kg + u]);
        }
#pragma unroll
        for (int u = 0; u < 8; ++u) o[u] = (short)f2bf(v[u]);
      }
      *(short8*)&As[0][slot][kg] = o;
    }
  }
  __syncthreads();

  const int rA = wv * 16 + ln15;
  const int baseIdx = (rA >> L) * (IH + 1) + (rA & (IH - 1));
  constexpr int NT[4] = {4, 2, 2, 1};
  constexpr int TT[4][4] = {{4, 5, 7, 8}, {3, 6, 0, 0}, {1, 2, 0, 0}, {0, 0, 0, 0}};
  const float bv0 = bias[2 * ln15], bv1 = bias[2 * ln15 + 1];
  unsigned* Yp = (unsigned*)Y;
  float cS[2] = {0.f, 0.f}, cQ[2] = {0.f, 0.f};

#pragma unroll
  for (int s = 0; s < NSTRIP; ++s) {
    const int cur = s & 1, nxt = cur ^ 1;
    const int iy0 = iy0base + s * RSPAN;

    short8 rbf[ITER];
    float4 rva[ITER], rvb[ITER];
    bool vld[ITER];
    if (s + 1 < NSTRIP) {
      const int iyN0 = iy0 + RSPAN;
#pragma unroll
      for (int it = 0; it < ITER; ++it) {
        vld[it] = false;
        const int i = tid + it * 256;
        if (i < TI) {
          const int slot = i / (CIN / 8), kg = (i % (CIN / 8)) * 8;
          const int ty = slot / (IH + 1), tx = slot - ty * (IH + 1);
          const int iy = iyN0 + ty;
          if (iy < IH && tx < IH) {
            vld[it] = true;
            if constexpr (INBF) {
              const ushort* xp = (const ushort*)X +
                                 (((size_t)n * IH + iy) * IH + tx) * CIN + kg;
              rbf[it] = *(const short8*)xp;
            } else {
              const float* xp =
                  &X[(((size_t)n * IH + iy) * IH + tx) * CIN + kg];
              rva[it] = *(const float4*)xp;
              rvb[it] = *(const float4*)(xp + 4);
            }
          }
        }
      }
    }

    f32x4 acc[4][2];
#pragma unroll
    for (int p = 0; p < 4; ++p)
#pragma unroll
      for (int f = 0; f < 2; ++f) acc[p][f] = (f32x4){0.f, 0.f, 0.f, 0.f};
#pragma unroll
    for (int sh = 0; sh < 4; ++sh) {
      const int off = (sh >> 1) * (IH + 1) + (sh & 1);
#pragma unroll
      for (int j = 0; j < NT[sh]; ++j) {
        const int t = TT[sh][j];
        const int ky = t / 3, kx = t - ky * 3;
        const int par = ((ky == 1) ? 0 : 2) + ((kx == 1) ? 0 : 1);
#pragma unroll
        for (int ks = 0; ks < CIN / 32; ++ks) {
          const short8 a =
              *(const short8*)&As[cur][baseIdx + off][ks * 32 + quad * 8];
#pragma unroll
          for (int f = 0; f < 2; ++f) {
            const short8 b =
                *(const short8*)&Ws[t * 32 + f * 16 + ln15][ks * 32 + quad * 8];
            acc[par][f] = __builtin_amdgcn_mfma_f32_16x16x32_bf16(
                a, b, acc[par][f], 0, 0, 0);
          }
        }
      }
    }

#pragma unroll
    for (int i = 0; i < 4; ++i) {
      const int rD = wv * 16 + quad * 4 + i;
      const int ry = rD >> L, rx = rD & (IH - 1);
      const int iy = iy0 + ry;
#pragma unroll
      for (int p = 0; p < 4; ++p) {
        const int a = p >> 1, b = p & 1;
        const size_t base =
            (((size_t)n * OH + 2 * iy + a) * OH + 2 * rx + b) * 32;
        const float o0 = lrelu(acc[p][0][i] + bv0);
        const float o1 = lrelu(acc[p][1][i] + bv1);
        cS[0] += o0; cQ[0] += o0 * o0;
        cS[1] += o1; cQ[1] += o1 * o1;
        Yp[(base >> 1) + ln15] = (unsigned)f2bf(o0) | ((unsigned)f2bf(o1) << 16);
      }
    }

    if (s + 1 < NSTRIP) {
#pragma unroll
      for (int it = 0; it < ITER; ++it) {
        const int i = tid + it * 256;
        if (i < TI) {
          const int slot = i / (CIN / 8), kg = (i % (CIN / 8)) * 8;
          short8 o = {0, 0, 0, 0, 0, 0, 0, 0};
          if (vld[it]) {
            float v[8];
            if constexpr (INBF) {
#pragma unroll
              for (int u = 0; u < 8; ++u) v[u] = bf2f((ushort)rbf[it][u]);
            } else {
              v[0] = rva[it].x; v[1] = rva[it].y;
              v[2] = rva[it].z; v[3] = rva[it].w;
              v[4] = rvb[it].x; v[5] = rvb[it].y;
              v[6] = rvb[it].z; v[7] = rvb[it].w;
            }
            if (HASN) {
#pragma unroll
              for (int u = 0; u < 8; ++u)
                v[u] = fmaf(v[u], nrm0[kg + u], -nrm1[kg + u]);
            }
#pragma unroll
            for (int u = 0; u < 8; ++u) o[u] = (short)f2bf(v[u]);
          }
          *(short8*)&As[nxt][slot][kg] = o;
        }
      }
    }
    __syncthreads();
  }

#pragma unroll
  for (int f = 0; f < 2; ++f) {
    float s_ = cS[f], q_ = cQ[f];
    s_ += __shfl_down(s_, 32); s_ += __shfl_down(s_, 16);
    q_ += __shfl_down(q_, 32); q_ += __shfl_down(q_, 16);
    if (lane < 16) { redS[wv][f * 16 + ln15] = s_; redQ[wv][f * 16 + ln15] = q_; }
  }
  __syncthreads();
  if (tid < 32) {
    float S = redS[0][tid] + redS[1][tid] + redS[2][tid] + redS[3][tid];
    float Q = redQ[0][tid] + redQ[1][tid] + redQ[2][tid] + redQ[3][tid];
    const int ch = ((tid & 15) << 1) | (tid >> 4);
    atomicAdd(&stOut[ch], S);
    atomicAdd(&stOut[256 + ch], Q);
  }
}

// ======================= conv1 (CIN=3) full-channel LDS-tiled, bf16 out ====
// Block = image x 8 output rows, 256 threads = 1 px each, all 32 channels.
// Input tile 3x17x67 fp32 in LDS (odd stride -> 2-way conflicts only).
// Weights [27][32] fp32 read via uniform scalar loads. Output packed bf16
// NHWC (64B/thread contiguous). Stats fp32 pre-rounding.
__global__ __launch_bounds__(256) void conv1_bf(
    const float* __restrict__ x, const float* __restrict__ wc,
    const float* __restrict__ bias, ushort* __restrict__ y,
    float* __restrict__ st) {
  __shared__ float xin[3][17][67];
  __shared__ float redS[4][32], redQ[4][32];
  const int tid = threadIdx.x;
  const int wv = tid >> 6, lane = tid & 63;
  const int n = blockIdx.x >> 2;
  const int oy0 = (blockIdx.x & 3) * 8;
  const int iy0 = 2 * oy0 - 1;
  if (tid < 51) {  // zero halo col 0 (3*17)
    const int ci = tid / 17, r = tid - ci * 17;
    xin[ci][r][0] = 0.f;
  }
  for (int i = tid; i < 816; i += 256) {
    const int ci = i / 272;
    const int r = (i - ci * 272) >> 4;
    const int c4 = (i & 15) << 2;
    const int iy = iy0 + r;
    float4 v = make_float4(0.f, 0.f, 0.f, 0.f);
    if ((unsigned)iy < 64u)
      v = *(const float4*)&x[((size_t)(n * 3 + ci) * 64 + iy) * 64 + c4];
    xin[ci][r][1 + c4] = v.x;
    xin[ci][r][2 + c4] = v.y;
    xin[ci][r][3 + c4] = v.z;
    xin[ci][r][4 + c4] = v.w;
  }
  __syncthreads();
  const int py = tid >> 5, px = tid & 31;
  float acc[32];
#pragma unroll
  for (int c = 0; c < 32; ++c) acc[c] = 0.f;
#pragma unroll
  for (int ci = 0; ci < 3; ++ci)
#pragma unroll
    for (int ky = 0; ky < 3; ++ky)
#pragma unroll
      for (int kx = 0; kx < 3; ++kx) {
        const float v = xin[ci][2 * py + ky][2 * px + kx];
        const int t = (ci * 3 + ky) * 3 + kx;
#pragma unroll
        for (int c = 0; c < 32; ++c)
          acc[c] = fmaf(v, wc[t * 32 + c], acc[c]);
      }
#pragma unroll
  for (int c = 0; c < 32; ++c) acc[c] = lrelu(acc[c] + bias[c]);
  // packed bf16 store (64B contiguous per thread)
  {
    ushort* yp = y + (((size_t)n * 1024 + (oy0 + py) * 32 + px) << 5);
#pragma unroll
    for (int j = 0; j < 4; ++j) {
      uint4 o;
      o.x = (unsigned)f2bf(acc[8 * j + 0]) | ((unsigned)f2bf(acc[8 * j + 1]) << 16);
      o.y = (unsigned)f2bf(acc[8 * j + 2]) | ((unsigned)f2bf(acc[8 * j + 3]) << 16);
      o.z = (unsigned)f2bf(acc[8 * j + 4]) | ((unsigned)f2bf(acc[8 * j + 5]) << 16);
      o.w = (unsigned)f2bf(acc[8 * j + 6]) | ((unsigned)f2bf(acc[8 * j + 7]) << 16);
      *(uint4*)&yp[j * 8] = o;
    }
  }
  // per-channel stats: wave shuffle reduce, then block reduce + atomics
#pragma unroll
  for (int c = 0; c < 32; ++c) {
    float s_ = acc[c], q_ = acc[c] * acc[c];
#pragma unroll
    for (int off = 32; off > 0; off >>= 1) {
      s_ += __shfl_down(s_, off);
      q_ += __shfl_down(q_, off);
    }
    if (lane == 0) { redS[wv][c] = s_; redQ[wv][c] = q_; }
  }
  __syncthreads();
  if (tid < 32) {
    float S = redS[0][tid] + redS[1][tid] + redS[2][tid] + redS[3][tid];
    float Q = redQ[0][tid] + redQ[1][tid] + redQ[2][tid] + redQ[3][tid];
    atomicAdd(&st[tid], S);
    atomicAdd(&st[256 + tid], Q);
  }
}

// ======================= final convT via MFMA + 4-row LDS ring =============
__global__ __launch_bounds__(256) void convt4_mfma(
    const float* __restrict__ X, const ushort* __restrict__ WT,
    const float* __restrict__ bias, const float* __restrict__ st, float invN,
    float* __restrict__ out) {
  __shared__ short ring[4][66][32];
  __shared__ float s0[32], s1[32];
  const int tid = threadIdx.x;
  const int wv = tid >> 6, lane = tid & 63;
  const int quad = lane >> 4, ln15 = lane & 15;
  if (tid < 32) {
    float m = st[tid] * invN;
    float var = st[256 + tid] * invN - m * m;
    float s = rsqrtf(var + EPS_BN);
    s0[tid] = s;
    s1[tid] = m * s;
  }
  if (tid >= 32 && tid < 64) {
    const int t = tid - 32;
    const int slot = t >> 3, h = (t >> 2) & 1, kg = (t & 3) * 8;
    short8 z = {0, 0, 0, 0, 0, 0, 0, 0};
    *(short8*)&ring[slot][h ? 65 : 0][kg] = z;
  }
  short8 bfrag[9];
#pragma unroll
  for (int s = 0; s < 9; ++s)
    bfrag[s] = *(const short8*)&WT[((size_t)s * 64 + lane) * 8];
  __syncthreads();

  const int n = blockIdx.x >> 2;
  const int y0 = (blockIdx.x & 3) * 16;
  const ushort* xn = (const ushort*)X + (size_t)n * 131072;
  const int spx = tid >> 2, skg = (tid & 3) * 8;

#pragma unroll
  for (int pr = 0; pr < 3; ++pr) {
    const int Y = y0 - 1 + pr;
    short8 o = {0, 0, 0, 0, 0, 0, 0, 0};
    if ((unsigned)Y < 64u) {
      const short8 raw = *(const short8*)&xn[((size_t)Y * 64 + spx) * 32 + skg];
#pragma unroll
      for (int u = 0; u < 8; ++u)
        o[u] = (short)f2bf(fmaf(bf2f((ushort)raw[u]), s0[skg + u], -s1[skg + u]));
    }
    *(short8*)&ring[Y & 3][spx + 1][skg] = o;
  }
  __syncthreads();

  const int x0 = wv * 16;
  const float bv = (ln15 < 3) ? bias[ln15] : 0.f;
  float* op = out + (size_t)n * 3 * 4096;

  for (int y = y0; y < y0 + 16; ++y) {
    const int Ypf = y + 2;
    const bool pre = (Ypf <= y0 + 16);
    short8 raw;
    bool vld = false;
    if (pre && (unsigned)Ypf < 64u) {
      raw = *(const short8*)&xn[((size_t)Ypf * 64 + spx) * 32 + skg];
      vld = true;
    }

    f32x4 acc0 = (f32x4){0.f, 0.f, 0.f, 0.f};
    f32x4 acc1 = (f32x4){0.f, 0.f, 0.f, 0.f};
#pragma unroll
    for (int ty = 0; ty < 3; ++ty) {
      const short* rp = &ring[(y - 1 + ty) & 3][0][0];
#pragma unroll
      for (int tx = 0; tx < 3; ++tx) {
        const short8 a = *(const short8*)&rp[(x0 + ln15 + tx) * 32 + quad * 8];
        const int s = ty * 3 + tx;
        if (s & 1)
          acc1 = __builtin_amdgcn_mfma_f32_16x16x32_bf16(a, bfrag[s], acc1, 0, 0, 0);
        else
          acc0 = __builtin_amdgcn_mfma_f32_16x16x32_bf16(a, bfrag[s], acc0, 0, 0, 0);
      }
    }

    if (ln15 < 3) {
      float4 o;
      float v;
      v = acc0[0] + acc1[0] + bv; o.x = 1.f / (1.f + __expf(-2.f * v));
      v = acc0[1] + acc1[1] + bv; o.y = 1.f / (1.f + __expf(-2.f * v));
      v = acc0[2] + acc1[2] + bv; o.z = 1.f / (1.f + __expf(-2.f * v));
      v = acc0[3] + acc1[3] + bv; o.w = 1.f / (1.f + __expf(-2.f * v));
      *(float4*)&op[(size_t)ln15 * 4096 + y * 64 + x0 + quad * 4] = o;
    }

    if (pre) {
      short8 o = {0, 0, 0, 0, 0, 0, 0, 0};
      if (vld) {
#pragma unroll
        for (int u = 0; u < 8; ++u)
          o[u] = (short)f2bf(
              fmaf(bf2f((ushort)raw[u]), s0[skg + u], -s1[skg + u]));
      }
      *(short8*)&ring[Ypf & 3][spx + 1][skg] = o;
    }
    __syncthreads();
  }
}

// ======================= dense GEMM (fc / VQ distance), fp32 ===============
__global__ __launch_bounds__(256) void gemm_abt(
    const float* __restrict__ A, const float* __restrict__ B,
    const float* __restrict__ bias, const float* __restrict__ stA, float invN,
    float* __restrict__ C, float* __restrict__ P, int K, int ldc, int col0,
    float alpha, int act) {
  __shared__ float As[16][68];
  __shared__ float Bsh[16][68];
  __shared__ float nrm[2][256];
  const int tid = threadIdx.x;
  if (stA) {
    const int c = tid;
    float m = stA[c] * invN;
    float var = stA[256 + c] * invN - m * m;
    float s = rsqrtf(var + EPS_BN);
    nrm[0][c] = s;
    nrm[1][c] = m * s;
    __syncthreads();
  }
  const int lm = tid >> 2, lk = (tid & 3) << 2;
  const int KS = gridDim.z;
  const int kChunk = K / KS;
  const int kStart = blockIdx.z * kChunk;
  const float* Arow = A + (size_t)(blockIdx.y * 64 + lm) * K + lk;
  const float* Brow = B + (size_t)(blockIdx.x * 64 + lm) * K + lk;
  float acc[4][4] = {};
  const int m0 = (tid >> 4) << 2, n0 = (tid & 15) << 2;

  for (int k0 = kStart; k0 < kStart + kChunk; k0 += 16) {
    float4 av = *(const float4*)(Arow + k0);
    float4 bv = *(const float4*)(Brow + k0);
    if (stA) {
      const int ch = (k0 + lk) >> 4;
      const float s = nrm[0][ch], ms = nrm[1][ch];
      av.x = fmaf(av.x, s, -ms);
      av.y = fmaf(av.y, s, -ms);
      av.z = fmaf(av.z, s, -ms);
      av.w = fmaf(av.w, s, -ms);
    }
    As[lk + 0][lm] = av.x; As[lk + 1][lm] = av.y;
    As[lk + 2][lm] = av.z; As[lk + 3][lm] = av.w;
    Bsh[lk + 0][lm] = bv.x; Bsh[lk + 1][lm] = bv.y;
    Bsh[lk + 2][lm] = bv.z; Bsh[lk + 3][lm] = bv.w;
    __syncthreads();
#pragma unroll
    for (int kk = 0; kk < 16; ++kk) {
      const float4 a = *(const float4*)&As[kk][m0];
      const float4 b = *(const float4*)&Bsh[kk][n0];
      acc[0][0] = fmaf(a.x, b.x, acc[0][0]); acc[0][1] = fmaf(a.x, b.y, acc[0][1]);
      acc[0][2] = fmaf(a.x, b.z, acc[0][2]); acc[0][3] = fmaf(a.x, b.w, acc[0][3]);
      acc[1][0] = fmaf(a.y, b.x, acc[1][0]); acc[1][1] = fmaf(a.y, b.y, acc[1][1]);
      acc[1][2] = fmaf(a.y, b.z, acc[1][2]); acc[1][3] = fmaf(a.y, b.w, acc[1][3]);
      acc[2][0] = fmaf(a.z, b.x, acc[2][0]); acc[2][1] = fmaf(a.z, b.y, acc[2][1]);
      acc[2][2] = fmaf(a.z, b.z, acc[2][2]); acc[2][3] = fmaf(a.z, b.w, acc[2][3]);
      acc[3][0] = fmaf(a.w, b.x, acc[3][0]); acc[3][1] = fmaf(a.w, b.y, acc[3][1]);
      acc[3][2] = fmaf(a.w, b.z, acc[3][2]); acc[3][3] = fmaf(a.w, b.w, acc[3][3]);
    }
    __syncthreads();
  }

  const int gm = blockIdx.y * 64 + m0;
  const int gn = blockIdx.x * 64 + n0;
  if (KS == 1) {
#pragma unroll
    for (int i = 0; i < 4; ++i) {
      float4 o;
      o.x = alpha * acc[i][0] + bias[gn + 0];
      o.y = alpha * acc[i][1] + bias[gn + 1];
      o.z = alpha * acc[i][2] + bias[gn + 2];
      o.w = alpha * acc[i][3] + bias[gn + 3];
      if (act == 1) {
        o.x = fmaxf(o.x, 0.f); o.y = fmaxf(o.y, 0.f);
        o.z = fmaxf(o.z, 0.f); o.w = fmaxf(o.w, 0.f);
      }
      *(float4*)&C[(size_t)(gm + i) * ldc + col0 + gn] = o;
    }
  } else {
    const int M = gridDim.y * 64, N = gridDim.x * 64;
#pragma unroll
    for (int i = 0; i < 4; ++i)
      *(float4*)&P[((size_t)blockIdx.z * M + gm + i) * N + gn] =
          make_float4(acc[i][0], acc[i][1], acc[i][2], acc[i][3]);
  }
}

__global__ __launch_bounds__(256) void gemm_reduce(
    const float* __restrict__ P, float* __restrict__ C,
    const float* __restrict__ bias, int M, int N, int ldc, int col0,
    float alpha, int act, int KS) {
  const int idx = blockIdx.x * 256 + threadIdx.x;
  if (idx >= M * N) return;
  const int m = idx / N, n = idx % N;
  float s = 0.f;
  for (int z = 0; z < KS; ++z) s += P[((size_t)z * M + m) * N + n];
  float v = alpha * s + bias[n];
  if (act == 1) v = fmaxf(v, 0.f);
  C[(size_t)m * ldc + col0 + n] = v;
}

// ======================= VQ =================================================
__global__ __launch_bounds__(256) void rowsq(const float* __restrict__ cb,
                                             float* __restrict__ csq) {
  const int row = blockIdx.x * 4 + (threadIdx.x >> 6);
  const int ln = threadIdx.x & 63;
  const float4 v = ((const float4*)(cb + (size_t)row * 256))[ln];
  float s = v.x * v.x + v.y * v.y + v.z * v.z + v.w * v.w;
#pragma unroll
  for (int off = 32; off > 0; off >>= 1) s += __shfl_down(s, off);
  if (ln == 0) csq[row] = s;
}

__global__ __launch_bounds__(256) void argmin_d2(const float* __restrict__ d2,
                                                 int* __restrict__ idx) {
  const int b = blockIdx.x, t = threadIdx.x;
  const float* row = d2 + (size_t)b * 8192;
  float best = 3.4e38f;
  int bi = 0x7fffffff;
  for (int k = t; k < 8192; k += 256) {
    const float v = row[k];
    if (v < best) { best = v; bi = k; }
  }
  __shared__ float bval[256];
  __shared__ int bidx[256];
  bval[t] = best;
  bidx[t] = bi;
  __syncthreads();
  for (int s = 128; s > 0; s >>= 1) {
    if (t < s) {
      const float ov = bval[t + s];
      const int oi = bidx[t + s];
      if (ov < bval[t] || (ov == bval[t] && oi < bidx[t])) {
        bval[t] = ov;
        bidx[t] = oi;
      }
    }
    __syncthreads();
  }
  if (t == 0) idx[b] = bidx[0];
}

__global__ __launch_bounds__(256) void vq_gather_loss(
    const float* __restrict__ ze, const float* __restrict__ cb,
    const int* __restrict__ idx, float* __restrict__ zq,
    float* __restrict__ lossacc) {
  const int b = blockIdx.x, d = threadIdx.x;
  const int i = b * 256 + d;
  const float q = cb[(size_t)idx[b] * 256 + d];
  zq[i] = q;
  const float df = ze[i] - q;
  float v = df * df;
  __shared__ float sh[256];
  sh[d] = v;
  __syncthreads();
  for (int s = 128; s > 0; s >>= 1) {
    if (d < s) sh[d] += sh[d + s];
    __syncthreads();
  }
  if (d == 0) atomicAdd(lossacc, sh[0]);
}

__global__ void write_loss(const float* __restrict__ lossacc,
                           float* __restrict__ out) {
  out[0] = 2.f * lossacc[0];
}

// ---------------------------------------------------------------------------
extern "C" void kernel_launch(void* const* d_in, const int* in_sizes, int n_in,
                              void* d_out, int out_size, void* d_ws,
                              size_t ws_size, hipStream_t stream) {
  const float* x = (const float*)d_in[0];
  const float* ew1 = (const float*)d_in[1];
  const float* eb1 = (const float*)d_in[2];
  const float* ew2 = (const float*)d_in[3];
  const float* eb2 = (const float*)d_in[4];
  const float* ew3 = (const float*)d_in[5];
  const float* eb3 = (const float*)d_in[6];
  const float* ew4 = (const float*)d_in[7];
  const float* eb4 = (const float*)d_in[8];
  const float* wmu = (const float*)d_in[9];
  const float* bmu = (const float*)d_in[10];
  const float* wcov = (const float*)d_in[11];
  const float* bcov = (const float*)d_in[12];
  const float* cb = (const float*)d_in[13];
  const float* wfc = (const float*)d_in[14];
  const float* bfc = (const float*)d_in[15];
  const float* wt1 = (const float*)d_in[16];
  const float* bt1 = (const float*)d_in[17];
  const float* wt2 = (const float*)d_in[18];
  const float* bt2 = (const float*)d_in[19];
  const float* wt3 = (const float*)d_in[20];
  const float* bt3 = (const float*)d_in[21];
  const float* wt31 = (const float*)d_in[22];
  const float* bt31 = (const float*)d_in[23];
  const float* wt4 = (const float*)d_in[24];
  const float* bt4 = (const float*)d_in[25];

  float* ws = (float*)d_ws;
  float* a1 = ws;               // NHWC [256,32,32,32] bf16 (reused as g3, bf16)
  float* a2 = a1 + 8388608;     // NHWC [256,16,16,64]  (reused as g2)
  float* a3 = a2 + 4194304;     // NHWC [256,8,8,128]   (reused as g1)
  float* a4 = a3 + 2097152;     // NHWC [256,4,4,256]   (reused as g0)
  float* g31 = a4 + 1048576;    // NHWC [256,64,64,32] bf16 (region 33554432 f)
  float* d2 = g31;              // [256,8192]
  float* P = g31 + 2097152;     // 262144
  float* csq = g31 + 2359296;   // 8192
  float* a4n = g31 + 2367488;   // NCHW a4 copy
  float* wfcT = g31 + 3416064;  // 1048576
  float* bfcT = g31 + 4464640;  // 4096
  ushort* wTc2 = (ushort*)(g31 + 4468736);  // 18432 bf16
  ushort* wTc3 = (ushort*)(g31 + 4487168);  // 73728 bf16
  ushort* wTc4 = (ushort*)(g31 + 4560896);  // 294912 bf16
  float* ze = g31 + 33554432;   // [256,256]
  float* zq = ze + 65536;
  float* stats = zq + 65536;    // 8 layers x 512
  float* lossacc = stats + 4096;
  int* idx = (int*)(lossacc + 4);
  ushort* wTt1 = (ushort*)(lossacc + 4 + 256);  // 294912 bf16 (parity)
  ushort* wTt2 = wTt1 + 294912;                 // 73728 bf16 (parity)
  ushort* wTt3 = wTt2 + 73728;                  // 18432 bf16 (tap-major,perm)
  ushort* wTt31 = wTt3 + 18432;                 // 9216 bf16 (tap-major,perm)
  ushort* wT4 = wTt31 + 9216;                   // 4608 bf16 (convt4 B frags)
  float* wc1 = (float*)(wT4 + 4608);            // 864 fp32 (conv1 [27][32])
  float* g3 = a1;   // bf16 content
  float* g2 = a2;
  float* g1 = a3;
  float* g0 = a4;

  float* st0 = stats + 0 * 512;
  float* st1 = stats + 1 * 512;
  float* st2 = stats + 2 * 512;
  float* st3 = stats + 3 * 512;
  float* st4 = stats + 4 * 512;
  float* st5 = stats + 5 * 512;
  float* st6 = stats + 6 * 512;
  float* st7 = stats + 7 * 512;

  hipMemsetAsync(stats, 0, (4096 + 8) * sizeof(float), stream);

  // ---- weight transposes (bf16) ----
  tr_convw_bf<<<72, 256, 0, stream>>>(ew2, wTc2, 32, 64, 18432);
  tr_convw_bf<<<288, 256, 0, stream>>>(ew3, wTc3, 64, 128, 73728);
  tr_convw_bf<<<1152, 256, 0, stream>>>(ew4, wTc4, 128, 256, 294912);
  tr_convtw_bf<<<1152, 256, 0, stream>>>(wt1, wTt1, 256, 128, 294912);
  tr_convtw_bf<<<288, 256, 0, stream>>>(wt2, wTt2, 128, 64, 73728);
  tr_convtw_tc<<<72, 256, 0, stream>>>(wt3, wTt3, 64, 32, 18432);
  tr_convtw_tc<<<36, 256, 0, stream>>>(wt31, wTt31, 32, 32, 9216);
  tr_w4<<<18, 256, 0, stream>>>(wt4, wT4);
  tr_w1<<<4, 256, 0, stream>>>(ew1, wc1);
  tr_fcdec<<<4096, 256, 0, stream>>>(wfc, bfc, wfcT, bfcT);
  rowsq<<<2048, 256, 0, stream>>>(cb, csq);

  // ---- encoder ----
  conv1_bf<<<1024, 256, 0, stream>>>(x, wc1, eb1, (ushort*)a1, st0);
  mfmaconv<64, 0, 32, 32, 64, true, true><<<dim3(1, 1024), 256, 0, stream>>>(
      a1, wTc2, eb2, st0, 1.f / (256.f * 1024.f), a2, st1);
  mfmaconv<64, 0, 16, 64, 128, true, false><<<dim3(2, 256), 256, 0, stream>>>(
      a2, wTc3, eb3, st1, 1.f / (256.f * 256.f), a3, st2);
  mfmaconv<64, 0, 8, 128, 256, true, false><<<dim3(4, 64), 256, 0, stream>>>(
      a3, wTc4, eb4, st2, 1.f / (256.f * 64.f), a4, st3);
  tr_a4<<<4096, 256, 0, stream>>>(a4, a4n);

  // ---- encoder FC (fp32) ----
  gemm_abt<<<dim3(2, 4, 8), 256, 0, stream>>>(a4n, wmu, nullptr, st3,
                                              1.f / 4096.f, nullptr, P, 4096,
                                              0, 0, 1.f, 0);
  gemm_reduce<<<128, 256, 0, stream>>>(P, ze, bmu, 256, 128, 256, 0, 1.f, 0, 8);
  gemm_abt<<<dim3(2, 4, 8), 256, 0, stream>>>(a4n, wcov, nullptr, st3,
                                              1.f / 4096.f, nullptr, P, 4096,
                                              0, 0, 1.f, 0);
  gemm_reduce<<<128, 256, 0, stream>>>(P, ze, bcov, 256, 128, 256, 128, 1.f, 1, 8);

  // ---- VQ (fp32) ----
  gemm_abt<<<dim3(128, 4, 1), 256, 0, stream>>>(ze, cb, csq, nullptr, 0.f, d2,
                                                nullptr, 256, 8192, 0, -2.f, 0);
  argmin_d2<<<256, 256, 0, stream>>>(d2, idx);
  vq_gather_loss<<<256, 256, 0, stream>>>(ze, cb, idx, zq, lossacc);

  // ---- decoder FC (fp32) ----
  gemm_abt<<<dim3(64, 4, 1), 256, 0, stream>>>(zq, wfcT, bfcT, nullptr, 0.f,
                                               g0, nullptr, 256, 4096, 0, 1.f, 0);

  // ---- decoder ----
  mfmaconv<64, 1, 4, 256, 128, false, false><<<dim3(2, 64, 4), 256, 0, stream>>>(
      g0, wTt1, bt1, nullptr, 0.f, g1, st4);
  mfmaconv<64, 1, 8, 128, 64, true, false><<<dim3(1, 256, 4), 256, 0, stream>>>(
      g1, wTt2, bt2, st4, 1.f / (256.f * 64.f), g2, st5);
  convt_mfma<16, 64, true, false, 2><<<512, 256, 0, stream>>>(
      g2, wTt3, bt3, st5, 1.f / (256.f * 256.f), g3, st6);
  convt_mfma<32, 32, true, true, 4><<<1024, 256, 0, stream>>>(
      g3, wTt31, bt31, st6, 1.f / (256.f * 1024.f), g31, st7);

  convt4_mfma<<<1024, 256, 0, stream>>>(g31, wT4, bt4, st7,
                                        1.f / (256.f * 4096.f), (float*)d_out);
  write_loss<<<1, 1, 0, stream>>>(lossacc, (float*)d_out + 3145728);
}

// Round 5
// 539.483 us; speedup vs baseline: 1.1638x; 1.0332x over previous
//
#include <hip/hip_runtime.h>
#include <cmath>

// ---------------------------------------------------------------------------
// VQ-VAE forward. B=256, C=3, HW=64, D=256, K=8192, LAT=128
// R13: conv1 -> MFMA im2col (conv1_mfma). M=16px, K=32 (27 real: 3ci x 9taps,
// 5 zero), N=16 with channel-pair-permuted B fragments (lane ln15 owns ch
// 2*ln15,2*ln15+1 -> packed bf16 dword stores). Per wave/tile: 8 LDS gathers
// + 2 MFMA replace 13824 scalar FMAs; weights = 2 short8 VGPR frags; stats
// 2 ch/lane (8 shuffles vs 384). R12 LDS tile + packed NHWC bf16 out kept.
// R11 convt4 MFMA ring, R10 multi-strip convt_mfma, R9 bf16 tail retained.
// ---------------------------------------------------------------------------

#define EPS_BN 1e-5f
typedef unsigned short ushort;
typedef short short8 __attribute__((ext_vector_type(8)));
typedef ushort us4 __attribute__((ext_vector_type(4)));
typedef float f32x4 __attribute__((ext_vector_type(4)));

__device__ __forceinline__ float lrelu(float v) { return v >= 0.f ? v : 0.01f * v; }
__device__ __forceinline__ ushort f2bf(float f) {
  unsigned u = __float_as_uint(f);
  return (ushort)((u + 0x7FFF + ((u >> 16) & 1)) >> 16);
}
__device__ __forceinline__ float bf2f(ushort u) {
  return __uint_as_float(((unsigned)u) << 16);
}

// ======================= weight transposes (once per launch) ===============
// conv (COUT,CIN,3,3) -> bf16 [co][t*CIN+ci]
__global__ __launch_bounds__(256) void tr_convw_bf(const float* __restrict__ w,
                                                   ushort* __restrict__ wT,
                                                   int CIN, int COUT, int total) {
  int i = blockIdx.x * 256 + threadIdx.x;
  if (i >= total) return;
  int co = i / (9 * CIN);
  int r = i - co * 9 * CIN;
  int t = r / CIN, ci = r - t * CIN;
  wT[i] = f2bf(w[((size_t)co * CIN + ci) * 9 + t]);
}

// convT (CIN,COUT,3,3) -> bf16 parity-concat [p][co][k]
__global__ __launch_bounds__(256) void tr_convtw_bf(const float* __restrict__ w,
                                                    ushort* __restrict__ wT,
                                                    int CIN, int COUT, int total) {
  int i = blockIdx.x * 256 + threadIdx.x;
  if (i >= total) return;
  const int cc = CIN * COUT;
  int p, base, Kp;
  if (i < cc) { p = 0; base = 0; Kp = CIN; }
  else if (i < 3 * cc) { p = 1; base = cc; Kp = 2 * CIN; }
  else if (i < 5 * cc) { p = 2; base = 3 * cc; Kp = 2 * CIN; }
  else { p = 3; base = 5 * cc; Kp = 4 * CIN; }
  const int r = i - base;
  const int co = r / Kp;
  const int q = r - co * Kp;
  const int tix = q / CIN, ci = q - (q / CIN) * CIN;
  const int py = p >> 1, px = p & 1;
  const int nx = px ? 2 : 1;
  const int kyi = tix / nx, kxi = tix - kyi * nx;
  const int ky = py ? (kyi == 0 ? 0 : 2) : 1;
  const int kx = px ? (kxi == 0 ? 0 : 2) : 1;
  wT[i] = f2bf(w[((size_t)ci * COUT + co) * 9 + ky * 3 + kx]);
}

// convT (CIN,COUT=32,3,3) -> bf16 [t][co_slot][ci] (tap-major, columns
// PERMUTED so slot f*16+ln15 holds channel 2*ln15+f -> packed bf16 stores)
__global__ __launch_bounds__(256) void tr_convtw_tc(const float* __restrict__ w,
                                                    ushort* __restrict__ wT,
                                                    int CIN, int COUT, int total) {
  int i = blockIdx.x * 256 + threadIdx.x;
  if (i >= total) return;
  int ci = i % CIN;
  int tmp = i / CIN;
  int co = tmp % COUT;
  int t = tmp / COUT;
  const int co_slot = ((co & 1) << 4) | (co >> 1);
  wT[((size_t)t * COUT + co_slot) * CIN + ci] =
      f2bf(w[((size_t)ci * COUT + co) * 9 + t]);
}

// convt4 weights (CIN=32, COUT=3, 3,3) -> per-lane B fragments
__global__ __launch_bounds__(256) void tr_w4(const float* __restrict__ w,
                                             ushort* __restrict__ wT) {
  int i = blockIdx.x * 256 + threadIdx.x;
  if (i >= 4608) return;
  const int s = i >> 9;
  const int l = (i >> 3) & 63;
  const int j = i & 7;
  const int nn = l & 15;
  const int ci = ((l >> 4) << 3) + j;
  const int ty = s / 3, tx = s - ty * 3;
  ushort v = 0;
  if (nn < 3)
    v = f2bf(w[((size_t)ci * 3 + nn) * 9 + (2 - ty) * 3 + (2 - tx)]);
  wT[i] = v;
}

// conv1 weights (32,3,3,3) -> MFMA B fragments, channel-pair permuted:
// wT[(f*64+l)*8+j] = W[c=2*(l&15)+f][k=(l>>4)*8+j], k=(ci*9+ky*3+kx), 0 pad.
__global__ __launch_bounds__(256) void tr_w1b(const float* __restrict__ w,
                                              ushort* __restrict__ wT) {
  int i = blockIdx.x * 256 + threadIdx.x;
  if (i >= 1024) return;
  const int j = i & 7, l = (i >> 3) & 63, f = i >> 9;
  const int c = 2 * (l & 15) + f;
  const int k = ((l >> 4) << 3) + j;
  ushort v = 0;
  if (k < 27) {
    const int ci = k / 9, r = k - ci * 9;
    v = f2bf(w[((size_t)c * 3 + ci) * 9 + r]);
  }
  wT[i] = v;
}

// a4 NHWC [256,4,4,256] -> NCHW [256,256,4,4]
__global__ __launch_bounds__(256) void tr_a4(const float* __restrict__ in,
                                             float* __restrict__ out) {
  int i = blockIdx.x * 256 + threadIdx.x;
  int n = i >> 12, k = i & 4095;
  out[i] = in[(size_t)(n << 12) + ((k & 15) << 8) + (k >> 4)];
}

// wfc [4096,256] + bfc: permute ROWS from (c,y,x) to (y,x,c)
__global__ __launch_bounds__(256) void tr_fcdec(const float* __restrict__ in,
                                                const float* __restrict__ bin,
                                                float* __restrict__ out,
                                                float* __restrict__ bout) {
  int i = blockIdx.x * 256 + threadIdx.x;
  int k = i >> 8, d = i & 255;
  int kp = (k & 15) * 256 + (k >> 4);
  out[(size_t)kp * 256 + d] = in[i];
  if (d == 0) bout[kp] = bin[k];
}

// ======================= bf16 MFMA implicit-GEMM conv / convT ==============
template <int TN, int MODE, int IH, int CIN, int COUT, bool HASN, bool INBF>
__global__ __launch_bounds__(256) void mfmaconv(
    const float* __restrict__ X, const ushort* __restrict__ WT,
    const float* __restrict__ bias, const float* __restrict__ st, float invN,
    float* __restrict__ Y, float* __restrict__ stOut) {
  constexpr int OH = (MODE == 0) ? IH / 2 : 2 * IH;
  constexpr int NF = TN / 16;
  __shared__ short As[64][40];
  __shared__ short Bs[TN][40];
  __shared__ float nrm0[HASN ? CIN : 4], nrm1[HASN ? CIN : 4];
  __shared__ float redS[4][TN], redQ[4][TN];
  const int tid = threadIdx.x;
  const int wv = tid >> 6, lane = tid & 63;
  const int quad = lane >> 4, ln15 = tid & 15;
  if (HASN) {
    for (int c = tid; c < CIN; c += 256) {
      float m = st[c] * invN;
      float var = st[256 + c] * invN - m * m;
      float s = rsqrtf(var + EPS_BN);
      nrm0[c] = s;
      nrm1[c] = m * s;
    }
    __syncthreads();
  }
  int py = 0, px = 0, nx = 1, K = 9 * CIN;
  const ushort* W = WT;
  if (MODE == 1) {
    const int pz = blockIdx.z;
    py = pz >> 1;
    px = pz & 1;
    nx = px ? 2 : 1;
    const int ny = py ? 2 : 1;
    K = ny * nx * CIN;
    const int pre[4] = {0, 1, 3, 5};
    W = WT + (size_t)pre[pz] * CIN * COUT;
  }
  const int gyTM = blockIdx.y * 64;
  const int gxTN = blockIdx.x * TN;

  const int sm = tid & 63, skg = (tid >> 6) * 8;
  int baseNB, baseIY, baseIX;
  {
    const int gm = gyTM + sm;
    if (MODE == 0) {
      const int ni = gm / (OH * OH), r = gm % (OH * OH);
      baseNB = ni * IH * IH;
      baseIY = 2 * (r / OH) - 1;
      baseIX = 2 * (r % OH) - 1;
    } else {
      const int ni = gm / (IH * IH), r = gm % (IH * IH);
      baseNB = ni * IH * IH;
      baseIY = r / IH;
      baseIX = r % IH;
    }
  }
  f32x4 acc[NF];
#pragma unroll
  for (int f = 0; f < NF; ++f) acc[f] = (f32x4){0.f, 0.f, 0.f, 0.f};

  for (int k0 = 0; k0 < K; k0 += 32) {
    const int t = k0 / CIN;
    const int ci0 = k0 - t * CIN;
    int iy, ix;
    if (MODE == 0) {
      iy = baseIY + t / 3;
      ix = baseIX + (t - (t / 3) * 3);
    } else {
      const int kyi = t / nx, kxi = t - (t / nx) * nx;
      iy = baseIY + ((py && kyi == 0) ? 1 : 0);
      ix = baseIX + ((px && kxi == 0) ? 1 : 0);
    }
    {
      const bool ok =
          ((unsigned)iy < (unsigned)IH) && ((unsigned)ix < (unsigned)IH);
      float v[8] = {0.f, 0.f, 0.f, 0.f, 0.f, 0.f, 0.f, 0.f};
      if (ok) {
        if constexpr (INBF) {
          const ushort* xp = (const ushort*)X +
                             ((size_t)baseNB + iy * IH + ix) * CIN + ci0 + skg;
          const short8 raw = *(const short8*)xp;
#pragma unroll
          for (int u = 0; u < 8; ++u) v[u] = bf2f((ushort)raw[u]);
        } else {
          const float* xp =
              &X[((size_t)baseNB + iy * IH + ix) * CIN + ci0 + skg];
          const float4 va = *(const float4*)xp, vb = *(const float4*)(xp + 4);
          v[0] = va.x; v[1] = va.y; v[2] = va.z; v[3] = va.w;
          v[4] = vb.x; v[5] = vb.y; v[6] = vb.z; v[7] = vb.w;
        }
        if (HASN) {
          const int c = ci0 + skg;
#pragma unroll
          for (int u = 0; u < 8; ++u)
            v[u] = fmaf(v[u], nrm0[c + u], -nrm1[c + u]);
        }
      }
      short8 o;
#pragma unroll
      for (int u = 0; u < 8; ++u) o[u] = (short)f2bf(v[u]);
      *(short8*)&As[sm][skg] = o;
    }
    if (tid < TN * 4) {
      const int bn = tid >> 2, bkg = (tid & 3) * 8;
      *(short8*)&Bs[bn][bkg] =
          *(const short8*)&W[(size_t)(gxTN + bn) * K + k0 + bkg];
    }
    __syncthreads();
    const short8 a = *(const short8*)&As[wv * 16 + ln15][quad * 8];
#pragma unroll
    for (int f = 0; f < NF; ++f) {
      const short8 b = *(const short8*)&Bs[f * 16 + ln15][quad * 8];
      acc[f] = __builtin_amdgcn_mfma_f32_16x16x32_bf16(a, b, acc[f], 0, 0, 0);
    }
    __syncthreads();
  }

  size_t maddr[4];
#pragma unroll
  for (int r = 0; r < 4; ++r) {
    const int m = gyTM + wv * 16 + quad * 4 + r;
    if (MODE == 0) {
      const int ni = m / (OH * OH), rr = m % (OH * OH);
      maddr[r] = (((size_t)ni * OH + rr / OH) * OH + rr % OH) * COUT;
    } else {
      const int ni = m / (IH * IH), rr = m % (IH * IH);
      const int oy = 2 * (rr / IH) + py, ox = 2 * (rr % IH) + px;
      maddr[r] = (((size_t)ni * OH + oy) * OH + ox) * COUT;
    }
  }
#pragma unroll
  for (int f = 0; f < NF; ++f) {
    const int col = gxTN + f * 16 + ln15;
    const float bv = bias[col];
    float cS = 0.f, cQ = 0.f;
#pragma unroll
    for (int r = 0; r < 4; ++r) {
      const float o = lrelu(acc[f][r] + bv);
      cS += o;
      cQ += o * o;
      Y[maddr[r] + col] = o;
    }
    cS += __shfl_down(cS, 32); cS += __shfl_down(cS, 16);
    cQ += __shfl_down(cQ, 32); cQ += __shfl_down(cQ, 16);
    if (lane < 16) { redS[wv][f * 16 + ln15] = cS; redQ[wv][f * 16 + ln15] = cQ; }
  }
  __syncthreads();
  if (tid < TN) {
    float S = redS[0][tid] + redS[1][tid] + redS[2][tid] + redS[3][tid];
    float Q = redQ[0][tid] + redQ[1][tid] + redQ[2][tid] + redQ[3][tid];
    atomicAdd(&stOut[gxTN + tid], S);
    atomicAdd(&stOut[256 + gxTN + tid], Q);
  }
}

// ======================= halo-tile merged convT (COUT=32, CIN<=64) =========
// Multi-strip software pipeline (R10). Output = packed bf16.
template <int IH, int CIN, bool HASN, bool INBF, int NSTRIP>
__global__ __launch_bounds__(256) void convt_mfma(
    const float* __restrict__ X, const ushort* __restrict__ WT,
    const float* __restrict__ bias, const float* __restrict__ st, float invN,
    float* __restrict__ Y, float* __restrict__ stOut) {
  constexpr int OH = 2 * IH;
  constexpr int L = (IH == 32) ? 5 : 4;
  constexpr int RSPAN = 64 / IH;
  constexpr int NP = (RSPAN + 1) * (IH + 1);
  constexpr int LK = CIN + 8;
  constexpr int TI = NP * (CIN / 8);
  constexpr int ITER = (TI + 255) / 256;
  __shared__ short As[2][NP][LK];
  __shared__ short Ws[9 * 32][LK];
  __shared__ float nrm0[HASN ? CIN : 4], nrm1[HASN ? CIN : 4];
  __shared__ float redS[4][32], redQ[4][32];
  const int tid = threadIdx.x;
  const int wv = tid >> 6, lane = tid & 63;
  const int quad = lane >> 4, ln15 = lane & 15;
  if (HASN) {
    for (int c = tid; c < CIN; c += 256) {
      float m = st[c] * invN;
      float var = st[256 + c] * invN - m * m;
      float s = rsqrtf(var + EPS_BN);
      nrm0[c] = s;
      nrm1[c] = m * s;
    }
  }
  for (int i = tid; i < 9 * 32 * (CIN / 8); i += 256) {
    const int row = i / (CIN / 8), kg = (i % (CIN / 8)) * 8;
    *(short8*)&Ws[row][kg] = *(const short8*)&WT[(size_t)row * CIN + kg];
  }
  __syncthreads();

  const int strip0 = blockIdx.x * NSTRIP;
  const int n = (strip0 * 64) / (IH * IH);
  const int iy0base = (strip0 * 64 - n * (IH * IH)) >> L;

#pragma unroll
  for (int it = 0; it < ITER; ++it) {
    const int i = tid + it * 256;
    if (i < TI) {
      const int slot = i / (CIN / 8), kg = (i % (CIN / 8)) * 8;
      const int ty = slot / (IH + 1), tx = slot - ty * (IH + 1);
      const int iy = iy0base + ty;
      short8 o = {0, 0, 0, 0, 0, 0, 0, 0};
      if (iy < IH && tx < IH) {
        float v[8];
        if constexpr (INBF) {
          const ushort* xp =
              (const ushort*)X + (((size_t)n * IH + iy) * IH + tx) * CIN + kg;
          const short8 raw = *(const short8*)xp;
#pragma unroll
          for (int u = 0; u < 8; ++u) v[u] = bf2f((ushort)raw[u]);
        } else {
          const float* xp = &X[(((size_t)n * IH + iy) * IH + tx) * CIN + kg];
          const float4 va = *(const float4*)xp, vb = *(const float4*)(xp + 4);
          v[0] = va.x; v[1] = va.y; v[2] = va.z; v[3] = va.w;
          v[4] = vb.x; v[5] = vb.y; v[6] = vb.z; v[7] = vb.w;
        }
        if (HASN) {
#pragma unroll
          for (int u = 0; u < 8; ++u)
            v[u] = fmaf(v[u], nrm0[kg + u], -nrm1[kg + u]);
        }
#pragma unroll
        for (int u = 0; u < 8; ++u) o[u] = (short)f2bf(v[u]);
      }
      *(short8*)&As[0][slot][kg] = o;
    }
  }
  __syncthreads();

  const int rA = wv * 16 + ln15;
  const int baseIdx = (rA >> L) * (IH + 1) + (rA & (IH - 1));
  constexpr int NT[4] = {4, 2, 2, 1};
  constexpr int TT[4][4] = {{4, 5, 7, 8}, {3, 6, 0, 0}, {1, 2, 0, 0}, {0, 0, 0, 0}};
  const float bv0 = bias[2 * ln15], bv1 = bias[2 * ln15 + 1];
  unsigned* Yp = (unsigned*)Y;
  float cS[2] = {0.f, 0.f}, cQ[2] = {0.f, 0.f};

#pragma unroll
  for (int s = 0; s < NSTRIP; ++s) {
    const int cur = s & 1, nxt = cur ^ 1;
    const int iy0 = iy0base + s * RSPAN;

    short8 rbf[ITER];
    float4 rva[ITER], rvb[ITER];
    bool vld[ITER];
    if (s + 1 < NSTRIP) {
      const int iyN0 = iy0 + RSPAN;
#pragma unroll
      for (int it = 0; it < ITER; ++it) {
        vld[it] = false;
        const int i = tid + it * 256;
        if (i < TI) {
          const int slot = i / (CIN / 8), kg = (i % (CIN / 8)) * 8;
          const int ty = slot / (IH + 1), tx = slot - ty * (IH + 1);
          const int iy = iyN0 + ty;
          if (iy < IH && tx < IH) {
            vld[it] = true;
            if constexpr (INBF) {
              const ushort* xp = (const ushort*)X +
                                 (((size_t)n * IH + iy) * IH + tx) * CIN + kg;
              rbf[it] = *(const short8*)xp;
            } else {
              const float* xp =
                  &X[(((size_t)n * IH + iy) * IH + tx) * CIN + kg];
              rva[it] = *(const float4*)xp;
              rvb[it] = *(const float4*)(xp + 4);
            }
          }
        }
      }
    }

    f32x4 acc[4][2];
#pragma unroll
    for (int p = 0; p < 4; ++p)
#pragma unroll
      for (int f = 0; f < 2; ++f) acc[p][f] = (f32x4){0.f, 0.f, 0.f, 0.f};
#pragma unroll
    for (int sh = 0; sh < 4; ++sh) {
      const int off = (sh >> 1) * (IH + 1) + (sh & 1);
#pragma unroll
      for (int j = 0; j < NT[sh]; ++j) {
        const int t = TT[sh][j];
        const int ky = t / 3, kx = t - ky * 3;
        const int par = ((ky == 1) ? 0 : 2) + ((kx == 1) ? 0 : 1);
#pragma unroll
        for (int ks = 0; ks < CIN / 32; ++ks) {
          const short8 a =
              *(const short8*)&As[cur][baseIdx + off][ks * 32 + quad * 8];
#pragma unroll
          for (int f = 0; f < 2; ++f) {
            const short8 b =
                *(const short8*)&Ws[t * 32 + f * 16 + ln15][ks * 32 + quad * 8];
            acc[par][f] = __builtin_amdgcn_mfma_f32_16x16x32_bf16(
                a, b, acc[par][f], 0, 0, 0);
          }
        }
      }
    }

#pragma unroll
    for (int i = 0; i < 4; ++i) {
      const int rD = wv * 16 + quad * 4 + i;
      const int ry = rD >> L, rx = rD & (IH - 1);
      const int iy = iy0 + ry;
#pragma unroll
      for (int p = 0; p < 4; ++p) {
        const int a = p >> 1, b = p & 1;
        const size_t base =
            (((size_t)n * OH + 2 * iy + a) * OH + 2 * rx + b) * 32;
        const float o0 = lrelu(acc[p][0][i] + bv0);
        const float o1 = lrelu(acc[p][1][i] + bv1);
        cS[0] += o0; cQ[0] += o0 * o0;
        cS[1] += o1; cQ[1] += o1 * o1;
        Yp[(base >> 1) + ln15] = (unsigned)f2bf(o0) | ((unsigned)f2bf(o1) << 16);
      }
    }

    if (s + 1 < NSTRIP) {
#pragma unroll
      for (int it = 0; it < ITER; ++it) {
        const int i = tid + it * 256;
        if (i < TI) {
          const int slot = i / (CIN / 8), kg = (i % (CIN / 8)) * 8;
          short8 o = {0, 0, 0, 0, 0, 0, 0, 0};
          if (vld[it]) {
            float v[8];
            if constexpr (INBF) {
#pragma unroll
              for (int u = 0; u < 8; ++u) v[u] = bf2f((ushort)rbf[it][u]);
            } else {
              v[0] = rva[it].x; v[1] = rva[it].y;
              v[2] = rva[it].z; v[3] = rva[it].w;
              v[4] = rvb[it].x; v[5] = rvb[it].y;
              v[6] = rvb[it].z; v[7] = rvb[it].w;
            }
            if (HASN) {
#pragma unroll
              for (int u = 0; u < 8; ++u)
                v[u] = fmaf(v[u], nrm0[kg + u], -nrm1[kg + u]);
            }
#pragma unroll
            for (int u = 0; u < 8; ++u) o[u] = (short)f2bf(v[u]);
          }
          *(short8*)&As[nxt][slot][kg] = o;
        }
      }
    }
    __syncthreads();
  }

#pragma unroll
  for (int f = 0; f < 2; ++f) {
    float s_ = cS[f], q_ = cQ[f];
    s_ += __shfl_down(s_, 32); s_ += __shfl_down(s_, 16);
    q_ += __shfl_down(q_, 32); q_ += __shfl_down(q_, 16);
    if (lane < 16) { redS[wv][f * 16 + ln15] = s_; redQ[wv][f * 16 + ln15] = q_; }
  }
  __syncthreads();
  if (tid < 32) {
    float S = redS[0][tid] + redS[1][tid] + redS[2][tid] + redS[3][tid];
    float Q = redQ[0][tid] + redQ[1][tid] + redQ[2][tid] + redQ[3][tid];
    const int ch = ((tid & 15) << 1) | (tid >> 4);
    atomicAdd(&stOut[ch], S);
    atomicAdd(&stOut[256 + ch], Q);
  }
}

// ======================= conv1 via MFMA im2col =============================
// Block = image x 8 output rows. Input tile 3x17x67 fp32 in LDS. Each wave:
// 2 rows x 2 half-rows = 4 tiles of 16 px. Per tile: 8 LDS gathers -> bf16
// A-frag (K=32: 27 real + 5 zero), 2 MFMAs vs channel-pair-permuted B frags
// (lane ln15 -> ch 2*ln15, 2*ln15+1), packed bf16 dword stores. Stats fp32
// pre-rounding, 2 ch/lane.
__global__ __launch_bounds__(256) void conv1_mfma(
    const float* __restrict__ x, const ushort* __restrict__ WT,
    const float* __restrict__ bias, ushort* __restrict__ y,
    float* __restrict__ st) {
  __shared__ float xin[3][17][67];
  __shared__ float redS[4][32], redQ[4][32];
  const int tid = threadIdx.x;
  const int wv = tid >> 6, lane = tid & 63;
  const int quad = lane >> 4, ln15 = lane & 15;
  const short8 bf0 = *(const short8*)&WT[(size_t)lane * 8];
  const short8 bf1 = *(const short8*)&WT[(size_t)(64 + lane) * 8];
  const int n = blockIdx.x >> 2;
  const int oy0 = (blockIdx.x & 3) * 8;
  const int iy0 = 2 * oy0 - 1;
  if (tid < 51) {  // zero halo col 0 (3*17)
    const int ci = tid / 17, r = tid - ci * 17;
    xin[ci][r][0] = 0.f;
  }
  for (int i = tid; i < 816; i += 256) {
    const int ci = i / 272;
    const int r = (i - ci * 272) >> 4;
    const int c4 = (i & 15) << 2;
    const int iy = iy0 + r;
    float4 v = make_float4(0.f, 0.f, 0.f, 0.f);
    if ((unsigned)iy < 64u)
      v = *(const float4*)&x[((size_t)(n * 3 + ci) * 64 + iy) * 64 + c4];
    xin[ci][r][1 + c4] = v.x;
    xin[ci][r][2 + c4] = v.y;
    xin[ci][r][3 + c4] = v.z;
    xin[ci][r][4 + c4] = v.w;
  }
  __syncthreads();

  const float bv0 = bias[2 * ln15], bv1 = bias[2 * ln15 + 1];
  unsigned* Yp = (unsigned*)y;
  float cS[2] = {0.f, 0.f}, cQ[2] = {0.f, 0.f};
#pragma unroll
  for (int rr = 0; rr < 2; ++rr) {
    const int row = 2 * wv + rr;
#pragma unroll
    for (int h = 0; h < 2; ++h) {
      short8 a;
#pragma unroll
      for (int j = 0; j < 8; ++j) {
        const int k = quad * 8 + j;
        float val = 0.f;
        if (k < 27) {
          const int ci = k / 9, r2 = k - ci * 9;
          const int ky = r2 / 3, kx = r2 - ky * 3;
          val = xin[ci][2 * row + ky][2 * (h * 16 + ln15) + kx];
        }
        a[j] = (short)f2bf(val);
      }
      f32x4 acc0 = (f32x4){0.f, 0.f, 0.f, 0.f};
      f32x4 acc1 = (f32x4){0.f, 0.f, 0.f, 0.f};
      acc0 = __builtin_amdgcn_mfma_f32_16x16x32_bf16(a, bf0, acc0, 0, 0, 0);
      acc1 = __builtin_amdgcn_mfma_f32_16x16x32_bf16(a, bf1, acc1, 0, 0, 0);
#pragma unroll
      for (int r = 0; r < 4; ++r) {
        const int px = h * 16 + quad * 4 + r;
        const float o0 = lrelu(acc0[r] + bv0);
        const float o1 = lrelu(acc1[r] + bv1);
        cS[0] += o0; cQ[0] += o0 * o0;
        cS[1] += o1; cQ[1] += o1 * o1;
        Yp[((size_t)n * 1024 + (oy0 + row) * 32 + px) * 16 + ln15] =
            (unsigned)f2bf(o0) | ((unsigned)f2bf(o1) << 16);
      }
    }
  }
#pragma unroll
  for (int f = 0; f < 2; ++f) {
    float s_ = cS[f], q_ = cQ[f];
    s_ += __shfl_down(s_, 32); s_ += __shfl_down(s_, 16);
    q_ += __shfl_down(q_, 32); q_ += __shfl_down(q_, 16);
    if (lane < 16) { redS[wv][f * 16 + ln15] = s_; redQ[wv][f * 16 + ln15] = q_; }
  }
  __syncthreads();
  if (tid < 32) {
    float S = redS[0][tid] + redS[1][tid] + redS[2][tid] + redS[3][tid];
    float Q = redQ[0][tid] + redQ[1][tid] + redQ[2][tid] + redQ[3][tid];
    const int ch = ((tid & 15) << 1) | (tid >> 4);
    atomicAdd(&st[ch], S);
    atomicAdd(&st[256 + ch], Q);
  }
}

// ======================= final convT via MFMA + 4-row LDS ring =============
__global__ __launch_bounds__(256) void convt4_mfma(
    const float* __restrict__ X, const ushort* __restrict__ WT,
    const float* __restrict__ bias, const float* __restrict__ st, float invN,
    float* __restrict__ out) {
  __shared__ short ring[4][66][32];
  __shared__ float s0[32], s1[32];
  const int tid = threadIdx.x;
  const int wv = tid >> 6, lane = tid & 63;
  const int quad = lane >> 4, ln15 = lane & 15;
  if (tid < 32) {
    float m = st[tid] * invN;
    float var = st[256 + tid] * invN - m * m;
    float s = rsqrtf(var + EPS_BN);
    s0[tid] = s;
    s1[tid] = m * s;
  }
  if (tid >= 32 && tid < 64) {
    const int t = tid - 32;
    const int slot = t >> 3, h = (t >> 2) & 1, kg = (t & 3) * 8;
    short8 z = {0, 0, 0, 0, 0, 0, 0, 0};
    *(short8*)&ring[slot][h ? 65 : 0][kg] = z;
  }
  short8 bfrag[9];
#pragma unroll
  for (int s = 0; s < 9; ++s)
    bfrag[s] = *(const short8*)&WT[((size_t)s * 64 + lane) * 8];
  __syncthreads();

  const int n = blockIdx.x >> 2;
  const int y0 = (blockIdx.x & 3) * 16;
  const ushort* xn = (const ushort*)X + (size_t)n * 131072;
  const int spx = tid >> 2, skg = (tid & 3) * 8;

#pragma unroll
  for (int pr = 0; pr < 3; ++pr) {
    const int Y = y0 - 1 + pr;
    short8 o = {0, 0, 0, 0, 0, 0, 0, 0};
    if ((unsigned)Y < 64u) {
      const short8 raw = *(const short8*)&xn[((size_t)Y * 64 + spx) * 32 + skg];
#pragma unroll
      for (int u = 0; u < 8; ++u)
        o[u] = (short)f2bf(fmaf(bf2f((ushort)raw[u]), s0[skg + u], -s1[skg + u]));
    }
    *(short8*)&ring[Y & 3][spx + 1][skg] = o;
  }
  __syncthreads();

  const int x0 = wv * 16;
  const float bv = (ln15 < 3) ? bias[ln15] : 0.f;
  float* op = out + (size_t)n * 3 * 4096;

  for (int y = y0; y < y0 + 16; ++y) {
    const int Ypf = y + 2;
    const bool pre = (Ypf <= y0 + 16);
    short8 raw;
    bool vld = false;
    if (pre && (unsigned)Ypf < 64u) {
      raw = *(const short8*)&xn[((size_t)Ypf * 64 + spx) * 32 + skg];
      vld = true;
    }

    f32x4 acc0 = (f32x4){0.f, 0.f, 0.f, 0.f};
    f32x4 acc1 = (f32x4){0.f, 0.f, 0.f, 0.f};
#pragma unroll
    for (int ty = 0; ty < 3; ++ty) {
      const short* rp = &ring[(y - 1 + ty) & 3][0][0];
#pragma unroll
      for (int tx = 0; tx < 3; ++tx) {
        const short8 a = *(const short8*)&rp[(x0 + ln15 + tx) * 32 + quad * 8];
        const int s = ty * 3 + tx;
        if (s & 1)
          acc1 = __builtin_amdgcn_mfma_f32_16x16x32_bf16(a, bfrag[s], acc1, 0, 0, 0);
        else
          acc0 = __builtin_amdgcn_mfma_f32_16x16x32_bf16(a, bfrag[s], acc0, 0, 0, 0);
      }
    }

    if (ln15 < 3) {
      float4 o;
      float v;
      v = acc0[0] + acc1[0] + bv; o.x = 1.f / (1.f + __expf(-2.f * v));
      v = acc0[1] + acc1[1] + bv; o.y = 1.f / (1.f + __expf(-2.f * v));
      v = acc0[2] + acc1[2] + bv; o.z = 1.f / (1.f + __expf(-2.f * v));
      v = acc0[3] + acc1[3] + bv; o.w = 1.f / (1.f + __expf(-2.f * v));
      *(float4*)&op[(size_t)ln15 * 4096 + y * 64 + x0 + quad * 4] = o;
    }

    if (pre) {
      short8 o = {0, 0, 0, 0, 0, 0, 0, 0};
      if (vld) {
#pragma unroll
        for (int u = 0; u < 8; ++u)
          o[u] = (short)f2bf(
              fmaf(bf2f((ushort)raw[u]), s0[skg + u], -s1[skg + u]));
      }
      *(short8*)&ring[Ypf & 3][spx + 1][skg] = o;
    }
    __syncthreads();
  }
}

// ======================= dense GEMM (fc / VQ distance), fp32 ===============
__global__ __launch_bounds__(256) void gemm_abt(
    const float* __restrict__ A, const float* __restrict__ B,
    const float* __restrict__ bias, const float* __restrict__ stA, float invN,
    float* __restrict__ C, float* __restrict__ P, int K, int ldc, int col0,
    float alpha, int act) {
  __shared__ float As[16][68];
  __shared__ float Bsh[16][68];
  __shared__ float nrm[2][256];
  const int tid = threadIdx.x;
  if (stA) {
    const int c = tid;
    float m = stA[c] * invN;
    float var = stA[256 + c] * invN - m * m;
    float s = rsqrtf(var + EPS_BN);
    nrm[0][c] = s;
    nrm[1][c] = m * s;
    __syncthreads();
  }
  const int lm = tid >> 2, lk = (tid & 3) << 2;
  const int KS = gridDim.z;
  const int kChunk = K / KS;
  const int kStart = blockIdx.z * kChunk;
  const float* Arow = A + (size_t)(blockIdx.y * 64 + lm) * K + lk;
  const float* Brow = B + (size_t)(blockIdx.x * 64 + lm) * K + lk;
  float acc[4][4] = {};
  const int m0 = (tid >> 4) << 2, n0 = (tid & 15) << 2;

  for (int k0 = kStart; k0 < kStart + kChunk; k0 += 16) {
    float4 av = *(const float4*)(Arow + k0);
    float4 bv = *(const float4*)(Brow + k0);
    if (stA) {
      const int ch = (k0 + lk) >> 4;
      const float s = nrm[0][ch], ms = nrm[1][ch];
      av.x = fmaf(av.x, s, -ms);
      av.y = fmaf(av.y, s, -ms);
      av.z = fmaf(av.z, s, -ms);
      av.w = fmaf(av.w, s, -ms);
    }
    As[lk + 0][lm] = av.x; As[lk + 1][lm] = av.y;
    As[lk + 2][lm] = av.z; As[lk + 3][lm] = av.w;
    Bsh[lk + 0][lm] = bv.x; Bsh[lk + 1][lm] = bv.y;
    Bsh[lk + 2][lm] = bv.z; Bsh[lk + 3][lm] = bv.w;
    __syncthreads();
#pragma unroll
    for (int kk = 0; kk < 16; ++kk) {
      const float4 a = *(const float4*)&As[kk][m0];
      const float4 b = *(const float4*)&Bsh[kk][n0];
      acc[0][0] = fmaf(a.x, b.x, acc[0][0]); acc[0][1] = fmaf(a.x, b.y, acc[0][1]);
      acc[0][2] = fmaf(a.x, b.z, acc[0][2]); acc[0][3] = fmaf(a.x, b.w, acc[0][3]);
      acc[1][0] = fmaf(a.y, b.x, acc[1][0]); acc[1][1] = fmaf(a.y, b.y, acc[1][1]);
      acc[1][2] = fmaf(a.y, b.z, acc[1][2]); acc[1][3] = fmaf(a.y, b.w, acc[1][3]);
      acc[2][0] = fmaf(a.z, b.x, acc[2][0]); acc[2][1] = fmaf(a.z, b.y, acc[2][1]);
      acc[2][2] = fmaf(a.z, b.z, acc[2][2]); acc[2][3] = fmaf(a.z, b.w, acc[2][3]);
      acc[3][0] = fmaf(a.w, b.x, acc[3][0]); acc[3][1] = fmaf(a.w, b.y, acc[3][1]);
      acc[3][2] = fmaf(a.w, b.z, acc[3][2]); acc[3][3] = fmaf(a.w, b.w, acc[3][3]);
    }
    __syncthreads();
  }

  const int gm = blockIdx.y * 64 + m0;
  const int gn = blockIdx.x * 64 + n0;
  if (KS == 1) {
#pragma unroll
    for (int i = 0; i < 4; ++i) {
      float4 o;
      o.x = alpha * acc[i][0] + bias[gn + 0];
      o.y = alpha * acc[i][1] + bias[gn + 1];
      o.z = alpha * acc[i][2] + bias[gn + 2];
      o.w = alpha * acc[i][3] + bias[gn + 3];
      if (act == 1) {
        o.x = fmaxf(o.x, 0.f); o.y = fmaxf(o.y, 0.f);
        o.z = fmaxf(o.z, 0.f); o.w = fmaxf(o.w, 0.f);
      }
      *(float4*)&C[(size_t)(gm + i) * ldc + col0 + gn] = o;
    }
  } else {
    const int M = gridDim.y * 64, N = gridDim.x * 64;
#pragma unroll
    for (int i = 0; i < 4; ++i)
      *(float4*)&P[((size_t)blockIdx.z * M + gm + i) * N + gn] =
          make_float4(acc[i][0], acc[i][1], acc[i][2], acc[i][3]);
  }
}

__global__ __launch_bounds__(256) void gemm_reduce(
    const float* __restrict__ P, float* __restrict__ C,
    const float* __restrict__ bias, int M, int N, int ldc, int col0,
    float alpha, int act, int KS) {
  const int idx = blockIdx.x * 256 + threadIdx.x;
  if (idx >= M * N) return;
  const int m = idx / N, n = idx % N;
  float s = 0.f;
  for (int z = 0; z < KS; ++z) s += P[((size_t)z * M + m) * N + n];
  float v = alpha * s + bias[n];
  if (act == 1) v = fmaxf(v, 0.f);
  C[(size_t)m * ldc + col0 + n] = v;
}

// ======================= VQ =================================================
__global__ __launch_bounds__(256) void rowsq(const float* __restrict__ cb,
                                             float* __restrict__ csq) {
  const int row = blockIdx.x * 4 + (threadIdx.x >> 6);
  const int ln = threadIdx.x & 63;
  const float4 v = ((const float4*)(cb + (size_t)row * 256))[ln];
  float s = v.x * v.x + v.y * v.y + v.z * v.z + v.w * v.w;
#pragma unroll
  for (int off = 32; off > 0; off >>= 1) s += __shfl_down(s, off);
  if (ln == 0) csq[row] = s;
}

__global__ __launch_bounds__(256) void argmin_d2(const float* __restrict__ d2,
                                                 int* __restrict__ idx) {
  const int b = blockIdx.x, t = threadIdx.x;
  const float* row = d2 + (size_t)b * 8192;
  float best = 3.4e38f;
  int bi = 0x7fffffff;
  for (int k = t; k < 8192; k += 256) {
    const float v = row[k];
    if (v < best) { best = v; bi = k; }
  }
  __shared__ float bval[256];
  __shared__ int bidx[256];
  bval[t] = best;
  bidx[t] = bi;
  __syncthreads();
  for (int s = 128; s > 0; s >>= 1) {
    if (t < s) {
      const float ov = bval[t + s];
      const int oi = bidx[t + s];
      if (ov < bval[t] || (ov == bval[t] && oi < bidx[t])) {
        bval[t] = ov;
        bidx[t] = oi;
      }
    }
    __syncthreads();
  }
  if (t == 0) idx[b] = bidx[0];
}

__global__ __launch_bounds__(256) void vq_gather_loss(
    const float* __restrict__ ze, const float* __restrict__ cb,
    const int* __restrict__ idx, float* __restrict__ zq,
    float* __restrict__ lossacc) {
  const int b = blockIdx.x, d = threadIdx.x;
  const int i = b * 256 + d;
  const float q = cb[(size_t)idx[b] * 256 + d];
  zq[i] = q;
  const float df = ze[i] - q;
  float v = df * df;
  __shared__ float sh[256];
  sh[d] = v;
  __syncthreads();
  for (int s = 128; s > 0; s >>= 1) {
    if (d < s) sh[d] += sh[d + s];
    __syncthreads();
  }
  if (d == 0) atomicAdd(lossacc, sh[0]);
}

__global__ void write_loss(const float* __restrict__ lossacc,
                           float* __restrict__ out) {
  out[0] = 2.f * lossacc[0];
}

// ---------------------------------------------------------------------------
extern "C" void kernel_launch(void* const* d_in, const int* in_sizes, int n_in,
                              void* d_out, int out_size, void* d_ws,
                              size_t ws_size, hipStream_t stream) {
  const float* x = (const float*)d_in[0];
  const float* ew1 = (const float*)d_in[1];
  const float* eb1 = (const float*)d_in[2];
  const float* ew2 = (const float*)d_in[3];
  const float* eb2 = (const float*)d_in[4];
  const float* ew3 = (const float*)d_in[5];
  const float* eb3 = (const float*)d_in[6];
  const float* ew4 = (const float*)d_in[7];
  const float* eb4 = (const float*)d_in[8];
  const float* wmu = (const float*)d_in[9];
  const float* bmu = (const float*)d_in[10];
  const float* wcov = (const float*)d_in[11];
  const float* bcov = (const float*)d_in[12];
  const float* cb = (const float*)d_in[13];
  const float* wfc = (const float*)d_in[14];
  const float* bfc = (const float*)d_in[15];
  const float* wt1 = (const float*)d_in[16];
  const float* bt1 = (const float*)d_in[17];
  const float* wt2 = (const float*)d_in[18];
  const float* bt2 = (const float*)d_in[19];
  const float* wt3 = (const float*)d_in[20];
  const float* bt3 = (const float*)d_in[21];
  const float* wt31 = (const float*)d_in[22];
  const float* bt31 = (const float*)d_in[23];
  const float* wt4 = (const float*)d_in[24];
  const float* bt4 = (const float*)d_in[25];

  float* ws = (float*)d_ws;
  float* a1 = ws;               // NHWC [256,32,32,32] bf16 (reused as g3, bf16)
  float* a2 = a1 + 8388608;     // NHWC [256,16,16,64]  (reused as g2)
  float* a3 = a2 + 4194304;     // NHWC [256,8,8,128]   (reused as g1)
  float* a4 = a3 + 2097152;     // NHWC [256,4,4,256]   (reused as g0)
  float* g31 = a4 + 1048576;    // NHWC [256,64,64,32] bf16 (region 33554432 f)
  float* d2 = g31;              // [256,8192]
  float* P = g31 + 2097152;     // 262144
  float* csq = g31 + 2359296;   // 8192
  float* a4n = g31 + 2367488;   // NCHW a4 copy
  float* wfcT = g31 + 3416064;  // 1048576
  float* bfcT = g31 + 4464640;  // 4096
  ushort* wTc2 = (ushort*)(g31 + 4468736);  // 18432 bf16
  ushort* wTc3 = (ushort*)(g31 + 4487168);  // 73728 bf16
  ushort* wTc4 = (ushort*)(g31 + 4560896);  // 294912 bf16
  float* ze = g31 + 33554432;   // [256,256]
  float* zq = ze + 65536;
  float* stats = zq + 65536;    // 8 layers x 512
  float* lossacc = stats + 4096;
  int* idx = (int*)(lossacc + 4);
  ushort* wTt1 = (ushort*)(lossacc + 4 + 256);  // 294912 bf16 (parity)
  ushort* wTt2 = wTt1 + 294912;                 // 73728 bf16 (parity)
  ushort* wTt3 = wTt2 + 73728;                  // 18432 bf16 (tap-major,perm)
  ushort* wTt31 = wTt3 + 18432;                 // 9216 bf16 (tap-major,perm)
  ushort* wT4 = wTt31 + 9216;                   // 4608 bf16 (convt4 B frags)
  ushort* wb1 = wT4 + 4608;                     // 1024 bf16 (conv1 B frags)
  float* g3 = a1;   // bf16 content
  float* g2 = a2;
  float* g1 = a3;
  float* g0 = a4;

  float* st0 = stats + 0 * 512;
  float* st1 = stats + 1 * 512;
  float* st2 = stats + 2 * 512;
  float* st3 = stats + 3 * 512;
  float* st4 = stats + 4 * 512;
  float* st5 = stats + 5 * 512;
  float* st6 = stats + 6 * 512;
  float* st7 = stats + 7 * 512;

  hipMemsetAsync(stats, 0, (4096 + 8) * sizeof(float), stream);

  // ---- weight transposes (bf16) ----
  tr_convw_bf<<<72, 256, 0, stream>>>(ew2, wTc2, 32, 64, 18432);
  tr_convw_bf<<<288, 256, 0, stream>>>(ew3, wTc3, 64, 128, 73728);
  tr_convw_bf<<<1152, 256, 0, stream>>>(ew4, wTc4, 128, 256, 294912);
  tr_convtw_bf<<<1152, 256, 0, stream>>>(wt1, wTt1, 256, 128, 294912);
  tr_convtw_bf<<<288, 256, 0, stream>>>(wt2, wTt2, 128, 64, 73728);
  tr_convtw_tc<<<72, 256, 0, stream>>>(wt3, wTt3, 64, 32, 18432);
  tr_convtw_tc<<<36, 256, 0, stream>>>(wt31, wTt31, 32, 32, 9216);
  tr_w4<<<18, 256, 0, stream>>>(wt4, wT4);
  tr_w1b<<<4, 256, 0, stream>>>(ew1, wb1);
  tr_fcdec<<<4096, 256, 0, stream>>>(wfc, bfc, wfcT, bfcT);
  rowsq<<<2048, 256, 0, stream>>>(cb, csq);

  // ---- encoder ----
  conv1_mfma<<<1024, 256, 0, stream>>>(x, wb1, eb1, (ushort*)a1, st0);
  mfmaconv<64, 0, 32, 32, 64, true, true><<<dim3(1, 1024), 256, 0, stream>>>(
      a1, wTc2, eb2, st0, 1.f / (256.f * 1024.f), a2, st1);
  mfmaconv<64, 0, 16, 64, 128, true, false><<<dim3(2, 256), 256, 0, stream>>>(
      a2, wTc3, eb3, st1, 1.f / (256.f * 256.f), a3, st2);
  mfmaconv<64, 0, 8, 128, 256, true, false><<<dim3(4, 64), 256, 0, stream>>>(
      a3, wTc4, eb4, st2, 1.f / (256.f * 64.f), a4, st3);
  tr_a4<<<4096, 256, 0, stream>>>(a4, a4n);

  // ---- encoder FC (fp32) ----
  gemm_abt<<<dim3(2, 4, 8), 256, 0, stream>>>(a4n, wmu, nullptr, st3,
                                              1.f / 4096.f, nullptr, P, 4096,
                                              0, 0, 1.f, 0);
  gemm_reduce<<<128, 256, 0, stream>>>(P, ze, bmu, 256, 128, 256, 0, 1.f, 0, 8);
  gemm_abt<<<dim3(2, 4, 8), 256, 0, stream>>>(a4n, wcov, nullptr, st3,
                                              1.f / 4096.f, nullptr, P, 4096,
                                              0, 0, 1.f, 0);
  gemm_reduce<<<128, 256, 0, stream>>>(P, ze, bcov, 256, 128, 256, 128, 1.f, 1, 8);

  // ---- VQ (fp32) ----
  gemm_abt<<<dim3(128, 4, 1), 256, 0, stream>>>(ze, cb, csq, nullptr, 0.f, d2,
                                                nullptr, 256, 8192, 0, -2.f, 0);
  argmin_d2<<<256, 256, 0, stream>>>(d2, idx);
  vq_gather_loss<<<256, 256, 0, stream>>>(ze, cb, idx, zq, lossacc);

  // ---- decoder FC (fp32) ----
  gemm_abt<<<dim3(64, 4, 1), 256, 0, stream>>>(zq, wfcT, bfcT, nullptr, 0.f,
                                               g0, nullptr, 256, 4096, 0, 1.f, 0);

  // ---- decoder ----
  mfmaconv<64, 1, 4, 256, 128, false, false><<<dim3(2, 64, 4), 256, 0, stream>>>(
      g0, wTt1, bt1, nullptr, 0.f, g1, st4);
  mfmaconv<64, 1, 8, 128, 64, true, false><<<dim3(1, 256, 4), 256, 0, stream>>>(
      g1, wTt2, bt2, st4, 1.f / (256.f * 64.f), g2, st5);
  convt_mfma<16, 64, true, false, 2><<<512, 256, 0, stream>>>(
      g2, wTt3, bt3, st5, 1.f / (256.f * 256.f), g3, st6);
  convt_mfma<32, 32, true, true, 4><<<1024, 256, 0, stream>>>(
      g3, wTt31, bt31, st6, 1.f / (256.f * 1024.f), g31, st7);

  convt4_mfma<<<1024, 256, 0, stream>>>(g31, wT4, bt4, st7,
                                        1.f / (256.f * 4096.f), (float*)d_out);
  write_loss<<<1, 1, 0, stream>>>(lossacc, (float*)d_out + 3145728);
}

// Round 7
// 520.117 us; speedup vs baseline: 1.2072x; 1.0372x over previous
//
#include <hip/hip_runtime.h>
#include <cmath>

// ---------------------------------------------------------------------------
// VQ-VAE forward. B=256, C=3, HW=64, D=256, K=8192, LAT=128
// R14 (resubmit; prior run died to container-acquisition failure, no kernel
// signal): mfmaconv k-loop rebuilt as single-barrier double-buffered
// pipeline: per step {issue k+1 global loads -> regs; MFMA on buf[cur];
// cvt+write regs -> buf[nxt]; ONE barrier}. Barriers halved, load latency
// hidden under MFMAs. Applies to conv2/3/4 + t1/t2 (5 dispatches).
// R13 conv1_mfma, R11 convt4 ring, R10 multi-strip convt_mfma, R9 bf16 tail.
// ---------------------------------------------------------------------------

#define EPS_BN 1e-5f
typedef unsigned short ushort;
typedef short short8 __attribute__((ext_vector_type(8)));
typedef ushort us4 __attribute__((ext_vector_type(4)));
typedef float f32x4 __attribute__((ext_vector_type(4)));

__device__ __forceinline__ float lrelu(float v) { return v >= 0.f ? v : 0.01f * v; }
__device__ __forceinline__ ushort f2bf(float f) {
  unsigned u = __float_as_uint(f);
  return (ushort)((u + 0x7FFF + ((u >> 16) & 1)) >> 16);
}
__device__ __forceinline__ float bf2f(ushort u) {
  return __uint_as_float(((unsigned)u) << 16);
}

// ======================= weight transposes (once per launch) ===============
// conv (COUT,CIN,3,3) -> bf16 [co][t*CIN+ci]
__global__ __launch_bounds__(256) void tr_convw_bf(const float* __restrict__ w,
                                                   ushort* __restrict__ wT,
                                                   int CIN, int COUT, int total) {
  int i = blockIdx.x * 256 + threadIdx.x;
  if (i >= total) return;
  int co = i / (9 * CIN);
  int r = i - co * 9 * CIN;
  int t = r / CIN, ci = r - t * CIN;
  wT[i] = f2bf(w[((size_t)co * CIN + ci) * 9 + t]);
}

// convT (CIN,COUT,3,3) -> bf16 parity-concat [p][co][k]
__global__ __launch_bounds__(256) void tr_convtw_bf(const float* __restrict__ w,
                                                    ushort* __restrict__ wT,
                                                    int CIN, int COUT, int total) {
  int i = blockIdx.x * 256 + threadIdx.x;
  if (i >= total) return;
  const int cc = CIN * COUT;
  int p, base, Kp;
  if (i < cc) { p = 0; base = 0; Kp = CIN; }
  else if (i < 3 * cc) { p = 1; base = cc; Kp = 2 * CIN; }
  else if (i < 5 * cc) { p = 2; base = 3 * cc; Kp = 2 * CIN; }
  else { p = 3; base = 5 * cc; Kp = 4 * CIN; }
  const int r = i - base;
  const int co = r / Kp;
  const int q = r - co * Kp;
  const int tix = q / CIN, ci = q - (q / CIN) * CIN;
  const int py = p >> 1, px = p & 1;
  const int nx = px ? 2 : 1;
  const int kyi = tix / nx, kxi = tix - kyi * nx;
  const int ky = py ? (kyi == 0 ? 0 : 2) : 1;
  const int kx = px ? (kxi == 0 ? 0 : 2) : 1;
  wT[i] = f2bf(w[((size_t)ci * COUT + co) * 9 + ky * 3 + kx]);
}

// convT (CIN,COUT=32,3,3) -> bf16 [t][co_slot][ci] (tap-major, columns
// PERMUTED so slot f*16+ln15 holds channel 2*ln15+f -> packed bf16 stores)
__global__ __launch_bounds__(256) void tr_convtw_tc(const float* __restrict__ w,
                                                    ushort* __restrict__ wT,
                                                    int CIN, int COUT, int total) {
  int i = blockIdx.x * 256 + threadIdx.x;
  if (i >= total) return;
  int ci = i % CIN;
  int tmp = i / CIN;
  int co = tmp % COUT;
  int t = tmp / COUT;
  const int co_slot = ((co & 1) << 4) | (co >> 1);
  wT[((size_t)t * COUT + co_slot) * CIN + ci] =
      f2bf(w[((size_t)ci * COUT + co) * 9 + t]);
}

// convt4 weights (CIN=32, COUT=3, 3,3) -> per-lane B fragments
__global__ __launch_bounds__(256) void tr_w4(const float* __restrict__ w,
                                             ushort* __restrict__ wT) {
  int i = blockIdx.x * 256 + threadIdx.x;
  if (i >= 4608) return;
  const int s = i >> 9;
  const int l = (i >> 3) & 63;
  const int j = i & 7;
  const int nn = l & 15;
  const int ci = ((l >> 4) << 3) + j;
  const int ty = s / 3, tx = s - ty * 3;
  ushort v = 0;
  if (nn < 3)
    v = f2bf(w[((size_t)ci * 3 + nn) * 9 + (2 - ty) * 3 + (2 - tx)]);
  wT[i] = v;
}

// conv1 weights (32,3,3,3) -> MFMA B fragments, channel-pair permuted:
// wT[(f*64+l)*8+j] = W[c=2*(l&15)+f][k=(l>>4)*8+j], k=(ci*9+ky*3+kx), 0 pad.
__global__ __launch_bounds__(256) void tr_w1b(const float* __restrict__ w,
                                              ushort* __restrict__ wT) {
  int i = blockIdx.x * 256 + threadIdx.x;
  if (i >= 1024) return;
  const int j = i & 7, l = (i >> 3) & 63, f = i >> 9;
  const int c = 2 * (l & 15) + f;
  const int k = ((l >> 4) << 3) + j;
  ushort v = 0;
  if (k < 27) {
    const int ci = k / 9, r = k - ci * 9;
    v = f2bf(w[((size_t)c * 3 + ci) * 9 + r]);
  }
  wT[i] = v;
}

// a4 NHWC [256,4,4,256] -> NCHW [256,256,4,4]
__global__ __launch_bounds__(256) void tr_a4(const float* __restrict__ in,
                                             float* __restrict__ out) {
  int i = blockIdx.x * 256 + threadIdx.x;
  int n = i >> 12, k = i & 4095;
  out[i] = in[(size_t)(n << 12) + ((k & 15) << 8) + (k >> 4)];
}

// wfc [4096,256] + bfc: permute ROWS from (c,y,x) to (y,x,c)
__global__ __launch_bounds__(256) void tr_fcdec(const float* __restrict__ in,
                                                const float* __restrict__ bin,
                                                float* __restrict__ out,
                                                float* __restrict__ bout) {
  int i = blockIdx.x * 256 + threadIdx.x;
  int k = i >> 8, d = i & 255;
  int kp = (k & 15) * 256 + (k >> 4);
  out[(size_t)kp * 256 + d] = in[i];
  if (d == 0) bout[kp] = bin[k];
}

// ======================= bf16 MFMA implicit-GEMM conv / convT ==============
// R14: single-barrier double-buffered k-loop (async-STAGE split).
template <int TN, int MODE, int IH, int CIN, int COUT, bool HASN, bool INBF>
__global__ __launch_bounds__(256) void mfmaconv(
    const float* __restrict__ X, const ushort* __restrict__ WT,
    const float* __restrict__ bias, const float* __restrict__ st, float invN,
    float* __restrict__ Y, float* __restrict__ stOut) {
  constexpr int OH = (MODE == 0) ? IH / 2 : 2 * IH;
  constexpr int NF = TN / 16;
  __shared__ short As[2][64][40];
  __shared__ short Bs[2][TN][40];
  __shared__ float nrm0[HASN ? CIN : 4], nrm1[HASN ? CIN : 4];
  __shared__ float redS[4][TN], redQ[4][TN];
  const int tid = threadIdx.x;
  const int wv = tid >> 6, lane = tid & 63;
  const int quad = lane >> 4, ln15 = tid & 15;
  if (HASN) {
    for (int c = tid; c < CIN; c += 256) {
      float m = st[c] * invN;
      float var = st[256 + c] * invN - m * m;
      float s = rsqrtf(var + EPS_BN);
      nrm0[c] = s;
      nrm1[c] = m * s;
    }
    __syncthreads();
  }
  int py = 0, px = 0, nx = 1, K = 9 * CIN;
  const ushort* W = WT;
  if (MODE == 1) {
    const int pz = blockIdx.z;
    py = pz >> 1;
    px = pz & 1;
    nx = px ? 2 : 1;
    const int ny = py ? 2 : 1;
    K = ny * nx * CIN;
    const int pre[4] = {0, 1, 3, 5};
    W = WT + (size_t)pre[pz] * CIN * COUT;
  }
  const int gyTM = blockIdx.y * 64;
  const int gxTN = blockIdx.x * TN;

  const int sm = tid & 63, skg = (tid >> 6) * 8;
  const int bn = tid >> 2, bkg = (tid & 3) * 8;
  int baseNB, baseIY, baseIX;
  {
    const int gm = gyTM + sm;
    if (MODE == 0) {
      const int ni = gm / (OH * OH), r = gm % (OH * OH);
      baseNB = ni * IH * IH;
      baseIY = 2 * (r / OH) - 1;
      baseIX = 2 * (r % OH) - 1;
    } else {
      const int ni = gm / (IH * IH), r = gm % (IH * IH);
      baseNB = ni * IH * IH;
      baseIY = r / IH;
      baseIX = r % IH;
    }
  }
  f32x4 acc[NF];
#pragma unroll
  for (int f = 0; f < NF; ++f) acc[f] = (f32x4){0.f, 0.f, 0.f, 0.f};

  const int nsteps = K / 32;

  // ---- prologue: stage step 0 into buf 0 ----
  {
    int iy, ix;
    if (MODE == 0) {
      iy = baseIY;
      ix = baseIX;
    } else {
      iy = baseIY + (py ? 1 : 0);
      ix = baseIX + (px ? 1 : 0);
    }
    const bool ok =
        ((unsigned)iy < (unsigned)IH) && ((unsigned)ix < (unsigned)IH);
    float v[8] = {0.f, 0.f, 0.f, 0.f, 0.f, 0.f, 0.f, 0.f};
    if (ok) {
      if constexpr (INBF) {
        const ushort* xp =
            (const ushort*)X + ((size_t)baseNB + iy * IH + ix) * CIN + skg;
        const short8 raw = *(const short8*)xp;
#pragma unroll
        for (int u = 0; u < 8; ++u) v[u] = bf2f((ushort)raw[u]);
      } else {
        const float* xp = &X[((size_t)baseNB + iy * IH + ix) * CIN + skg];
        const float4 va = *(const float4*)xp, vb = *(const float4*)(xp + 4);
        v[0] = va.x; v[1] = va.y; v[2] = va.z; v[3] = va.w;
        v[4] = vb.x; v[5] = vb.y; v[6] = vb.z; v[7] = vb.w;
      }
      if (HASN) {
#pragma unroll
        for (int u = 0; u < 8; ++u)
          v[u] = fmaf(v[u], nrm0[skg + u], -nrm1[skg + u]);
      }
    }
    short8 o;
#pragma unroll
    for (int u = 0; u < 8; ++u) o[u] = (short)f2bf(v[u]);
    *(short8*)&As[0][sm][skg] = o;
    if (tid < TN * 4)
      *(short8*)&Bs[0][bn][bkg] =
          *(const short8*)&W[(size_t)(gxTN + bn) * K + bkg];
  }
  __syncthreads();

  for (int kk = 0; kk < nsteps; ++kk) {
    const int cur = kk & 1, nxt = cur ^ 1;

    // ---- issue next step's global loads into regs ----
    bool okN = false;
    int ci0N = 0;
    short8 rawN;
    float4 vaN, vbN;
    short8 rawBN;
    const bool hasNext = (kk + 1 < nsteps);
    if (hasNext) {
      const int k0n = (kk + 1) * 32;
      const int t = k0n / CIN;
      ci0N = k0n - t * CIN;
      int iy, ix;
      if (MODE == 0) {
        iy = baseIY + t / 3;
        ix = baseIX + (t - (t / 3) * 3);
      } else {
        const int kyi = t / nx, kxi = t - (t / nx) * nx;
        iy = baseIY + ((py && kyi == 0) ? 1 : 0);
        ix = baseIX + ((px && kxi == 0) ? 1 : 0);
      }
      okN = ((unsigned)iy < (unsigned)IH) && ((unsigned)ix < (unsigned)IH);
      if (okN) {
        if constexpr (INBF) {
          const ushort* xp = (const ushort*)X +
                             ((size_t)baseNB + iy * IH + ix) * CIN + ci0N + skg;
          rawN = *(const short8*)xp;
        } else {
          const float* xp =
              &X[((size_t)baseNB + iy * IH + ix) * CIN + ci0N + skg];
          vaN = *(const float4*)xp;
          vbN = *(const float4*)(xp + 4);
        }
      }
      if (tid < TN * 4)
        rawBN = *(const short8*)&W[(size_t)(gxTN + bn) * K + k0n + bkg];
    }

    // ---- MFMAs on buf[cur] ----
    const short8 a = *(const short8*)&As[cur][wv * 16 + ln15][quad * 8];
#pragma unroll
    for (int f = 0; f < NF; ++f) {
      const short8 b = *(const short8*)&Bs[cur][f * 16 + ln15][quad * 8];
      acc[f] = __builtin_amdgcn_mfma_f32_16x16x32_bf16(a, b, acc[f], 0, 0, 0);
    }

    // ---- convert + write next step into buf[nxt] ----
    if (hasNext) {
      float v[8] = {0.f, 0.f, 0.f, 0.f, 0.f, 0.f, 0.f, 0.f};
      if (okN) {
        if constexpr (INBF) {
#pragma unroll
          for (int u = 0; u < 8; ++u) v[u] = bf2f((ushort)rawN[u]);
        } else {
          v[0] = vaN.x; v[1] = vaN.y; v[2] = vaN.z; v[3] = vaN.w;
          v[4] = vbN.x; v[5] = vbN.y; v[6] = vbN.z; v[7] = vbN.w;
        }
        if (HASN) {
          const int c = ci0N + skg;
#pragma unroll
          for (int u = 0; u < 8; ++u)
            v[u] = fmaf(v[u], nrm0[c + u], -nrm1[c + u]);
        }
      }
      short8 o;
#pragma unroll
      for (int u = 0; u < 8; ++u) o[u] = (short)f2bf(v[u]);
      *(short8*)&As[nxt][sm][skg] = o;
      if (tid < TN * 4) *(short8*)&Bs[nxt][bn][bkg] = rawBN;
    }
    __syncthreads();
  }

  size_t maddr[4];
#pragma unroll
  for (int r = 0; r < 4; ++r) {
    const int m = gyTM + wv * 16 + quad * 4 + r;
    if (MODE == 0) {
      const int ni = m / (OH * OH), rr = m % (OH * OH);
      maddr[r] = (((size_t)ni * OH + rr / OH) * OH + rr % OH) * COUT;
    } else {
      const int ni = m / (IH * IH), rr = m % (IH * IH);
      const int oy = 2 * (rr / IH) + py, ox = 2 * (rr % IH) + px;
      maddr[r] = (((size_t)ni * OH + oy) * OH + ox) * COUT;
    }
  }
#pragma unroll
  for (int f = 0; f < NF; ++f) {
    const int col = gxTN + f * 16 + ln15;
    const float bv = bias[col];
    float cS = 0.f, cQ = 0.f;
#pragma unroll
    for (int r = 0; r < 4; ++r) {
      const float o = lrelu(acc[f][r] + bv);
      cS += o;
      cQ += o * o;
      Y[maddr[r] + col] = o;
    }
    cS += __shfl_down(cS, 32); cS += __shfl_down(cS, 16);
    cQ += __shfl_down(cQ, 32); cQ += __shfl_down(cQ, 16);
    if (lane < 16) { redS[wv][f * 16 + ln15] = cS; redQ[wv][f * 16 + ln15] = cQ; }
  }
  __syncthreads();
  if (tid < TN) {
    float S = redS[0][tid] + redS[1][tid] + redS[2][tid] + redS[3][tid];
    float Q = redQ[0][tid] + redQ[1][tid] + redQ[2][tid] + redQ[3][tid];
    atomicAdd(&stOut[gxTN + tid], S);
    atomicAdd(&stOut[256 + gxTN + tid], Q);
  }
}

// ======================= halo-tile merged convT (COUT=32, CIN<=64) =========
// Multi-strip software pipeline (R10). Output = packed bf16.
template <int IH, int CIN, bool HASN, bool INBF, int NSTRIP>
__global__ __launch_bounds__(256) void convt_mfma(
    const float* __restrict__ X, const ushort* __restrict__ WT,
    const float* __restrict__ bias, const float* __restrict__ st, float invN,
    float* __restrict__ Y, float* __restrict__ stOut) {
  constexpr int OH = 2 * IH;
  constexpr int L = (IH == 32) ? 5 : 4;
  constexpr int RSPAN = 64 / IH;
  constexpr int NP = (RSPAN + 1) * (IH + 1);
  constexpr int LK = CIN + 8;
  constexpr int TI = NP * (CIN / 8);
  constexpr int ITER = (TI + 255) / 256;
  __shared__ short As[2][NP][LK];
  __shared__ short Ws[9 * 32][LK];
  __shared__ float nrm0[HASN ? CIN : 4], nrm1[HASN ? CIN : 4];
  __shared__ float redS[4][32], redQ[4][32];
  const int tid = threadIdx.x;
  const int wv = tid >> 6, lane = tid & 63;
  const int quad = lane >> 4, ln15 = lane & 15;
  if (HASN) {
    for (int c = tid; c < CIN; c += 256) {
      float m = st[c] * invN;
      float var = st[256 + c] * invN - m * m;
      float s = rsqrtf(var + EPS_BN);
      nrm0[c] = s;
      nrm1[c] = m * s;
    }
  }
  for (int i = tid; i < 9 * 32 * (CIN / 8); i += 256) {
    const int row = i / (CIN / 8), kg = (i % (CIN / 8)) * 8;
    *(short8*)&Ws[row][kg] = *(const short8*)&WT[(size_t)row * CIN + kg];
  }
  __syncthreads();

  const int strip0 = blockIdx.x * NSTRIP;
  const int n = (strip0 * 64) / (IH * IH);
  const int iy0base = (strip0 * 64 - n * (IH * IH)) >> L;

#pragma unroll
  for (int it = 0; it < ITER; ++it) {
    const int i = tid + it * 256;
    if (i < TI) {
      const int slot = i / (CIN / 8), kg = (i % (CIN / 8)) * 8;
      const int ty = slot / (IH + 1), tx = slot - ty * (IH + 1);
      const int iy = iy0base + ty;
      short8 o = {0, 0, 0, 0, 0, 0, 0, 0};
      if (iy < IH && tx < IH) {
        float v[8];
        if constexpr (INBF) {
          const ushort* xp =
              (const ushort*)X + (((size_t)n * IH + iy) * IH + tx) * CIN + kg;
          const short8 raw = *(const short8*)xp;
#pragma unroll
          for (int u = 0; u < 8; ++u) v[u] = bf2f((ushort)raw[u]);
        } else {
          const float* xp = &X[(((size_t)n * IH + iy) * IH + tx) * CIN + kg];
          const float4 va = *(const float4*)xp, vb = *(const float4*)(xp + 4);
          v[0] = va.x; v[1] = va.y; v[2] = va.z; v[3] = va.w;
          v[4] = vb.x; v[5] = vb.y; v[6] = vb.z; v[7] = vb.w;
        }
        if (HASN) {
#pragma unroll
          for (int u = 0; u < 8; ++u)
            v[u] = fmaf(v[u], nrm0[kg + u], -nrm1[kg + u]);
        }
#pragma unroll
        for (int u = 0; u < 8; ++u) o[u] = (short)f2bf(v[u]);
      }
      *(short8*)&As[0][slot][kg] = o;
    }
  }
  __syncthreads();

  const int rA = wv * 16 + ln15;
  const int baseIdx = (rA >> L) * (IH + 1) + (rA & (IH - 1));
  constexpr int NT[4] = {4, 2, 2, 1};
  constexpr int TT[4][4] = {{4, 5, 7, 8}, {3, 6, 0, 0}, {1, 2, 0, 0}, {0, 0, 0, 0}};
  const float bv0 = bias[2 * ln15], bv1 = bias[2 * ln15 + 1];
  unsigned* Yp = (unsigned*)Y;
  float cS[2] = {0.f, 0.f}, cQ[2] = {0.f, 0.f};

#pragma unroll
  for (int s = 0; s < NSTRIP; ++s) {
    const int cur = s & 1, nxt = cur ^ 1;
    const int iy0 = iy0base + s * RSPAN;

    short8 rbf[ITER];
    float4 rva[ITER], rvb[ITER];
    bool vld[ITER];
    if (s + 1 < NSTRIP) {
      const int iyN0 = iy0 + RSPAN;
#pragma unroll
      for (int it = 0; it < ITER; ++it) {
        vld[it] = false;
        const int i = tid + it * 256;
        if (i < TI) {
          const int slot = i / (CIN / 8), kg = (i % (CIN / 8)) * 8;
          const int ty = slot / (IH + 1), tx = slot - ty * (IH + 1);
          const int iy = iyN0 + ty;
          if (iy < IH && tx < IH) {
            vld[it] = true;
            if constexpr (INBF) {
              const ushort* xp = (const ushort*)X +
                                 (((size_t)n * IH + iy) * IH + tx) * CIN + kg;
              rbf[it] = *(const short8*)xp;
            } else {
              const float* xp =
                  &X[(((size_t)n * IH + iy) * IH + tx) * CIN + kg];
              rva[it] = *(const float4*)xp;
              rvb[it] = *(const float4*)(xp + 4);
            }
          }
        }
      }
    }

    f32x4 acc[4][2];
#pragma unroll
    for (int p = 0; p < 4; ++p)
#pragma unroll
      for (int f = 0; f < 2; ++f) acc[p][f] = (f32x4){0.f, 0.f, 0.f, 0.f};
#pragma unroll
    for (int sh = 0; sh < 4; ++sh) {
      const int off = (sh >> 1) * (IH + 1) + (sh & 1);
#pragma unroll
      for (int j = 0; j < NT[sh]; ++j) {
        const int t = TT[sh][j];
        const int ky = t / 3, kx = t - ky * 3;
        const int par = ((ky == 1) ? 0 : 2) + ((kx == 1) ? 0 : 1);
#pragma unroll
        for (int ks = 0; ks < CIN / 32; ++ks) {
          const short8 a =
              *(const short8*)&As[cur][baseIdx + off][ks * 32 + quad * 8];
#pragma unroll
          for (int f = 0; f < 2; ++f) {
            const short8 b =
                *(const short8*)&Ws[t * 32 + f * 16 + ln15][ks * 32 + quad * 8];
            acc[par][f] = __builtin_amdgcn_mfma_f32_16x16x32_bf16(
                a, b, acc[par][f], 0, 0, 0);
          }
        }
      }
    }

#pragma unroll
    for (int i = 0; i < 4; ++i) {
      const int rD = wv * 16 + quad * 4 + i;
      const int ry = rD >> L, rx = rD & (IH - 1);
      const int iy = iy0 + ry;
#pragma unroll
      for (int p = 0; p < 4; ++p) {
        const int a = p >> 1, b = p & 1;
        const size_t base =
            (((size_t)n * OH + 2 * iy + a) * OH + 2 * rx + b) * 32;
        const float o0 = lrelu(acc[p][0][i] + bv0);
        const float o1 = lrelu(acc[p][1][i] + bv1);
        cS[0] += o0; cQ[0] += o0 * o0;
        cS[1] += o1; cQ[1] += o1 * o1;
        Yp[(base >> 1) + ln15] = (unsigned)f2bf(o0) | ((unsigned)f2bf(o1) << 16);
      }
    }

    if (s + 1 < NSTRIP) {
#pragma unroll
      for (int it = 0; it < ITER; ++it) {
        const int i = tid + it * 256;
        if (i < TI) {
          const int slot = i / (CIN / 8), kg = (i % (CIN / 8)) * 8;
          short8 o = {0, 0, 0, 0, 0, 0, 0, 0};
          if (vld[it]) {
            float v[8];
            if constexpr (INBF) {
#pragma unroll
              for (int u = 0; u < 8; ++u) v[u] = bf2f((ushort)rbf[it][u]);
            } else {
              v[0] = rva[it].x; v[1] = rva[it].y;
              v[2] = rva[it].z; v[3] = rva[it].w;
              v[4] = rvb[it].x; v[5] = rvb[it].y;
              v[6] = rvb[it].z; v[7] = rvb[it].w;
            }
            if (HASN) {
#pragma unroll
              for (int u = 0; u < 8; ++u)
                v[u] = fmaf(v[u], nrm0[kg + u], -nrm1[kg + u]);
            }
#pragma unroll
            for (int u = 0; u < 8; ++u) o[u] = (short)f2bf(v[u]);
          }
          *(short8*)&As[nxt][slot][kg] = o;
        }
      }
    }
    __syncthreads();
  }

#pragma unroll
  for (int f = 0; f < 2; ++f) {
    float s_ = cS[f], q_ = cQ[f];
    s_ += __shfl_down(s_, 32); s_ += __shfl_down(s_, 16);
    q_ += __shfl_down(q_, 32); q_ += __shfl_down(q_, 16);
    if (lane < 16) { redS[wv][f * 16 + ln15] = s_; redQ[wv][f * 16 + ln15] = q_; }
  }
  __syncthreads();
  if (tid < 32) {
    float S = redS[0][tid] + redS[1][tid] + redS[2][tid] + redS[3][tid];
    float Q = redQ[0][tid] + redQ[1][tid] + redQ[2][tid] + redQ[3][tid];
    const int ch = ((tid & 15) << 1) | (tid >> 4);
    atomicAdd(&stOut[ch], S);
    atomicAdd(&stOut[256 + ch], Q);
  }
}

// ======================= conv1 via MFMA im2col =============================
__global__ __launch_bounds__(256) void conv1_mfma(
    const float* __restrict__ x, const ushort* __restrict__ WT,
    const float* __restrict__ bias, ushort* __restrict__ y,
    float* __restrict__ st) {
  __shared__ float xin[3][17][67];
  __shared__ float redS[4][32], redQ[4][32];
  const int tid = threadIdx.x;
  const int wv = tid >> 6, lane = tid & 63;
  const int quad = lane >> 4, ln15 = lane & 15;
  const short8 bf0 = *(const short8*)&WT[(size_t)lane * 8];
  const short8 bf1 = *(const short8*)&WT[(size_t)(64 + lane) * 8];
  const int n = blockIdx.x >> 2;
  const int oy0 = (blockIdx.x & 3) * 8;
  const int iy0 = 2 * oy0 - 1;
  if (tid < 51) {  // zero halo col 0 (3*17)
    const int ci = tid / 17, r = tid - ci * 17;
    xin[ci][r][0] = 0.f;
  }
  for (int i = tid; i < 816; i += 256) {
    const int ci = i / 272;
    const int r = (i - ci * 272) >> 4;
    const int c4 = (i & 15) << 2;
    const int iy = iy0 + r;
    float4 v = make_float4(0.f, 0.f, 0.f, 0.f);
    if ((unsigned)iy < 64u)
      v = *(const float4*)&x[((size_t)(n * 3 + ci) * 64 + iy) * 64 + c4];
    xin[ci][r][1 + c4] = v.x;
    xin[ci][r][2 + c4] = v.y;
    xin[ci][r][3 + c4] = v.z;
    xin[ci][r][4 + c4] = v.w;
  }
  __syncthreads();

  const float bv0 = bias[2 * ln15], bv1 = bias[2 * ln15 + 1];
  unsigned* Yp = (unsigned*)y;
  float cS[2] = {0.f, 0.f}, cQ[2] = {0.f, 0.f};
#pragma unroll
  for (int rr = 0; rr < 2; ++rr) {
    const int row = 2 * wv + rr;
#pragma unroll
    for (int h = 0; h < 2; ++h) {
      short8 a;
#pragma unroll
      for (int j = 0; j < 8; ++j) {
        const int k = quad * 8 + j;
        float val = 0.f;
        if (k < 27) {
          const int ci = k / 9, r2 = k - ci * 9;
          const int ky = r2 / 3, kx = r2 - ky * 3;
          val = xin[ci][2 * row + ky][2 * (h * 16 + ln15) + kx];
        }
        a[j] = (short)f2bf(val);
      }
      f32x4 acc0 = (f32x4){0.f, 0.f, 0.f, 0.f};
      f32x4 acc1 = (f32x4){0.f, 0.f, 0.f, 0.f};
      acc0 = __builtin_amdgcn_mfma_f32_16x16x32_bf16(a, bf0, acc0, 0, 0, 0);
      acc1 = __builtin_amdgcn_mfma_f32_16x16x32_bf16(a, bf1, acc1, 0, 0, 0);
#pragma unroll
      for (int r = 0; r < 4; ++r) {
        const int px = h * 16 + quad * 4 + r;
        const float o0 = lrelu(acc0[r] + bv0);
        const float o1 = lrelu(acc1[r] + bv1);
        cS[0] += o0; cQ[0] += o0 * o0;
        cS[1] += o1; cQ[1] += o1 * o1;
        Yp[((size_t)n * 1024 + (oy0 + row) * 32 + px) * 16 + ln15] =
            (unsigned)f2bf(o0) | ((unsigned)f2bf(o1) << 16);
      }
    }
  }
#pragma unroll
  for (int f = 0; f < 2; ++f) {
    float s_ = cS[f], q_ = cQ[f];
    s_ += __shfl_down(s_, 32); s_ += __shfl_down(s_, 16);
    q_ += __shfl_down(q_, 32); q_ += __shfl_down(q_, 16);
    if (lane < 16) { redS[wv][f * 16 + ln15] = s_; redQ[wv][f * 16 + ln15] = q_; }
  }
  __syncthreads();
  if (tid < 32) {
    float S = redS[0][tid] + redS[1][tid] + redS[2][tid] + redS[3][tid];
    float Q = redQ[0][tid] + redQ[1][tid] + redQ[2][tid] + redQ[3][tid];
    const int ch = ((tid & 15) << 1) | (tid >> 4);
    atomicAdd(&st[ch], S);
    atomicAdd(&st[256 + ch], Q);
  }
}

// ======================= final convT via MFMA + 4-row LDS ring =============
__global__ __launch_bounds__(256) void convt4_mfma(
    const float* __restrict__ X, const ushort* __restrict__ WT,
    const float* __restrict__ bias, const float* __restrict__ st, float invN,
    float* __restrict__ out) {
  __shared__ short ring[4][66][32];
  __shared__ float s0[32], s1[32];
  const int tid = threadIdx.x;
  const int wv = tid >> 6, lane = tid & 63;
  const int quad = lane >> 4, ln15 = lane & 15;
  if (tid < 32) {
    float m = st[tid] * invN;
    float var = st[256 + tid] * invN - m * m;
    float s = rsqrtf(var + EPS_BN);
    s0[tid] = s;
    s1[tid] = m * s;
  }
  if (tid >= 32 && tid < 64) {
    const int t = tid - 32;
    const int slot = t >> 3, h = (t >> 2) & 1, kg = (t & 3) * 8;
    short8 z = {0, 0, 0, 0, 0, 0, 0, 0};
    *(short8*)&ring[slot][h ? 65 : 0][kg] = z;
  }
  short8 bfrag[9];
#pragma unroll
  for (int s = 0; s < 9; ++s)
    bfrag[s] = *(const short8*)&WT[((size_t)s * 64 + lane) * 8];
  __syncthreads();

  const int n = blockIdx.x >> 2;
  const int y0 = (blockIdx.x & 3) * 16;
  const ushort* xn = (const ushort*)X + (size_t)n * 131072;
  const int spx = tid >> 2, skg = (tid & 3) * 8;

#pragma unroll
  for (int pr = 0; pr < 3; ++pr) {
    const int Y = y0 - 1 + pr;
    short8 o = {0, 0, 0, 0, 0, 0, 0, 0};
    if ((unsigned)Y < 64u) {
      const short8 raw = *(const short8*)&xn[((size_t)Y * 64 + spx) * 32 + skg];
#pragma unroll
      for (int u = 0; u < 8; ++u)
        o[u] = (short)f2bf(fmaf(bf2f((ushort)raw[u]), s0[skg + u], -s1[skg + u]));
    }
    *(short8*)&ring[Y & 3][spx + 1][skg] = o;
  }
  __syncthreads();

  const int x0 = wv * 16;
  const float bv = (ln15 < 3) ? bias[ln15] : 0.f;
  float* op = out + (size_t)n * 3 * 4096;

  for (int y = y0; y < y0 + 16; ++y) {
    const int Ypf = y + 2;
    const bool pre = (Ypf <= y0 + 16);
    short8 raw;
    bool vld = false;
    if (pre && (unsigned)Ypf < 64u) {
      raw = *(const short8*)&xn[((size_t)Ypf * 64 + spx) * 32 + skg];
      vld = true;
    }

    f32x4 acc0 = (f32x4){0.f, 0.f, 0.f, 0.f};
    f32x4 acc1 = (f32x4){0.f, 0.f, 0.f, 0.f};
#pragma unroll
    for (int ty = 0; ty < 3; ++ty) {
      const short* rp = &ring[(y - 1 + ty) & 3][0][0];
#pragma unroll
      for (int tx = 0; tx < 3; ++tx) {
        const short8 a = *(const short8*)&rp[(x0 + ln15 + tx) * 32 + quad * 8];
        const int s = ty * 3 + tx;
        if (s & 1)
          acc1 = __builtin_amdgcn_mfma_f32_16x16x32_bf16(a, bfrag[s], acc1, 0, 0, 0);
        else
          acc0 = __builtin_amdgcn_mfma_f32_16x16x32_bf16(a, bfrag[s], acc0, 0, 0, 0);
      }
    }

    if (ln15 < 3) {
      float4 o;
      float v;
      v = acc0[0] + acc1[0] + bv; o.x = 1.f / (1.f + __expf(-2.f * v));
      v = acc0[1] + acc1[1] + bv; o.y = 1.f / (1.f + __expf(-2.f * v));
      v = acc0[2] + acc1[2] + bv; o.z = 1.f / (1.f + __expf(-2.f * v));
      v = acc0[3] + acc1[3] + bv; o.w = 1.f / (1.f + __expf(-2.f * v));
      *(float4*)&op[(size_t)ln15 * 4096 + y * 64 + x0 + quad * 4] = o;
    }

    if (pre) {
      short8 o = {0, 0, 0, 0, 0, 0, 0, 0};
      if (vld) {
#pragma unroll
        for (int u = 0; u < 8; ++u)
          o[u] = (short)f2bf(
              fmaf(bf2f((ushort)raw[u]), s0[skg + u], -s1[skg + u]));
      }
      *(short8*)&ring[Ypf & 3][spx + 1][skg] = o;
    }
    __syncthreads();
  }
}

// ======================= dense GEMM (fc / VQ distance), fp32 ===============
__global__ __launch_bounds__(256) void gemm_abt(
    const float* __restrict__ A, const float* __restrict__ B,
    const float* __restrict__ bias, const float* __restrict__ stA, float invN,
    float* __restrict__ C, float* __restrict__ P, int K, int ldc, int col0,
    float alpha, int act) {
  __shared__ float As[16][68];
  __shared__ float Bsh[16][68];
  __shared__ float nrm[2][256];
  const int tid = threadIdx.x;
  if (stA) {
    const int c = tid;
    float m = stA[c] * invN;
    float var = stA[256 + c] * invN - m * m;
    float s = rsqrtf(var + EPS_BN);
    nrm[0][c] = s;
    nrm[1][c] = m * s;
    __syncthreads();
  }
  const int lm = tid >> 2, lk = (tid & 3) << 2;
  const int KS = gridDim.z;
  const int kChunk = K / KS;
  const int kStart = blockIdx.z * kChunk;
  const float* Arow = A + (size_t)(blockIdx.y * 64 + lm) * K + lk;
  const float* Brow = B + (size_t)(blockIdx.x * 64 + lm) * K + lk;
  float acc[4][4] = {};
  const int m0 = (tid >> 4) << 2, n0 = (tid & 15) << 2;

  for (int k0 = kStart; k0 < kStart + kChunk; k0 += 16) {
    float4 av = *(const float4*)(Arow + k0);
    float4 bv = *(const float4*)(Brow + k0);
    if (stA) {
      const int ch = (k0 + lk) >> 4;
      const float s = nrm[0][ch], ms = nrm[1][ch];
      av.x = fmaf(av.x, s, -ms);
      av.y = fmaf(av.y, s, -ms);
      av.z = fmaf(av.z, s, -ms);
      av.w = fmaf(av.w, s, -ms);
    }
    As[lk + 0][lm] = av.x; As[lk + 1][lm] = av.y;
    As[lk + 2][lm] = av.z; As[lk + 3][lm] = av.w;
    Bsh[lk + 0][lm] = bv.x; Bsh[lk + 1][lm] = bv.y;
    Bsh[lk + 2][lm] = bv.z; Bsh[lk + 3][lm] = bv.w;
    __syncthreads();
#pragma unroll
    for (int kk = 0; kk < 16; ++kk) {
      const float4 a = *(const float4*)&As[kk][m0];
      const float4 b = *(const float4*)&Bsh[kk][n0];
      acc[0][0] = fmaf(a.x, b.x, acc[0][0]); acc[0][1] = fmaf(a.x, b.y, acc[0][1]);
      acc[0][2] = fmaf(a.x, b.z, acc[0][2]); acc[0][3] = fmaf(a.x, b.w, acc[0][3]);
      acc[1][0] = fmaf(a.y, b.x, acc[1][0]); acc[1][1] = fmaf(a.y, b.y, acc[1][1]);
      acc[1][2] = fmaf(a.y, b.z, acc[1][2]); acc[1][3] = fmaf(a.y, b.w, acc[1][3]);
      acc[2][0] = fmaf(a.z, b.x, acc[2][0]); acc[2][1] = fmaf(a.z, b.y, acc[2][1]);
      acc[2][2] = fmaf(a.z, b.z, acc[2][2]); acc[2][3] = fmaf(a.z, b.w, acc[2][3]);
      acc[3][0] = fmaf(a.w, b.x, acc[3][0]); acc[3][1] = fmaf(a.w, b.y, acc[3][1]);
      acc[3][2] = fmaf(a.w, b.z, acc[3][2]); acc[3][3] = fmaf(a.w, b.w, acc[3][3]);
    }
    __syncthreads();
  }

  const int gm = blockIdx.y * 64 + m0;
  const int gn = blockIdx.x * 64 + n0;
  if (KS == 1) {
#pragma unroll
    for (int i = 0; i < 4; ++i) {
      float4 o;
      o.x = alpha * acc[i][0] + bias[gn + 0];
      o.y = alpha * acc[i][1] + bias[gn + 1];
      o.z = alpha * acc[i][2] + bias[gn + 2];
      o.w = alpha * acc[i][3] + bias[gn + 3];
      if (act == 1) {
        o.x = fmaxf(o.x, 0.f); o.y = fmaxf(o.y, 0.f);
        o.z = fmaxf(o.z, 0.f); o.w = fmaxf(o.w, 0.f);
      }
      *(float4*)&C[(size_t)(gm + i) * ldc + col0 + gn] = o;
    }
  } else {
    const int M = gridDim.y * 64, N = gridDim.x * 64;
#pragma unroll
    for (int i = 0; i < 4; ++i)
      *(float4*)&P[((size_t)blockIdx.z * M + gm + i) * N + gn] =
          make_float4(acc[i][0], acc[i][1], acc[i][2], acc[i][3]);
  }
}

__global__ __launch_bounds__(256) void gemm_reduce(
    const float* __restrict__ P, float* __restrict__ C,
    const float* __restrict__ bias, int M, int N, int ldc, int col0,
    float alpha, int act, int KS) {
  const int idx = blockIdx.x * 256 + threadIdx.x;
  if (idx >= M * N) return;
  const int m = idx / N, n = idx % N;
  float s = 0.f;
  for (int z = 0; z < KS; ++z) s += P[((size_t)z * M + m) * N + n];
  float v = alpha * s + bias[n];
  if (act == 1) v = fmaxf(v, 0.f);
  C[(size_t)m * ldc + col0 + n] = v;
}

// ======================= VQ =================================================
__global__ __launch_bounds__(256) void rowsq(const float* __restrict__ cb,
                                             float* __restrict__ csq) {
  const int row = blockIdx.x * 4 + (threadIdx.x >> 6);
  const int ln = threadIdx.x & 63;
  const float4 v = ((const float4*)(cb + (size_t)row * 256))[ln];
  float s = v.x * v.x + v.y * v.y + v.z * v.z + v.w * v.w;
#pragma unroll
  for (int off = 32; off > 0; off >>= 1) s += __shfl_down(s, off);
  if (ln == 0) csq[row] = s;
}

__global__ __launch_bounds__(256) void argmin_d2(const float* __restrict__ d2,
                                                 int* __restrict__ idx) {
  const int b = blockIdx.x, t = threadIdx.x;
  const float* row = d2 + (size_t)b * 8192;
  float best = 3.4e38f;
  int bi = 0x7fffffff;
  for (int k = t; k < 8192; k += 256) {
    const float v = row[k];
    if (v < best) { best = v; bi = k; }
  }
  __shared__ float bval[256];
  __shared__ int bidx[256];
  bval[t] = best;
  bidx[t] = bi;
  __syncthreads();
  for (int s = 128; s > 0; s >>= 1) {
    if (t < s) {
      const float ov = bval[t + s];
      const int oi = bidx[t + s];
      if (ov < bval[t] || (ov == bval[t] && oi < bidx[t])) {
        bval[t] = ov;
        bidx[t] = oi;
      }
    }
    __syncthreads();
  }
  if (t == 0) idx[b] = bidx[0];
}

__global__ __launch_bounds__(256) void vq_gather_loss(
    const float* __restrict__ ze, const float* __restrict__ cb,
    const int* __restrict__ idx, float* __restrict__ zq,
    float* __restrict__ lossacc) {
  const int b = blockIdx.x, d = threadIdx.x;
  const int i = b * 256 + d;
  const float q = cb[(size_t)idx[b] * 256 + d];
  zq[i] = q;
  const float df = ze[i] - q;
  float v = df * df;
  __shared__ float sh[256];
  sh[d] = v;
  __syncthreads();
  for (int s = 128; s > 0; s >>= 1) {
    if (d < s) sh[d] += sh[d + s];
    __syncthreads();
  }
  if (d == 0) atomicAdd(lossacc, sh[0]);
}

__global__ void write_loss(const float* __restrict__ lossacc,
                           float* __restrict__ out) {
  out[0] = 2.f * lossacc[0];
}

// ---------------------------------------------------------------------------
extern "C" void kernel_launch(void* const* d_in, const int* in_sizes, int n_in,
                              void* d_out, int out_size, void* d_ws,
                              size_t ws_size, hipStream_t stream) {
  const float* x = (const float*)d_in[0];
  const float* ew1 = (const float*)d_in[1];
  const float* eb1 = (const float*)d_in[2];
  const float* ew2 = (const float*)d_in[3];
  const float* eb2 = (const float*)d_in[4];
  const float* ew3 = (const float*)d_in[5];
  const float* eb3 = (const float*)d_in[6];
  const float* ew4 = (const float*)d_in[7];
  const float* eb4 = (const float*)d_in[8];
  const float* wmu = (const float*)d_in[9];
  const float* bmu = (const float*)d_in[10];
  const float* wcov = (const float*)d_in[11];
  const float* bcov = (const float*)d_in[12];
  const float* cb = (const float*)d_in[13];
  const float* wfc = (const float*)d_in[14];
  const float* bfc = (const float*)d_in[15];
  const float* wt1 = (const float*)d_in[16];
  const float* bt1 = (const float*)d_in[17];
  const float* wt2 = (const float*)d_in[18];
  const float* bt2 = (const float*)d_in[19];
  const float* wt3 = (const float*)d_in[20];
  const float* bt3 = (const float*)d_in[21];
  const float* wt31 = (const float*)d_in[22];
  const float* bt31 = (const float*)d_in[23];
  const float* wt4 = (const float*)d_in[24];
  const float* bt4 = (const float*)d_in[25];

  float* ws = (float*)d_ws;
  float* a1 = ws;               // NHWC [256,32,32,32] bf16 (reused as g3, bf16)
  float* a2 = a1 + 8388608;     // NHWC [256,16,16,64]  (reused as g2)
  float* a3 = a2 + 4194304;     // NHWC [256,8,8,128]   (reused as g1)
  float* a4 = a3 + 2097152;     // NHWC [256,4,4,256]   (reused as g0)
  float* g31 = a4 + 1048576;    // NHWC [256,64,64,32] bf16 (region 33554432 f)
  float* d2 = g31;              // [256,8192]
  float* P = g31 + 2097152;     // 262144
  float* csq = g31 + 2359296;   // 8192
  float* a4n = g31 + 2367488;   // NCHW a4 copy
  float* wfcT = g31 + 3416064;  // 1048576
  float* bfcT = g31 + 4464640;  // 4096
  ushort* wTc2 = (ushort*)(g31 + 4468736);  // 18432 bf16
  ushort* wTc3 = (ushort*)(g31 + 4487168);  // 73728 bf16
  ushort* wTc4 = (ushort*)(g31 + 4560896);  // 294912 bf16
  float* ze = g31 + 33554432;   // [256,256]
  float* zq = ze + 65536;
  float* stats = zq + 65536;    // 8 layers x 512
  float* lossacc = stats + 4096;
  int* idx = (int*)(lossacc + 4);
  ushort* wTt1 = (ushort*)(lossacc + 4 + 256);  // 294912 bf16 (parity)
  ushort* wTt2 = wTt1 + 294912;                 // 73728 bf16 (parity)
  ushort* wTt3 = wTt2 + 73728;                  // 18432 bf16 (tap-major,perm)
  ushort* wTt31 = wTt3 + 18432;                 // 9216 bf16 (tap-major,perm)
  ushort* wT4 = wTt31 + 9216;                   // 4608 bf16 (convt4 B frags)
  ushort* wb1 = wT4 + 4608;                     // 1024 bf16 (conv1 B frags)
  float* g3 = a1;   // bf16 content
  float* g2 = a2;
  float* g1 = a3;
  float* g0 = a4;

  float* st0 = stats + 0 * 512;
  float* st1 = stats + 1 * 512;
  float* st2 = stats + 2 * 512;
  float* st3 = stats + 3 * 512;
  float* st4 = stats + 4 * 512;
  float* st5 = stats + 5 * 512;
  float* st6 = stats + 6 * 512;
  float* st7 = stats + 7 * 512;

  hipMemsetAsync(stats, 0, (4096 + 8) * sizeof(float), stream);

  // ---- weight transposes (bf16) ----
  tr_convw_bf<<<72, 256, 0, stream>>>(ew2, wTc2, 32, 64, 18432);
  tr_convw_bf<<<288, 256, 0, stream>>>(ew3, wTc3, 64, 128, 73728);
  tr_convw_bf<<<1152, 256, 0, stream>>>(ew4, wTc4, 128, 256, 294912);
  tr_convtw_bf<<<1152, 256, 0, stream>>>(wt1, wTt1, 256, 128, 294912);
  tr_convtw_bf<<<288, 256, 0, stream>>>(wt2, wTt2, 128, 64, 73728);
  tr_convtw_tc<<<72, 256, 0, stream>>>(wt3, wTt3, 64, 32, 18432);
  tr_convtw_tc<<<36, 256, 0, stream>>>(wt31, wTt31, 32, 32, 9216);
  tr_w4<<<18, 256, 0, stream>>>(wt4, wT4);
  tr_w1b<<<4, 256, 0, stream>>>(ew1, wb1);
  tr_fcdec<<<4096, 256, 0, stream>>>(wfc, bfc, wfcT, bfcT);
  rowsq<<<2048, 256, 0, stream>>>(cb, csq);

  // ---- encoder ----
  conv1_mfma<<<1024, 256, 0, stream>>>(x, wb1, eb1, (ushort*)a1, st0);
  mfmaconv<64, 0, 32, 32, 64, true, true><<<dim3(1, 1024), 256, 0, stream>>>(
      a1, wTc2, eb2, st0, 1.f / (256.f * 1024.f), a2, st1);
  mfmaconv<64, 0, 16, 64, 128, true, false><<<dim3(2, 256), 256, 0, stream>>>(
      a2, wTc3, eb3, st1, 1.f / (256.f * 256.f), a3, st2);
  mfmaconv<64, 0, 8, 128, 256, true, false><<<dim3(4, 64), 256, 0, stream>>>(
      a3, wTc4, eb4, st2, 1.f / (256.f * 64.f), a4, st3);
  tr_a4<<<4096, 256, 0, stream>>>(a4, a4n);

  // ---- encoder FC (fp32) ----
  gemm_abt<<<dim3(2, 4, 8), 256, 0, stream>>>(a4n, wmu, nullptr, st3,
                                              1.f / 4096.f, nullptr, P, 4096,
                                              0, 0, 1.f, 0);
  gemm_reduce<<<128, 256, 0, stream>>>(P, ze, bmu, 256, 128, 256, 0, 1.f, 0, 8);
  gemm_abt<<<dim3(2, 4, 8), 256, 0, stream>>>(a4n, wcov, nullptr, st3,
                                              1.f / 4096.f, nullptr, P, 4096,
                                              0, 0, 1.f, 0);
  gemm_reduce<<<128, 256, 0, stream>>>(P, ze, bcov, 256, 128, 256, 128, 1.f, 1, 8);

  // ---- VQ (fp32) ----
  gemm_abt<<<dim3(128, 4, 1), 256, 0, stream>>>(ze, cb, csq, nullptr, 0.f, d2,
                                                nullptr, 256, 8192, 0, -2.f, 0);
  argmin_d2<<<256, 256, 0, stream>>>(d2, idx);
  vq_gather_loss<<<256, 256, 0, stream>>>(ze, cb, idx, zq, lossacc);

  // ---- decoder FC (fp32) ----
  gemm_abt<<<dim3(64, 4, 1), 256, 0, stream>>>(zq, wfcT, bfcT, nullptr, 0.f,
                                               g0, nullptr, 256, 4096, 0, 1.f, 0);

  // ---- decoder ----
  mfmaconv<64, 1, 4, 256, 128, false, false><<<dim3(2, 64, 4), 256, 0, stream>>>(
      g0, wTt1, bt1, nullptr, 0.f, g1, st4);
  mfmaconv<64, 1, 8, 128, 64, true, false><<<dim3(1, 256, 4), 256, 0, stream>>>(
      g1, wTt2, bt2, st4, 1.f / (256.f * 64.f), g2, st5);
  convt_mfma<16, 64, true, false, 2><<<512, 256, 0, stream>>>(
      g2, wTt3, bt3, st5, 1.f / (256.f * 256.f), g3, st6);
  convt_mfma<32, 32, true, true, 4><<<1024, 256, 0, stream>>>(
      g3, wTt31, bt31, st6, 1.f / (256.f * 1024.f), g31, st7);

  convt4_mfma<<<1024, 256, 0, stream>>>(g31, wT4, bt4, st7,
                                        1.f / (256.f * 4096.f), (float*)d_out);
  write_loss<<<1, 1, 0, stream>>>(lossacc, (float*)d_out + 3145728);
}

// Round 8
// 505.121 us; speedup vs baseline: 1.2430x; 1.0297x over previous
//
#include <hip/hip_runtime.h>
#include <cmath>

// ---------------------------------------------------------------------------
// VQ-VAE forward. B=256, C=3, HW=64, D=256, K=8192, LAT=128
// R15: VQ distance GEMM + decoder FC -> bf16 MFMA (gemm_bf_abt, 64x64 tile,
// R14-style double-buffered single-barrier k-loop). d2 = csq[n] - 2*ze.cb
// (row-constant |ze|^2 dropped: argmin-invariant). Loss still computed fp32
// from ze/cb in vq_gather_loss. Encoder FC stays fp32 (loss precision).
// R14 pipelined mfmaconv, R13 conv1_mfma, R11 convt4 ring, R10 multi-strip
// convt_mfma, R9 packed-bf16 tail retained.
// ---------------------------------------------------------------------------

#define EPS_BN 1e-5f
typedef unsigned short ushort;
typedef short short8 __attribute__((ext_vector_type(8)));
typedef ushort us4 __attribute__((ext_vector_type(4)));
typedef float f32x4 __attribute__((ext_vector_type(4)));

__device__ __forceinline__ float lrelu(float v) { return v >= 0.f ? v : 0.01f * v; }
__device__ __forceinline__ ushort f2bf(float f) {
  unsigned u = __float_as_uint(f);
  return (ushort)((u + 0x7FFF + ((u >> 16) & 1)) >> 16);
}
__device__ __forceinline__ float bf2f(ushort u) {
  return __uint_as_float(((unsigned)u) << 16);
}

// ======================= weight transposes (once per launch) ===============
// conv (COUT,CIN,3,3) -> bf16 [co][t*CIN+ci]
__global__ __launch_bounds__(256) void tr_convw_bf(const float* __restrict__ w,
                                                   ushort* __restrict__ wT,
                                                   int CIN, int COUT, int total) {
  int i = blockIdx.x * 256 + threadIdx.x;
  if (i >= total) return;
  int co = i / (9 * CIN);
  int r = i - co * 9 * CIN;
  int t = r / CIN, ci = r - t * CIN;
  wT[i] = f2bf(w[((size_t)co * CIN + ci) * 9 + t]);
}

// convT (CIN,COUT,3,3) -> bf16 parity-concat [p][co][k]
__global__ __launch_bounds__(256) void tr_convtw_bf(const float* __restrict__ w,
                                                    ushort* __restrict__ wT,
                                                    int CIN, int COUT, int total) {
  int i = blockIdx.x * 256 + threadIdx.x;
  if (i >= total) return;
  const int cc = CIN * COUT;
  int p, base, Kp;
  if (i < cc) { p = 0; base = 0; Kp = CIN; }
  else if (i < 3 * cc) { p = 1; base = cc; Kp = 2 * CIN; }
  else if (i < 5 * cc) { p = 2; base = 3 * cc; Kp = 2 * CIN; }
  else { p = 3; base = 5 * cc; Kp = 4 * CIN; }
  const int r = i - base;
  const int co = r / Kp;
  const int q = r - co * Kp;
  const int tix = q / CIN, ci = q - (q / CIN) * CIN;
  const int py = p >> 1, px = p & 1;
  const int nx = px ? 2 : 1;
  const int kyi = tix / nx, kxi = tix - kyi * nx;
  const int ky = py ? (kyi == 0 ? 0 : 2) : 1;
  const int kx = px ? (kxi == 0 ? 0 : 2) : 1;
  wT[i] = f2bf(w[((size_t)ci * COUT + co) * 9 + ky * 3 + kx]);
}

// convT (CIN,COUT=32,3,3) -> bf16 [t][co_slot][ci] (tap-major, columns
// PERMUTED so slot f*16+ln15 holds channel 2*ln15+f -> packed bf16 stores)
__global__ __launch_bounds__(256) void tr_convtw_tc(const float* __restrict__ w,
                                                    ushort* __restrict__ wT,
                                                    int CIN, int COUT, int total) {
  int i = blockIdx.x * 256 + threadIdx.x;
  if (i >= total) return;
  int ci = i % CIN;
  int tmp = i / CIN;
  int co = tmp % COUT;
  int t = tmp / COUT;
  const int co_slot = ((co & 1) << 4) | (co >> 1);
  wT[((size_t)t * COUT + co_slot) * CIN + ci] =
      f2bf(w[((size_t)ci * COUT + co) * 9 + t]);
}

// convt4 weights (CIN=32, COUT=3, 3,3) -> per-lane B fragments
__global__ __launch_bounds__(256) void tr_w4(const float* __restrict__ w,
                                             ushort* __restrict__ wT) {
  int i = blockIdx.x * 256 + threadIdx.x;
  if (i >= 4608) return;
  const int s = i >> 9;
  const int l = (i >> 3) & 63;
  const int j = i & 7;
  const int nn = l & 15;
  const int ci = ((l >> 4) << 3) + j;
  const int ty = s / 3, tx = s - ty * 3;
  ushort v = 0;
  if (nn < 3)
    v = f2bf(w[((size_t)ci * 3 + nn) * 9 + (2 - ty) * 3 + (2 - tx)]);
  wT[i] = v;
}

// conv1 weights (32,3,3,3) -> MFMA B fragments, channel-pair permuted:
// wT[(f*64+l)*8+j] = W[c=2*(l&15)+f][k=(l>>4)*8+j], k=(ci*9+ky*3+kx), 0 pad.
__global__ __launch_bounds__(256) void tr_w1b(const float* __restrict__ w,
                                              ushort* __restrict__ wT) {
  int i = blockIdx.x * 256 + threadIdx.x;
  if (i >= 1024) return;
  const int j = i & 7, l = (i >> 3) & 63, f = i >> 9;
  const int c = 2 * (l & 15) + f;
  const int k = ((l >> 4) << 3) + j;
  ushort v = 0;
  if (k < 27) {
    const int ci = k / 9, r = k - ci * 9;
    v = f2bf(w[((size_t)c * 3 + ci) * 9 + r]);
  }
  wT[i] = v;
}

// a4 NHWC [256,4,4,256] -> NCHW [256,256,4,4]
__global__ __launch_bounds__(256) void tr_a4(const float* __restrict__ in,
                                             float* __restrict__ out) {
  int i = blockIdx.x * 256 + threadIdx.x;
  int n = i >> 12, k = i & 4095;
  out[i] = in[(size_t)(n << 12) + ((k & 15) << 8) + (k >> 4)];
}

// wfc [4096,256] + bfc: permute ROWS from (c,y,x) to (y,x,c)
__global__ __launch_bounds__(256) void tr_fcdec(const float* __restrict__ in,
                                                const float* __restrict__ bin,
                                                float* __restrict__ out,
                                                float* __restrict__ bout) {
  int i = blockIdx.x * 256 + threadIdx.x;
  int k = i >> 8, d = i & 255;
  int kp = (k & 15) * 256 + (k >> 4);
  out[(size_t)kp * 256 + d] = in[i];
  if (d == 0) bout[kp] = bin[k];
}

// ======================= bf16 MFMA implicit-GEMM conv / convT ==============
// R14: single-barrier double-buffered k-loop (async-STAGE split).
template <int TN, int MODE, int IH, int CIN, int COUT, bool HASN, bool INBF>
__global__ __launch_bounds__(256) void mfmaconv(
    const float* __restrict__ X, const ushort* __restrict__ WT,
    const float* __restrict__ bias, const float* __restrict__ st, float invN,
    float* __restrict__ Y, float* __restrict__ stOut) {
  constexpr int OH = (MODE == 0) ? IH / 2 : 2 * IH;
  constexpr int NF = TN / 16;
  __shared__ short As[2][64][40];
  __shared__ short Bs[2][TN][40];
  __shared__ float nrm0[HASN ? CIN : 4], nrm1[HASN ? CIN : 4];
  __shared__ float redS[4][TN], redQ[4][TN];
  const int tid = threadIdx.x;
  const int wv = tid >> 6, lane = tid & 63;
  const int quad = lane >> 4, ln15 = tid & 15;
  if (HASN) {
    for (int c = tid; c < CIN; c += 256) {
      float m = st[c] * invN;
      float var = st[256 + c] * invN - m * m;
      float s = rsqrtf(var + EPS_BN);
      nrm0[c] = s;
      nrm1[c] = m * s;
    }
    __syncthreads();
  }
  int py = 0, px = 0, nx = 1, K = 9 * CIN;
  const ushort* W = WT;
  if (MODE == 1) {
    const int pz = blockIdx.z;
    py = pz >> 1;
    px = pz & 1;
    nx = px ? 2 : 1;
    const int ny = py ? 2 : 1;
    K = ny * nx * CIN;
    const int pre[4] = {0, 1, 3, 5};
    W = WT + (size_t)pre[pz] * CIN * COUT;
  }
  const int gyTM = blockIdx.y * 64;
  const int gxTN = blockIdx.x * TN;

  const int sm = tid & 63, skg = (tid >> 6) * 8;
  const int bn = tid >> 2, bkg = (tid & 3) * 8;
  int baseNB, baseIY, baseIX;
  {
    const int gm = gyTM + sm;
    if (MODE == 0) {
      const int ni = gm / (OH * OH), r = gm % (OH * OH);
      baseNB = ni * IH * IH;
      baseIY = 2 * (r / OH) - 1;
      baseIX = 2 * (r % OH) - 1;
    } else {
      const int ni = gm / (IH * IH), r = gm % (IH * IH);
      baseNB = ni * IH * IH;
      baseIY = r / IH;
      baseIX = r % IH;
    }
  }
  f32x4 acc[NF];
#pragma unroll
  for (int f = 0; f < NF; ++f) acc[f] = (f32x4){0.f, 0.f, 0.f, 0.f};

  const int nsteps = K / 32;

  // ---- prologue: stage step 0 into buf 0 ----
  {
    int iy, ix;
    if (MODE == 0) {
      iy = baseIY;
      ix = baseIX;
    } else {
      iy = baseIY + (py ? 1 : 0);
      ix = baseIX + (px ? 1 : 0);
    }
    const bool ok =
        ((unsigned)iy < (unsigned)IH) && ((unsigned)ix < (unsigned)IH);
    float v[8] = {0.f, 0.f, 0.f, 0.f, 0.f, 0.f, 0.f, 0.f};
    if (ok) {
      if constexpr (INBF) {
        const ushort* xp =
            (const ushort*)X + ((size_t)baseNB + iy * IH + ix) * CIN + skg;
        const short8 raw = *(const short8*)xp;
#pragma unroll
        for (int u = 0; u < 8; ++u) v[u] = bf2f((ushort)raw[u]);
      } else {
        const float* xp = &X[((size_t)baseNB + iy * IH + ix) * CIN + skg];
        const float4 va = *(const float4*)xp, vb = *(const float4*)(xp + 4);
        v[0] = va.x; v[1] = va.y; v[2] = va.z; v[3] = va.w;
        v[4] = vb.x; v[5] = vb.y; v[6] = vb.z; v[7] = vb.w;
      }
      if (HASN) {
#pragma unroll
        for (int u = 0; u < 8; ++u)
          v[u] = fmaf(v[u], nrm0[skg + u], -nrm1[skg + u]);
      }
    }
    short8 o;
#pragma unroll
    for (int u = 0; u < 8; ++u) o[u] = (short)f2bf(v[u]);
    *(short8*)&As[0][sm][skg] = o;
    if (tid < TN * 4)
      *(short8*)&Bs[0][bn][bkg] =
          *(const short8*)&W[(size_t)(gxTN + bn) * K + bkg];
  }
  __syncthreads();

  for (int kk = 0; kk < nsteps; ++kk) {
    const int cur = kk & 1, nxt = cur ^ 1;

    // ---- issue next step's global loads into regs ----
    bool okN = false;
    int ci0N = 0;
    short8 rawN;
    float4 vaN, vbN;
    short8 rawBN;
    const bool hasNext = (kk + 1 < nsteps);
    if (hasNext) {
      const int k0n = (kk + 1) * 32;
      const int t = k0n / CIN;
      ci0N = k0n - t * CIN;
      int iy, ix;
      if (MODE == 0) {
        iy = baseIY + t / 3;
        ix = baseIX + (t - (t / 3) * 3);
      } else {
        const int kyi = t / nx, kxi = t - (t / nx) * nx;
        iy = baseIY + ((py && kyi == 0) ? 1 : 0);
        ix = baseIX + ((px && kxi == 0) ? 1 : 0);
      }
      okN = ((unsigned)iy < (unsigned)IH) && ((unsigned)ix < (unsigned)IH);
      if (okN) {
        if constexpr (INBF) {
          const ushort* xp = (const ushort*)X +
                             ((size_t)baseNB + iy * IH + ix) * CIN + ci0N + skg;
          rawN = *(const short8*)xp;
        } else {
          const float* xp =
              &X[((size_t)baseNB + iy * IH + ix) * CIN + ci0N + skg];
          vaN = *(const float4*)xp;
          vbN = *(const float4*)(xp + 4);
        }
      }
      if (tid < TN * 4)
        rawBN = *(const short8*)&W[(size_t)(gxTN + bn) * K + k0n + bkg];
    }

    // ---- MFMAs on buf[cur] ----
    const short8 a = *(const short8*)&As[cur][wv * 16 + ln15][quad * 8];
#pragma unroll
    for (int f = 0; f < NF; ++f) {
      const short8 b = *(const short8*)&Bs[cur][f * 16 + ln15][quad * 8];
      acc[f] = __builtin_amdgcn_mfma_f32_16x16x32_bf16(a, b, acc[f], 0, 0, 0);
    }

    // ---- convert + write next step into buf[nxt] ----
    if (hasNext) {
      float v[8] = {0.f, 0.f, 0.f, 0.f, 0.f, 0.f, 0.f, 0.f};
      if (okN) {
        if constexpr (INBF) {
#pragma unroll
          for (int u = 0; u < 8; ++u) v[u] = bf2f((ushort)rawN[u]);
        } else {
          v[0] = vaN.x; v[1] = vaN.y; v[2] = vaN.z; v[3] = vaN.w;
          v[4] = vbN.x; v[5] = vbN.y; v[6] = vbN.z; v[7] = vbN.w;
        }
        if (HASN) {
          const int c = ci0N + skg;
#pragma unroll
          for (int u = 0; u < 8; ++u)
            v[u] = fmaf(v[u], nrm0[c + u], -nrm1[c + u]);
        }
      }
      short8 o;
#pragma unroll
      for (int u = 0; u < 8; ++u) o[u] = (short)f2bf(v[u]);
      *(short8*)&As[nxt][sm][skg] = o;
      if (tid < TN * 4) *(short8*)&Bs[nxt][bn][bkg] = rawBN;
    }
    __syncthreads();
  }

  size_t maddr[4];
#pragma unroll
  for (int r = 0; r < 4; ++r) {
    const int m = gyTM + wv * 16 + quad * 4 + r;
    if (MODE == 0) {
      const int ni = m / (OH * OH), rr = m % (OH * OH);
      maddr[r] = (((size_t)ni * OH + rr / OH) * OH + rr % OH) * COUT;
    } else {
      const int ni = m / (IH * IH), rr = m % (IH * IH);
      const int oy = 2 * (rr / IH) + py, ox = 2 * (rr % IH) + px;
      maddr[r] = (((size_t)ni * OH + oy) * OH + ox) * COUT;
    }
  }
#pragma unroll
  for (int f = 0; f < NF; ++f) {
    const int col = gxTN + f * 16 + ln15;
    const float bv = bias[col];
    float cS = 0.f, cQ = 0.f;
#pragma unroll
    for (int r = 0; r < 4; ++r) {
      const float o = lrelu(acc[f][r] + bv);
      cS += o;
      cQ += o * o;
      Y[maddr[r] + col] = o;
    }
    cS += __shfl_down(cS, 32); cS += __shfl_down(cS, 16);
    cQ += __shfl_down(cQ, 32); cQ += __shfl_down(cQ, 16);
    if (lane < 16) { redS[wv][f * 16 + ln15] = cS; redQ[wv][f * 16 + ln15] = cQ; }
  }
  __syncthreads();
  if (tid < TN) {
    float S = redS[0][tid] + redS[1][tid] + redS[2][tid] + redS[3][tid];
    float Q = redQ[0][tid] + redQ[1][tid] + redQ[2][tid] + redQ[3][tid];
    atomicAdd(&stOut[gxTN + tid], S);
    atomicAdd(&stOut[256 + gxTN + tid], Q);
  }
}

// ======================= bf16 MFMA dense GEMM: C = alpha*(A.B^T) + bias ====
// A[M,K], B[N,K] fp32 in memory (converted to bf16 on stage). 64x64 tile,
// double-buffered single-barrier k-loop. grid = (N/64, M/64). K % 32 == 0.
__global__ __launch_bounds__(256) void gemm_bf_abt(
    const float* __restrict__ A, const float* __restrict__ B,
    const float* __restrict__ bias, float* __restrict__ C, int K, int N,
    float alpha) {
  __shared__ short As[2][64][40];
  __shared__ short Bs[2][64][40];
  const int tid = threadIdx.x;
  const int wv = tid >> 6, lane = tid & 63;
  const int quad = lane >> 4, ln15 = lane & 15;
  const int gm0 = blockIdx.y * 64, gn0 = blockIdx.x * 64;
  const int sm = tid & 63, skg = (tid >> 6) * 8;
  const int bn = tid >> 2, bkg = (tid & 3) * 8;
  const float* Ap = A + (size_t)(gm0 + sm) * K + skg;
  const float* Bp = B + (size_t)(gn0 + bn) * K + bkg;
  f32x4 acc[4];
#pragma unroll
  for (int f = 0; f < 4; ++f) acc[f] = (f32x4){0.f, 0.f, 0.f, 0.f};
  const int nsteps = K / 32;

  // prologue: stage step 0
  {
    const float4 va = *(const float4*)Ap, vb = *(const float4*)(Ap + 4);
    short8 o;
    o[0] = (short)f2bf(va.x); o[1] = (short)f2bf(va.y);
    o[2] = (short)f2bf(va.z); o[3] = (short)f2bf(va.w);
    o[4] = (short)f2bf(vb.x); o[5] = (short)f2bf(vb.y);
    o[6] = (short)f2bf(vb.z); o[7] = (short)f2bf(vb.w);
    *(short8*)&As[0][sm][skg] = o;
    const float4 wa = *(const float4*)Bp, wb = *(const float4*)(Bp + 4);
    short8 p;
    p[0] = (short)f2bf(wa.x); p[1] = (short)f2bf(wa.y);
    p[2] = (short)f2bf(wa.z); p[3] = (short)f2bf(wa.w);
    p[4] = (short)f2bf(wb.x); p[5] = (short)f2bf(wb.y);
    p[6] = (short)f2bf(wb.z); p[7] = (short)f2bf(wb.w);
    *(short8*)&Bs[0][bn][bkg] = p;
  }
  __syncthreads();

  for (int kk = 0; kk < nsteps; ++kk) {
    const int cur = kk & 1, nxt = cur ^ 1;
    const bool hasNext = (kk + 1 < nsteps);
    float4 vaN, vbN, waN, wbN;
    if (hasNext) {
      const int k0n = (kk + 1) * 32;
      vaN = *(const float4*)(Ap + k0n);
      vbN = *(const float4*)(Ap + k0n + 4);
      waN = *(const float4*)(Bp + k0n);
      wbN = *(const float4*)(Bp + k0n + 4);
    }

    const short8 a = *(const short8*)&As[cur][wv * 16 + ln15][quad * 8];
#pragma unroll
    for (int f = 0; f < 4; ++f) {
      const short8 b = *(const short8*)&Bs[cur][f * 16 + ln15][quad * 8];
      acc[f] = __builtin_amdgcn_mfma_f32_16x16x32_bf16(a, b, acc[f], 0, 0, 0);
    }

    if (hasNext) {
      short8 o;
      o[0] = (short)f2bf(vaN.x); o[1] = (short)f2bf(vaN.y);
      o[2] = (short)f2bf(vaN.z); o[3] = (short)f2bf(vaN.w);
      o[4] = (short)f2bf(vbN.x); o[5] = (short)f2bf(vbN.y);
      o[6] = (short)f2bf(vbN.z); o[7] = (short)f2bf(vbN.w);
      *(short8*)&As[nxt][sm][skg] = o;
      short8 p;
      p[0] = (short)f2bf(waN.x); p[1] = (short)f2bf(waN.y);
      p[2] = (short)f2bf(waN.z); p[3] = (short)f2bf(waN.w);
      p[4] = (short)f2bf(wbN.x); p[5] = (short)f2bf(wbN.y);
      p[6] = (short)f2bf(wbN.z); p[7] = (short)f2bf(wbN.w);
      *(short8*)&Bs[nxt][bn][bkg] = p;
    }
    __syncthreads();
  }

#pragma unroll
  for (int f = 0; f < 4; ++f) {
    const int col = gn0 + f * 16 + ln15;
    const float bv = bias[col];
#pragma unroll
    for (int r = 0; r < 4; ++r) {
      const int row = gm0 + wv * 16 + quad * 4 + r;
      C[(size_t)row * N + col] = fmaf(alpha, acc[f][r], bv);
    }
  }
}

// ======================= halo-tile merged convT (COUT=32, CIN<=64) =========
// Multi-strip software pipeline (R10). Output = packed bf16.
template <int IH, int CIN, bool HASN, bool INBF, int NSTRIP>
__global__ __launch_bounds__(256) void convt_mfma(
    const float* __restrict__ X, const ushort* __restrict__ WT,
    const float* __restrict__ bias, const float* __restrict__ st, float invN,
    float* __restrict__ Y, float* __restrict__ stOut) {
  constexpr int OH = 2 * IH;
  constexpr int L = (IH == 32) ? 5 : 4;
  constexpr int RSPAN = 64 / IH;
  constexpr int NP = (RSPAN + 1) * (IH + 1);
  constexpr int LK = CIN + 8;
  constexpr int TI = NP * (CIN / 8);
  constexpr int ITER = (TI + 255) / 256;
  __shared__ short As[2][NP][LK];
  __shared__ short Ws[9 * 32][LK];
  __shared__ float nrm0[HASN ? CIN : 4], nrm1[HASN ? CIN : 4];
  __shared__ float redS[4][32], redQ[4][32];
  const int tid = threadIdx.x;
  const int wv = tid >> 6, lane = tid & 63;
  const int quad = lane >> 4, ln15 = lane & 15;
  if (HASN) {
    for (int c = tid; c < CIN; c += 256) {
      float m = st[c] * invN;
      float var = st[256 + c] * invN - m * m;
      float s = rsqrtf(var + EPS_BN);
      nrm0[c] = s;
      nrm1[c] = m * s;
    }
  }
  for (int i = tid; i < 9 * 32 * (CIN / 8); i += 256) {
    const int row = i / (CIN / 8), kg = (i % (CIN / 8)) * 8;
    *(short8*)&Ws[row][kg] = *(const short8*)&WT[(size_t)row * CIN + kg];
  }
  __syncthreads();

  const int strip0 = blockIdx.x * NSTRIP;
  const int n = (strip0 * 64) / (IH * IH);
  const int iy0base = (strip0 * 64 - n * (IH * IH)) >> L;

#pragma unroll
  for (int it = 0; it < ITER; ++it) {
    const int i = tid + it * 256;
    if (i < TI) {
      const int slot = i / (CIN / 8), kg = (i % (CIN / 8)) * 8;
      const int ty = slot / (IH + 1), tx = slot - ty * (IH + 1);
      const int iy = iy0base + ty;
      short8 o = {0, 0, 0, 0, 0, 0, 0, 0};
      if (iy < IH && tx < IH) {
        float v[8];
        if constexpr (INBF) {
          const ushort* xp =
              (const ushort*)X + (((size_t)n * IH + iy) * IH + tx) * CIN + kg;
          const short8 raw = *(const short8*)xp;
#pragma unroll
          for (int u = 0; u < 8; ++u) v[u] = bf2f((ushort)raw[u]);
        } else {
          const float* xp = &X[(((size_t)n * IH + iy) * IH + tx) * CIN + kg];
          const float4 va = *(const float4*)xp, vb = *(const float4*)(xp + 4);
          v[0] = va.x; v[1] = va.y; v[2] = va.z; v[3] = va.w;
          v[4] = vb.x; v[5] = vb.y; v[6] = vb.z; v[7] = vb.w;
        }
        if (HASN) {
#pragma unroll
          for (int u = 0; u < 8; ++u)
            v[u] = fmaf(v[u], nrm0[kg + u], -nrm1[kg + u]);
        }
#pragma unroll
        for (int u = 0; u < 8; ++u) o[u] = (short)f2bf(v[u]);
      }
      *(short8*)&As[0][slot][kg] = o;
    }
  }
  __syncthreads();

  const int rA = wv * 16 + ln15;
  const int baseIdx = (rA >> L) * (IH + 1) + (rA & (IH - 1));
  constexpr int NT[4] = {4, 2, 2, 1};
  constexpr int TT[4][4] = {{4, 5, 7, 8}, {3, 6, 0, 0}, {1, 2, 0, 0}, {0, 0, 0, 0}};
  const float bv0 = bias[2 * ln15], bv1 = bias[2 * ln15 + 1];
  unsigned* Yp = (unsigned*)Y;
  float cS[2] = {0.f, 0.f}, cQ[2] = {0.f, 0.f};

#pragma unroll
  for (int s = 0; s < NSTRIP; ++s) {
    const int cur = s & 1, nxt = cur ^ 1;
    const int iy0 = iy0base + s * RSPAN;

    short8 rbf[ITER];
    float4 rva[ITER], rvb[ITER];
    bool vld[ITER];
    if (s + 1 < NSTRIP) {
      const int iyN0 = iy0 + RSPAN;
#pragma unroll
      for (int it = 0; it < ITER; ++it) {
        vld[it] = false;
        const int i = tid + it * 256;
        if (i < TI) {
          const int slot = i / (CIN / 8), kg = (i % (CIN / 8)) * 8;
          const int ty = slot / (IH + 1), tx = slot - ty * (IH + 1);
          const int iy = iyN0 + ty;
          if (iy < IH && tx < IH) {
            vld[it] = true;
            if constexpr (INBF) {
              const ushort* xp = (const ushort*)X +
                                 (((size_t)n * IH + iy) * IH + tx) * CIN + kg;
              rbf[it] = *(const short8*)xp;
            } else {
              const float* xp =
                  &X[(((size_t)n * IH + iy) * IH + tx) * CIN + kg];
              rva[it] = *(const float4*)xp;
              rvb[it] = *(const float4*)(xp + 4);
            }
          }
        }
      }
    }

    f32x4 acc[4][2];
#pragma unroll
    for (int p = 0; p < 4; ++p)
#pragma unroll
      for (int f = 0; f < 2; ++f) acc[p][f] = (f32x4){0.f, 0.f, 0.f, 0.f};
#pragma unroll
    for (int sh = 0; sh < 4; ++sh) {
      const int off = (sh >> 1) * (IH + 1) + (sh & 1);
#pragma unroll
      for (int j = 0; j < NT[sh]; ++j) {
        const int t = TT[sh][j];
        const int ky = t / 3, kx = t - ky * 3;
        const int par = ((ky == 1) ? 0 : 2) + ((kx == 1) ? 0 : 1);
#pragma unroll
        for (int ks = 0; ks < CIN / 32; ++ks) {
          const short8 a =
              *(const short8*)&As[cur][baseIdx + off][ks * 32 + quad * 8];
#pragma unroll
          for (int f = 0; f < 2; ++f) {
            const short8 b =
                *(const short8*)&Ws[t * 32 + f * 16 + ln15][ks * 32 + quad * 8];
            acc[par][f] = __builtin_amdgcn_mfma_f32_16x16x32_bf16(
                a, b, acc[par][f], 0, 0, 0);
          }
        }
      }
    }

#pragma unroll
    for (int i = 0; i < 4; ++i) {
      const int rD = wv * 16 + quad * 4 + i;
      const int ry = rD >> L, rx = rD & (IH - 1);
      const int iy = iy0 + ry;
#pragma unroll
      for (int p = 0; p < 4; ++p) {
        const int a = p >> 1, b = p & 1;
        const size_t base =
            (((size_t)n * OH + 2 * iy + a) * OH + 2 * rx + b) * 32;
        const float o0 = lrelu(acc[p][0][i] + bv0);
        const float o1 = lrelu(acc[p][1][i] + bv1);
        cS[0] += o0; cQ[0] += o0 * o0;
        cS[1] += o1; cQ[1] += o1 * o1;
        Yp[(base >> 1) + ln15] = (unsigned)f2bf(o0) | ((unsigned)f2bf(o1) << 16);
      }
    }

    if (s + 1 < NSTRIP) {
#pragma unroll
      for (int it = 0; it < ITER; ++it) {
        const int i = tid + it * 256;
        if (i < TI) {
          const int slot = i / (CIN / 8), kg = (i % (CIN / 8)) * 8;
          short8 o = {0, 0, 0, 0, 0, 0, 0, 0};
          if (vld[it]) {
            float v[8];
            if constexpr (INBF) {
#pragma unroll
              for (int u = 0; u < 8; ++u) v[u] = bf2f((ushort)rbf[it][u]);
            } else {
              v[0] = rva[it].x; v[1] = rva[it].y;
              v[2] = rva[it].z; v[3] = rva[it].w;
              v[4] = rvb[it].x; v[5] = rvb[it].y;
              v[6] = rvb[it].z; v[7] = rvb[it].w;
            }
            if (HASN) {
#pragma unroll
              for (int u = 0; u < 8; ++u)
                v[u] = fmaf(v[u], nrm0[kg + u], -nrm1[kg + u]);
            }
#pragma unroll
            for (int u = 0; u < 8; ++u) o[u] = (short)f2bf(v[u]);
          }
          *(short8*)&As[nxt][slot][kg] = o;
        }
      }
    }
    __syncthreads();
  }

#pragma unroll
  for (int f = 0; f < 2; ++f) {
    float s_ = cS[f], q_ = cQ[f];
    s_ += __shfl_down(s_, 32); s_ += __shfl_down(s_, 16);
    q_ += __shfl_down(q_, 32); q_ += __shfl_down(q_, 16);
    if (lane < 16) { redS[wv][f * 16 + ln15] = s_; redQ[wv][f * 16 + ln15] = q_; }
  }
  __syncthreads();
  if (tid < 32) {
    float S = redS[0][tid] + redS[1][tid] + redS[2][tid] + redS[3][tid];
    float Q = redQ[0][tid] + redQ[1][tid] + redQ[2][tid] + redQ[3][tid];
    const int ch = ((tid & 15) << 1) | (tid >> 4);
    atomicAdd(&stOut[ch], S);
    atomicAdd(&stOut[256 + ch], Q);
  }
}

// ======================= conv1 via MFMA im2col =============================
__global__ __launch_bounds__(256) void conv1_mfma(
    const float* __restrict__ x, const ushort* __restrict__ WT,
    const float* __restrict__ bias, ushort* __restrict__ y,
    float* __restrict__ st) {
  __shared__ float xin[3][17][67];
  __shared__ float redS[4][32], redQ[4][32];
  const int tid = threadIdx.x;
  const int wv = tid >> 6, lane = tid & 63;
  const int quad = lane >> 4, ln15 = lane & 15;
  const short8 bf0 = *(const short8*)&WT[(size_t)lane * 8];
  const short8 bf1 = *(const short8*)&WT[(size_t)(64 + lane) * 8];
  const int n = blockIdx.x >> 2;
  const int oy0 = (blockIdx.x & 3) * 8;
  const int iy0 = 2 * oy0 - 1;
  if (tid < 51) {  // zero halo col 0 (3*17)
    const int ci = tid / 17, r = tid - ci * 17;
    xin[ci][r][0] = 0.f;
  }
  for (int i = tid; i < 816; i += 256) {
    const int ci = i / 272;
    const int r = (i - ci * 272) >> 4;
    const int c4 = (i & 15) << 2;
    const int iy = iy0 + r;
    float4 v = make_float4(0.f, 0.f, 0.f, 0.f);
    if ((unsigned)iy < 64u)
      v = *(const float4*)&x[((size_t)(n * 3 + ci) * 64 + iy) * 64 + c4];
    xin[ci][r][1 + c4] = v.x;
    xin[ci][r][2 + c4] = v.y;
    xin[ci][r][3 + c4] = v.z;
    xin[ci][r][4 + c4] = v.w;
  }
  __syncthreads();

  const float bv0 = bias[2 * ln15], bv1 = bias[2 * ln15 + 1];
  unsigned* Yp = (unsigned*)y;
  float cS[2] = {0.f, 0.f}, cQ[2] = {0.f, 0.f};
#pragma unroll
  for (int rr = 0; rr < 2; ++rr) {
    const int row = 2 * wv + rr;
#pragma unroll
    for (int h = 0; h < 2; ++h) {
      short8 a;
#pragma unroll
      for (int j = 0; j < 8; ++j) {
        const int k = quad * 8 + j;
        float val = 0.f;
        if (k < 27) {
          const int ci = k / 9, r2 = k - ci * 9;
          const int ky = r2 / 3, kx = r2 - ky * 3;
          val = xin[ci][2 * row + ky][2 * (h * 16 + ln15) + kx];
        }
        a[j] = (short)f2bf(val);
      }
      f32x4 acc0 = (f32x4){0.f, 0.f, 0.f, 0.f};
      f32x4 acc1 = (f32x4){0.f, 0.f, 0.f, 0.f};
      acc0 = __builtin_amdgcn_mfma_f32_16x16x32_bf16(a, bf0, acc0, 0, 0, 0);
      acc1 = __builtin_amdgcn_mfma_f32_16x16x32_bf16(a, bf1, acc1, 0, 0, 0);
#pragma unroll
      for (int r = 0; r < 4; ++r) {
        const int px = h * 16 + quad * 4 + r;
        const float o0 = lrelu(acc0[r] + bv0);
        const float o1 = lrelu(acc1[r] + bv1);
        cS[0] += o0; cQ[0] += o0 * o0;
        cS[1] += o1; cQ[1] += o1 * o1;
        Yp[((size_t)n * 1024 + (oy0 + row) * 32 + px) * 16 + ln15] =
            (unsigned)f2bf(o0) | ((unsigned)f2bf(o1) << 16);
      }
    }
  }
#pragma unroll
  for (int f = 0; f < 2; ++f) {
    float s_ = cS[f], q_ = cQ[f];
    s_ += __shfl_down(s_, 32); s_ += __shfl_down(s_, 16);
    q_ += __shfl_down(q_, 32); q_ += __shfl_down(q_, 16);
    if (lane < 16) { redS[wv][f * 16 + ln15] = s_; redQ[wv][f * 16 + ln15] = q_; }
  }
  __syncthreads();
  if (tid < 32) {
    float S = redS[0][tid] + redS[1][tid] + redS[2][tid] + redS[3][tid];
    float Q = redQ[0][tid] + redQ[1][tid] + redQ[2][tid] + redQ[3][tid];
    const int ch = ((tid & 15) << 1) | (tid >> 4);
    atomicAdd(&st[ch], S);
    atomicAdd(&st[256 + ch], Q);
  }
}

// ======================= final convT via MFMA + 4-row LDS ring =============
__global__ __launch_bounds__(256) void convt4_mfma(
    const float* __restrict__ X, const ushort* __restrict__ WT,
    const float* __restrict__ bias, const float* __restrict__ st, float invN,
    float* __restrict__ out) {
  __shared__ short ring[4][66][32];
  __shared__ float s0[32], s1[32];
  const int tid = threadIdx.x;
  const int wv = tid >> 6, lane = tid & 63;
  const int quad = lane >> 4, ln15 = lane & 15;
  if (tid < 32) {
    float m = st[tid] * invN;
    float var = st[256 + tid] * invN - m * m;
    float s = rsqrtf(var + EPS_BN);
    s0[tid] = s;
    s1[tid] = m * s;
  }
  if (tid >= 32 && tid < 64) {
    const int t = tid - 32;
    const int slot = t >> 3, h = (t >> 2) & 1, kg = (t & 3) * 8;
    short8 z = {0, 0, 0, 0, 0, 0, 0, 0};
    *(short8*)&ring[slot][h ? 65 : 0][kg] = z;
  }
  short8 bfrag[9];
#pragma unroll
  for (int s = 0; s < 9; ++s)
    bfrag[s] = *(const short8*)&WT[((size_t)s * 64 + lane) * 8];
  __syncthreads();

  const int n = blockIdx.x >> 2;
  const int y0 = (blockIdx.x & 3) * 16;
  const ushort* xn = (const ushort*)X + (size_t)n * 131072;
  const int spx = tid >> 2, skg = (tid & 3) * 8;

#pragma unroll
  for (int pr = 0; pr < 3; ++pr) {
    const int Y = y0 - 1 + pr;
    short8 o = {0, 0, 0, 0, 0, 0, 0, 0};
    if ((unsigned)Y < 64u) {
      const short8 raw = *(const short8*)&xn[((size_t)Y * 64 + spx) * 32 + skg];
#pragma unroll
      for (int u = 0; u < 8; ++u)
        o[u] = (short)f2bf(fmaf(bf2f((ushort)raw[u]), s0[skg + u], -s1[skg + u]));
    }
    *(short8*)&ring[Y & 3][spx + 1][skg] = o;
  }
  __syncthreads();

  const int x0 = wv * 16;
  const float bv = (ln15 < 3) ? bias[ln15] : 0.f;
  float* op = out + (size_t)n * 3 * 4096;

  for (int y = y0; y < y0 + 16; ++y) {
    const int Ypf = y + 2;
    const bool pre = (Ypf <= y0 + 16);
    short8 raw;
    bool vld = false;
    if (pre && (unsigned)Ypf < 64u) {
      raw = *(const short8*)&xn[((size_t)Ypf * 64 + spx) * 32 + skg];
      vld = true;
    }

    f32x4 acc0 = (f32x4){0.f, 0.f, 0.f, 0.f};
    f32x4 acc1 = (f32x4){0.f, 0.f, 0.f, 0.f};
#pragma unroll
    for (int ty = 0; ty < 3; ++ty) {
      const short* rp = &ring[(y - 1 + ty) & 3][0][0];
#pragma unroll
      for (int tx = 0; tx < 3; ++tx) {
        const short8 a = *(const short8*)&rp[(x0 + ln15 + tx) * 32 + quad * 8];
        const int s = ty * 3 + tx;
        if (s & 1)
          acc1 = __builtin_amdgcn_mfma_f32_16x16x32_bf16(a, bfrag[s], acc1, 0, 0, 0);
        else
          acc0 = __builtin_amdgcn_mfma_f32_16x16x32_bf16(a, bfrag[s], acc0, 0, 0, 0);
      }
    }

    if (ln15 < 3) {
      float4 o;
      float v;
      v = acc0[0] + acc1[0] + bv; o.x = 1.f / (1.f + __expf(-2.f * v));
      v = acc0[1] + acc1[1] + bv; o.y = 1.f / (1.f + __expf(-2.f * v));
      v = acc0[2] + acc1[2] + bv; o.z = 1.f / (1.f + __expf(-2.f * v));
      v = acc0[3] + acc1[3] + bv; o.w = 1.f / (1.f + __expf(-2.f * v));
      *(float4*)&op[(size_t)ln15 * 4096 + y * 64 + x0 + quad * 4] = o;
    }

    if (pre) {
      short8 o = {0, 0, 0, 0, 0, 0, 0, 0};
      if (vld) {
#pragma unroll
        for (int u = 0; u < 8; ++u)
          o[u] = (short)f2bf(
              fmaf(bf2f((ushort)raw[u]), s0[skg + u], -s1[skg + u]));
      }
      *(short8*)&ring[Ypf & 3][spx + 1][skg] = o;
    }
    __syncthreads();
  }
}

// ======================= dense GEMM (encoder FC), fp32 =====================
__global__ __launch_bounds__(256) void gemm_abt(
    const float* __restrict__ A, const float* __restrict__ B,
    const float* __restrict__ bias, const float* __restrict__ stA, float invN,
    float* __restrict__ C, float* __restrict__ P, int K, int ldc, int col0,
    float alpha, int act) {
  __shared__ float As[16][68];
  __shared__ float Bsh[16][68];
  __shared__ float nrm[2][256];
  const int tid = threadIdx.x;
  if (stA) {
    const int c = tid;
    float m = stA[c] * invN;
    float var = stA[256 + c] * invN - m * m;
    float s = rsqrtf(var + EPS_BN);
    nrm[0][c] = s;
    nrm[1][c] = m * s;
    __syncthreads();
  }
  const int lm = tid >> 2, lk = (tid & 3) << 2;
  const int KS = gridDim.z;
  const int kChunk = K / KS;
  const int kStart = blockIdx.z * kChunk;
  const float* Arow = A + (size_t)(blockIdx.y * 64 + lm) * K + lk;
  const float* Brow = B + (size_t)(blockIdx.x * 64 + lm) * K + lk;
  float acc[4][4] = {};
  const int m0 = (tid >> 4) << 2, n0 = (tid & 15) << 2;

  for (int k0 = kStart; k0 < kStart + kChunk; k0 += 16) {
    float4 av = *(const float4*)(Arow + k0);
    float4 bv = *(const float4*)(Brow + k0);
    if (stA) {
      const int ch = (k0 + lk) >> 4;
      const float s = nrm[0][ch], ms = nrm[1][ch];
      av.x = fmaf(av.x, s, -ms);
      av.y = fmaf(av.y, s, -ms);
      av.z = fmaf(av.z, s, -ms);
      av.w = fmaf(av.w, s, -ms);
    }
    As[lk + 0][lm] = av.x; As[lk + 1][lm] = av.y;
    As[lk + 2][lm] = av.z; As[lk + 3][lm] = av.w;
    Bsh[lk + 0][lm] = bv.x; Bsh[lk + 1][lm] = bv.y;
    Bsh[lk + 2][lm] = bv.z; Bsh[lk + 3][lm] = bv.w;
    __syncthreads();
#pragma unroll
    for (int kk = 0; kk < 16; ++kk) {
      const float4 a = *(const float4*)&As[kk][m0];
      const float4 b = *(const float4*)&Bsh[kk][n0];
      acc[0][0] = fmaf(a.x, b.x, acc[0][0]); acc[0][1] = fmaf(a.x, b.y, acc[0][1]);
      acc[0][2] = fmaf(a.x, b.z, acc[0][2]); acc[0][3] = fmaf(a.x, b.w, acc[0][3]);
      acc[1][0] = fmaf(a.y, b.x, acc[1][0]); acc[1][1] = fmaf(a.y, b.y, acc[1][1]);
      acc[1][2] = fmaf(a.y, b.z, acc[1][2]); acc[1][3] = fmaf(a.y, b.w, acc[1][3]);
      acc[2][0] = fmaf(a.z, b.x, acc[2][0]); acc[2][1] = fmaf(a.z, b.y, acc[2][1]);
      acc[2][2] = fmaf(a.z, b.z, acc[2][2]); acc[2][3] = fmaf(a.z, b.w, acc[2][3]);
      acc[3][0] = fmaf(a.w, b.x, acc[3][0]); acc[3][1] = fmaf(a.w, b.y, acc[3][1]);
      acc[3][2] = fmaf(a.w, b.z, acc[3][2]); acc[3][3] = fmaf(a.w, b.w, acc[3][3]);
    }
    __syncthreads();
  }

  const int gm = blockIdx.y * 64 + m0;
  const int gn = blockIdx.x * 64 + n0;
  if (KS == 1) {
#pragma unroll
    for (int i = 0; i < 4; ++i) {
      float4 o;
      o.x = alpha * acc[i][0] + bias[gn + 0];
      o.y = alpha * acc[i][1] + bias[gn + 1];
      o.z = alpha * acc[i][2] + bias[gn + 2];
      o.w = alpha * acc[i][3] + bias[gn + 3];
      if (act == 1) {
        o.x = fmaxf(o.x, 0.f); o.y = fmaxf(o.y, 0.f);
        o.z = fmaxf(o.z, 0.f); o.w = fmaxf(o.w, 0.f);
      }
      *(float4*)&C[(size_t)(gm + i) * ldc + col0 + gn] = o;
    }
  } else {
    const int M = gridDim.y * 64, N = gridDim.x * 64;
#pragma unroll
    for (int i = 0; i < 4; ++i)
      *(float4*)&P[((size_t)blockIdx.z * M + gm + i) * N + gn] =
          make_float4(acc[i][0], acc[i][1], acc[i][2], acc[i][3]);
  }
}

__global__ __launch_bounds__(256) void gemm_reduce(
    const float* __restrict__ P, float* __restrict__ C,
    const float* __restrict__ bias, int M, int N, int ldc, int col0,
    float alpha, int act, int KS) {
  const int idx = blockIdx.x * 256 + threadIdx.x;
  if (idx >= M * N) return;
  const int m = idx / N, n = idx % N;
  float s = 0.f;
  for (int z = 0; z < KS; ++z) s += P[((size_t)z * M + m) * N + n];
  float v = alpha * s + bias[n];
  if (act == 1) v = fmaxf(v, 0.f);
  C[(size_t)m * ldc + col0 + n] = v;
}

// ======================= VQ =================================================
__global__ __launch_bounds__(256) void rowsq(const float* __restrict__ cb,
                                             float* __restrict__ csq) {
  const int row = blockIdx.x * 4 + (threadIdx.x >> 6);
  const int ln = threadIdx.x & 63;
  const float4 v = ((const float4*)(cb + (size_t)row * 256))[ln];
  float s = v.x * v.x + v.y * v.y + v.z * v.z + v.w * v.w;
#pragma unroll
  for (int off = 32; off > 0; off >>= 1) s += __shfl_down(s, off);
  if (ln == 0) csq[row] = s;
}

__global__ __launch_bounds__(256) void argmin_d2(const float* __restrict__ d2,
                                                 int* __restrict__ idx) {
  const int b = blockIdx.x, t = threadIdx.x;
  const float* row = d2 + (size_t)b * 8192;
  float best = 3.4e38f;
  int bi = 0x7fffffff;
  for (int k = t; k < 8192; k += 256) {
    const float v = row[k];
    if (v < best) { best = v; bi = k; }
  }
  __shared__ float bval[256];
  __shared__ int bidx[256];
  bval[t] = best;
  bidx[t] = bi;
  __syncthreads();
  for (int s = 128; s > 0; s >>= 1) {
    if (t < s) {
      const float ov = bval[t + s];
      const int oi = bidx[t + s];
      if (ov < bval[t] || (ov == bval[t] && oi < bidx[t])) {
        bval[t] = ov;
        bidx[t] = oi;
      }
    }
    __syncthreads();
  }
  if (t == 0) idx[b] = bidx[0];
}

__global__ __launch_bounds__(256) void vq_gather_loss(
    const float* __restrict__ ze, const float* __restrict__ cb,
    const int* __restrict__ idx, float* __restrict__ zq,
    float* __restrict__ lossacc) {
  const int b = blockIdx.x, d = threadIdx.x;
  const int i = b * 256 + d;
  const float q = cb[(size_t)idx[b] * 256 + d];
  zq[i] = q;
  const float df = ze[i] - q;
  float v = df * df;
  __shared__ float sh[256];
  sh[d] = v;
  __syncthreads();
  for (int s = 128; s > 0; s >>= 1) {
    if (d < s) sh[d] += sh[d + s];
    __syncthreads();
  }
  if (d == 0) atomicAdd(lossacc, sh[0]);
}

__global__ void write_loss(const float* __restrict__ lossacc,
                           float* __restrict__ out) {
  out[0] = 2.f * lossacc[0];
}

// ---------------------------------------------------------------------------
extern "C" void kernel_launch(void* const* d_in, const int* in_sizes, int n_in,
                              void* d_out, int out_size, void* d_ws,
                              size_t ws_size, hipStream_t stream) {
  const float* x = (const float*)d_in[0];
  const float* ew1 = (const float*)d_in[1];
  const float* eb1 = (const float*)d_in[2];
  const float* ew2 = (const float*)d_in[3];
  const float* eb2 = (const float*)d_in[4];
  const float* ew3 = (const float*)d_in[5];
  const float* eb3 = (const float*)d_in[6];
  const float* ew4 = (const float*)d_in[7];
  const float* eb4 = (const float*)d_in[8];
  const float* wmu = (const float*)d_in[9];
  const float* bmu = (const float*)d_in[10];
  const float* wcov = (const float*)d_in[11];
  const float* bcov = (const float*)d_in[12];
  const float* cb = (const float*)d_in[13];
  const float* wfc = (const float*)d_in[14];
  const float* bfc = (const float*)d_in[15];
  const float* wt1 = (const float*)d_in[16];
  const float* bt1 = (const float*)d_in[17];
  const float* wt2 = (const float*)d_in[18];
  const float* bt2 = (const float*)d_in[19];
  const float* wt3 = (const float*)d_in[20];
  const float* bt3 = (const float*)d_in[21];
  const float* wt31 = (const float*)d_in[22];
  const float* bt31 = (const float*)d_in[23];
  const float* wt4 = (const float*)d_in[24];
  const float* bt4 = (const float*)d_in[25];

  float* ws = (float*)d_ws;
  float* a1 = ws;               // NHWC [256,32,32,32] bf16 (reused as g3, bf16)
  float* a2 = a1 + 8388608;     // NHWC [256,16,16,64]  (reused as g2)
  float* a3 = a2 + 4194304;     // NHWC [256,8,8,128]   (reused as g1)
  float* a4 = a3 + 2097152;     // NHWC [256,4,4,256]   (reused as g0)
  float* g31 = a4 + 1048576;    // NHWC [256,64,64,32] bf16 (region 33554432 f)
  float* d2 = g31;              // [256,8192]
  float* P = g31 + 2097152;     // 262144
  float* csq = g31 + 2359296;   // 8192
  float* a4n = g31 + 2367488;   // NCHW a4 copy
  float* wfcT = g31 + 3416064;  // 1048576
  float* bfcT = g31 + 4464640;  // 4096
  ushort* wTc2 = (ushort*)(g31 + 4468736);  // 18432 bf16
  ushort* wTc3 = (ushort*)(g31 + 4487168);  // 73728 bf16
  ushort* wTc4 = (ushort*)(g31 + 4560896);  // 294912 bf16
  float* ze = g31 + 33554432;   // [256,256]
  float* zq = ze + 65536;
  float* stats = zq + 65536;    // 8 layers x 512
  float* lossacc = stats + 4096;
  int* idx = (int*)(lossacc + 4);
  ushort* wTt1 = (ushort*)(lossacc + 4 + 256);  // 294912 bf16 (parity)
  ushort* wTt2 = wTt1 + 294912;                 // 73728 bf16 (parity)
  ushort* wTt3 = wTt2 + 73728;                  // 18432 bf16 (tap-major,perm)
  ushort* wTt31 = wTt3 + 18432;                 // 9216 bf16 (tap-major,perm)
  ushort* wT4 = wTt31 + 9216;                   // 4608 bf16 (convt4 B frags)
  ushort* wb1 = wT4 + 4608;                     // 1024 bf16 (conv1 B frags)
  float* g3 = a1;   // bf16 content
  float* g2 = a2;
  float* g1 = a3;
  float* g0 = a4;

  float* st0 = stats + 0 * 512;
  float* st1 = stats + 1 * 512;
  float* st2 = stats + 2 * 512;
  float* st3 = stats + 3 * 512;
  float* st4 = stats + 4 * 512;
  float* st5 = stats + 5 * 512;
  float* st6 = stats + 6 * 512;
  float* st7 = stats + 7 * 512;

  hipMemsetAsync(stats, 0, (4096 + 8) * sizeof(float), stream);

  // ---- weight transposes (bf16) ----
  tr_convw_bf<<<72, 256, 0, stream>>>(ew2, wTc2, 32, 64, 18432);
  tr_convw_bf<<<288, 256, 0, stream>>>(ew3, wTc3, 64, 128, 73728);
  tr_convw_bf<<<1152, 256, 0, stream>>>(ew4, wTc4, 128, 256, 294912);
  tr_convtw_bf<<<1152, 256, 0, stream>>>(wt1, wTt1, 256, 128, 294912);
  tr_convtw_bf<<<288, 256, 0, stream>>>(wt2, wTt2, 128, 64, 73728);
  tr_convtw_tc<<<72, 256, 0, stream>>>(wt3, wTt3, 64, 32, 18432);
  tr_convtw_tc<<<36, 256, 0, stream>>>(wt31, wTt31, 32, 32, 9216);
  tr_w4<<<18, 256, 0, stream>>>(wt4, wT4);
  tr_w1b<<<4, 256, 0, stream>>>(ew1, wb1);
  tr_fcdec<<<4096, 256, 0, stream>>>(wfc, bfc, wfcT, bfcT);
  rowsq<<<2048, 256, 0, stream>>>(cb, csq);

  // ---- encoder ----
  conv1_mfma<<<1024, 256, 0, stream>>>(x, wb1, eb1, (ushort*)a1, st0);
  mfmaconv<64, 0, 32, 32, 64, true, true><<<dim3(1, 1024), 256, 0, stream>>>(
      a1, wTc2, eb2, st0, 1.f / (256.f * 1024.f), a2, st1);
  mfmaconv<64, 0, 16, 64, 128, true, false><<<dim3(2, 256), 256, 0, stream>>>(
      a2, wTc3, eb3, st1, 1.f / (256.f * 256.f), a3, st2);
  mfmaconv<64, 0, 8, 128, 256, true, false><<<dim3(4, 64), 256, 0, stream>>>(
      a3, wTc4, eb4, st2, 1.f / (256.f * 64.f), a4, st3);
  tr_a4<<<4096, 256, 0, stream>>>(a4, a4n);

  // ---- encoder FC (fp32, split-K) ----
  gemm_abt<<<dim3(2, 4, 8), 256, 0, stream>>>(a4n, wmu, nullptr, st3,
                                              1.f / 4096.f, nullptr, P, 4096,
                                              0, 0, 1.f, 0);
  gemm_reduce<<<128, 256, 0, stream>>>(P, ze, bmu, 256, 128, 256, 0, 1.f, 0, 8);
  gemm_abt<<<dim3(2, 4, 8), 256, 0, stream>>>(a4n, wcov, nullptr, st3,
                                              1.f / 4096.f, nullptr, P, 4096,
                                              0, 0, 1.f, 0);
  gemm_reduce<<<128, 256, 0, stream>>>(P, ze, bcov, 256, 128, 256, 128, 1.f, 1, 8);

  // ---- VQ: d2 = csq[n] - 2*ze.cb (|ze|^2 dropped, argmin-invariant) ----
  gemm_bf_abt<<<dim3(128, 4), 256, 0, stream>>>(ze, cb, csq, d2, 256, 8192,
                                                -2.f);
  argmin_d2<<<256, 256, 0, stream>>>(d2, idx);
  vq_gather_loss<<<256, 256, 0, stream>>>(ze, cb, idx, zq, lossacc);

  // ---- decoder FC (bf16 MFMA) ----
  gemm_bf_abt<<<dim3(64, 4), 256, 0, stream>>>(zq, wfcT, bfcT, g0, 256, 4096,
                                               1.f);

  // ---- decoder ----
  mfmaconv<64, 1, 4, 256, 128, false, false><<<dim3(2, 64, 4), 256, 0, stream>>>(
      g0, wTt1, bt1, nullptr, 0.f, g1, st4);
  mfmaconv<64, 1, 8, 128, 64, true, false><<<dim3(1, 256, 4), 256, 0, stream>>>(
      g1, wTt2, bt2, st4, 1.f / (256.f * 64.f), g2, st5);
  convt_mfma<16, 64, true, false, 2><<<512, 256, 0, stream>>>(
      g2, wTt3, bt3, st5, 1.f / (256.f * 256.f), g3, st6);
  convt_mfma<32, 32, true, true, 4><<<1024, 256, 0, stream>>>(
      g3, wTt31, bt31, st6, 1.f / (256.f * 1024.f), g31, st7);

  convt4_mfma<<<1024, 256, 0, stream>>>(g31, wT4, bt4, st7,
                                        1.f / (256.f * 4096.f), (float*)d_out);
  write_loss<<<1, 1, 0, stream>>>(lossacc, (float*)d_out + 3145728);
}